// Round 9
// baseline (1187.351 us; speedup 1.0000x reference)
//
#include <hip/hip_runtime.h>
#include <hip/hip_bf16.h>

#define N_TOK 32768
#define DIM   512
#define NE    2048

#define IDX_OFF  (N_TOK * DIM)
#define LOSS_OFF (IDX_OFF + N_TOK)
#define PERP_OFF (LOSS_OFF + 1)

#define KB(x) ((size_t)(x) << 10)
#define EPS 4e-4f

typedef __attribute__((ext_vector_type(8))) short bf16x8;
typedef __attribute__((ext_vector_type(4))) float f32x4;

__device__ inline unsigned short f2bf(float f) {
  unsigned int x = __float_as_uint(f);
  x = x + 0x7fffu + ((x >> 16) & 1u);
  return (unsigned short)(x >> 16);
}
__device__ inline float bfround(float f) {
  return __uint_as_float((unsigned int)f2bf(f) << 16);
}

__global__ void init_kernel(int* counts) {
  int g = blockIdx.x * 256 + threadIdx.x;
  if (g < NE) counts[g] = 0;
}

// np.sum(x*x, axis=1) exact replication (validated round 4) — do not touch.
__global__ __launch_bounds__(256) void npsum_sq(const float* __restrict__ x,
                                                float* __restrict__ out, int nrows) {
#pragma clang fp contract(off)
  int wave = threadIdx.x >> 6;
  int lane = threadIdx.x & 63;
  int grp = lane >> 4, l = lane & 15;
  int row = blockIdx.x * 16 + wave * 4 + grp;
  if (row >= nrows) return;
  const float* a = x + (size_t)row * DIM;
  float L[4];
  #pragma unroll
  for (int b = 0; b < 4; ++b) {
    const float* p = a + b * 128 + l;
    float q[8];
    #pragma unroll
    for (int j = 0; j < 8; ++j) {
      float t = p[16 * j];
      float s = t * t;
      asm volatile("" : "+v"(s));
      q[j] = s;
    }
    float v = ((q[0] + q[1]) + (q[2] + q[3])) + ((q[4] + q[5]) + (q[6] + q[7]));
    v += __shfl_xor(v, 8);
    v += __shfl_xor(v, 4);
    v += __shfl_xor(v, 2);
    v += __shfl_xor(v, 1);
    L[b] = v;
  }
  if (l == 0) out[row] = (L[0] + L[1]) + (L[2] + L[3]);
}

__global__ __launch_bounds__(256) void cvt_bf(const float* __restrict__ x,
                                              unsigned short* __restrict__ xbf) {
  size_t g = ((size_t)blockIdx.x * 256 + threadIdx.x) * 8;
  float4 a = *(const float4*)(x + g);
  float4 b = *(const float4*)(x + g + 4);
  unsigned short h[8] = {f2bf(a.x), f2bf(a.y), f2bf(a.z), f2bf(a.w),
                         f2bf(b.x), f2bf(b.y), f2bf(b.z), f2bf(b.w)};
  *(uint4*)(xbf + g) = *(uint4*)h;
}

// Stage a 128x64-bf16 tile (16KB) into LDS via global_load_lds width 16.
__device__ inline void stage_tile(const unsigned short* __restrict__ gsrc,
                                  unsigned short* lds_base, int w, int l) {
  const int swz_col = ((l & 7) ^ (l >> 3)) * 8;
  const int rsub = l >> 3;
  #pragma unroll
  for (int s4 = 0; s4 < 4; ++s4) {
    int s = w * 4 + s4;
    const unsigned short* g = gsrc + (size_t)(s * 8 + rsub) * DIM + swz_col;
    __builtin_amdgcn_global_load_lds(
        (const __attribute__((address_space(1))) unsigned int*)g,
        (__attribute__((address_space(3))) unsigned int*)(lds_base + s * 512),
        16, 0, 0);
  }
}

// MFMA GEMM. Block = 128 codes x 128 tokens, K=512 in 8 steps of 64,
// double-buffered LDS, 2-phase. Epilogue: per-16-code-group min.
__global__ __launch_bounds__(256, 2) void gemm_groupmin(
    const unsigned short* __restrict__ ebf, const unsigned short* __restrict__ zbf,
    const float* __restrict__ esum, float* __restrict__ groupmin) {
  __shared__ unsigned short smem[2 * 16384];

  const int tid = threadIdx.x;
  const int cb = blockIdx.x;
  const int tb = blockIdx.y;
  const int w = tid >> 6, l = tid & 63;
  const int lr = l & 15, lk = l >> 4;
  const int wrow = (w >> 1) * 64;
  const int wcol = (w & 1) * 64;

  float esr[4][4];
  #pragma unroll
  for (int i = 0; i < 4; ++i)
    #pragma unroll
    for (int q = 0; q < 4; ++q)
      esr[i][q] = esum[cb * 128 + wrow + i * 16 + lk * 4 + q];

  f32x4 acc[4][4];
  #pragma unroll
  for (int i = 0; i < 4; ++i)
    #pragma unroll
    for (int j = 0; j < 4; ++j) acc[i][j] = (f32x4)(0.f);

  const unsigned short* Ag = ebf + (size_t)(cb * 128) * DIM;
  const unsigned short* Bg = zbf + (size_t)(tb * 128) * DIM;

  stage_tile(Ag, &smem[0], w, l);
  stage_tile(Bg, &smem[8192], w, l);
  asm volatile("s_waitcnt vmcnt(0)" ::: "memory");
  __syncthreads();

  for (int kt = 0; kt < 8; ++kt) {
    const int cur = kt & 1;
    if (kt < 7) {
      stage_tile(Ag + (kt + 1) * 64, &smem[(cur ^ 1) * 16384], w, l);
      stage_tile(Bg + (kt + 1) * 64, &smem[(cur ^ 1) * 16384 + 8192], w, l);
    }
    const unsigned short* Ab = &smem[cur * 16384];
    const unsigned short* Bb = Ab + 8192;
    #pragma unroll
    for (int ks = 0; ks < 2; ++ks) {
      bf16x8 a[4], b[4];
      #pragma unroll
      for (int i = 0; i < 4; ++i) {
        int row = wrow + i * 16 + lr;
        a[i] = *(const bf16x8*)&Ab[row * 64 + (((ks * 4 + lk) ^ (lr & 7)) * 8)];
      }
      #pragma unroll
      for (int j = 0; j < 4; ++j) {
        int row = wcol + j * 16 + lr;
        b[j] = *(const bf16x8*)&Bb[row * 64 + (((ks * 4 + lk) ^ (lr & 7)) * 8)];
      }
      #pragma unroll
      for (int i = 0; i < 4; ++i)
        #pragma unroll
        for (int j = 0; j < 4; ++j)
          acc[i][j] = __builtin_amdgcn_mfma_f32_16x16x32_bf16(a[i], b[j], acc[i][j], 0, 0, 0);
    }
    if (kt < 7) {
      asm volatile("s_waitcnt vmcnt(0)" ::: "memory");
      __syncthreads();
    }
  }

  #pragma unroll
  for (int i = 0; i < 4; ++i) {
    const int g = cb * 8 + (wrow >> 4) + i;
    #pragma unroll
    for (int j = 0; j < 4; ++j) {
      float v0 = fmaf(-2.f, acc[i][j][0], esr[i][0]);
      float v1 = fmaf(-2.f, acc[i][j][1], esr[i][1]);
      float v2 = fmaf(-2.f, acc[i][j][2], esr[i][2]);
      float v3 = fmaf(-2.f, acc[i][j][3], esr[i][3]);
      float m = fminf(fminf(v0, v1), fminf(v2, v3));
      m = fminf(m, __shfl_xor(m, 16));
      m = fminf(m, __shfl_xor(m, 32));
      if (lk == 0) {
        int token = tb * 128 + wcol + j * 16 + lr;
        groupmin[(size_t)token * 128 + g] = m;
      }
    }
  }
}

// One wave per token. Exact np-replica rescan with BATCHED loads: 8 batches
// of {32 float4 loads -> sequential fmaf chain}. Chain order (ascending k)
// is bit-identical to the validated rolled version; only load scheduling
// changed (fixes the round-8 latency serialization).
__global__ __launch_bounds__(256) void select_exact(
    const float* __restrict__ z, const float* __restrict__ e,
    const float* __restrict__ zsum, const float* __restrict__ esum,
    const float* __restrict__ groupmin,
    int* __restrict__ idx_final, int* __restrict__ counts,
    float* __restrict__ out) {
  int t = blockIdx.x * 4 + (threadIdx.x >> 6);
  int lane = threadIdx.x & 63;
  float g0 = groupmin[(size_t)t * 128 + lane];
  float g1 = groupmin[(size_t)t * 128 + 64 + lane];
  float m = fminf(g0, g1);
  #pragma unroll
  for (int s = 32; s >= 1; s >>= 1) m = fminf(m, __shfl_xor(m, s));
  float lim = m + EPS;
  unsigned long long mm0 = __ballot(g0 <= lim);
  unsigned long long mm1 = __ballot(g1 <= lim);
  float zst = zsum[t];
  const float* zr = z + (size_t)t * DIM;
  float bd = 3.402823466e38f; int bc = 0x7fffffff;

  #pragma unroll 1
  for (int half = 0; half < 2; ++half) {
    unsigned long long mk = half ? mm1 : mm0;
    while (mk) {
      int ga[4]; int np = 0;
      while (mk && np < 4) {
        int b = __ffsll((unsigned long long)mk) - 1;
        mk &= mk - 1;
        ga[np++] = half * 64 + b;
      }
      int sub = lane >> 4;
      bool valid = sub < np;
      int grp = ga[valid ? sub : 0];
      int c = grp * 16 + (lane & 15);
      const float* er = e + (size_t)c * DIM;
      float acc = 0.f;
      #pragma unroll
      for (int kb = 0; kb < DIM; kb += 64) {
        float4 zv[16], ev[16];
        #pragma unroll
        for (int u = 0; u < 16; ++u) zv[u] = *(const float4*)(zr + kb + 4 * u);
        #pragma unroll
        for (int u = 0; u < 16; ++u) ev[u] = *(const float4*)(er + kb + 4 * u);
        #pragma unroll
        for (int u = 0; u < 16; ++u) {
          acc = fmaf(zv[u].x, ev[u].x, acc);
          acc = fmaf(zv[u].y, ev[u].y, acc);
          acc = fmaf(zv[u].z, ev[u].z, acc);
          acc = fmaf(zv[u].w, ev[u].w, acc);
        }
      }
      float s = zst + esum[c];
      float d = s - 2.f * acc;
      if (!valid) { d = 3.402823466e38f; c = 0x7fffffff; }
      if (d < bd || (d == bd && c < bc)) { bd = d; bc = c; }
    }
  }
  #pragma unroll
  for (int s = 32; s >= 1; s >>= 1) {
    float od = __shfl_xor(bd, s); int oc = __shfl_xor(bc, s);
    if (od < bd || (od == bd && oc < bc)) { bd = od; bc = oc; }
  }
  if (lane == 0) {
    idx_final[t] = bc;
    out[IDX_OFF + t] = bfround((float)bc);
    atomicAdd(&counts[bc], 1);
  }
}

// 8 tokens/block, 32 threads/token; per-block loss partial (no atomics).
__global__ __launch_bounds__(256) void gather_loss(
    const float* __restrict__ z, const float* __restrict__ e,
    const int* __restrict__ idx_final, float* __restrict__ out,
    float* __restrict__ lossp) {
  __shared__ float red[4];
  int t = blockIdx.x * 8 + (threadIdx.x >> 5);
  int g = threadIdx.x & 31;
  int idx = idx_final[t] & (NE - 1);
  const float* zr = z + (size_t)t * DIM;
  const float* er = e + (size_t)idx * DIM;
  float* op = out + (size_t)t * DIM;
  float s = 0.f;
  #pragma unroll
  for (int p = 0; p < 4; ++p) {
    int c = p * 128 + g * 4;
    float4 ev = *(const float4*)(er + c);
    float4 zv = *(const float4*)(zr + c);
    float4 ov;
    ov.x = bfround(ev.x); ov.y = bfround(ev.y);
    ov.z = bfround(ev.z); ov.w = bfround(ev.w);
    *(float4*)(op + c) = ov;
    float dx = ev.x - zv.x, dy = ev.y - zv.y, dz2 = ev.z - zv.z, dw = ev.w - zv.w;
    s += dx*dx + dy*dy + dz2*dz2 + dw*dw;
  }
  #pragma unroll
  for (int m = 32; m >= 1; m >>= 1) s += __shfl_xor(s, m);
  if ((threadIdx.x & 63) == 0) red[threadIdx.x >> 6] = s;
  __syncthreads();
  if (threadIdx.x == 0)
    lossp[blockIdx.x] = red[0] + red[1] + red[2] + red[3];
}

__global__ void finalize_kernel(const int* __restrict__ counts,
                                const float* __restrict__ lossp,
                                float* __restrict__ out) {
  __shared__ float red[4], red2[4];
  int tid = threadIdx.x;
  float s = 0.f;
  for (int j = tid; j < NE; j += 256) {
    float p = (float)counts[j] * (1.0f / (float)N_TOK);
    s += p * logf(p + 1e-10f);
  }
  float ls = 0.f;
  for (int j = tid; j < 4096; j += 256) ls += lossp[j];
  #pragma unroll
  for (int m = 32; m >= 1; m >>= 1) {
    s += __shfl_xor(s, m);
    ls += __shfl_xor(ls, m);
  }
  if ((tid & 63) == 0) { red[tid >> 6] = s; red2[tid >> 6] = ls; }
  __syncthreads();
  if (tid == 0) {
    float tot = red[0] + red[1] + red[2] + red[3];
    float lt = red2[0] + red2[1] + red2[2] + red2[3];
    out[PERP_OFF] = bfround(expf(-tot));
    out[LOSS_OFF] = bfround(lt * 1.25f / (float)(N_TOK * DIM));
  }
}

extern "C" void kernel_launch(void* const* d_in, const int* in_sizes, int n_in,
                              void* d_out, int out_size, void* d_ws, size_t ws_size,
                              hipStream_t stream) {
  const float* z = (const float*)d_in[0];
  const float* e = (const float*)d_in[1];
  float* out = (float*)d_out;
  char* ws = (char*)d_ws;

  float*    zsum      = (float*)(ws + KB(0));      // 128 KB
  float*    esum      = (float*)(ws + KB(128));    // 8 KB
  int*      counts    = (int*)(ws + KB(136));      // 8 KB
  float*    lossp     = (float*)(ws + KB(144));    // 16 KB
  int*      idx_final = (int*)(ws + KB(160));      // 128 KB
  unsigned short* ebf = (unsigned short*)(ws + KB(288)); // 2 MB

  unsigned short* zbf = (unsigned short*)out;      // 32 MB scratch in d_out
  float* groupmin = out + 8388608;                 // 16 MB scratch in d_out

  init_kernel<<<8, 256, 0, stream>>>(counts);
  npsum_sq<<<N_TOK / 16, 256, 0, stream>>>(z, zsum, N_TOK);
  npsum_sq<<<NE / 16, 256, 0, stream>>>(e, esum, NE);
  cvt_bf<<<(NE * DIM) / (256 * 8), 256, 0, stream>>>(e, ebf);
  cvt_bf<<<(N_TOK * DIM) / (256 * 8), 256, 0, stream>>>(z, zbf);
  gemm_groupmin<<<dim3(NE / 128, N_TOK / 128), 256, 0, stream>>>(ebf, zbf, esum, groupmin);
  select_exact<<<N_TOK / 4, 256, 0, stream>>>(z, e, zsum, esum, groupmin,
                                              idx_final, counts, out);
  gather_loss<<<N_TOK / 8, 256, 0, stream>>>(z, e, idx_final, out, lossp);
  finalize_kernel<<<1, 256, 0, stream>>>(counts, lossp, out);
}

// Round 10
// 674.287 us; speedup vs baseline: 1.7609x; 1.7609x over previous
//
#include <hip/hip_runtime.h>
#include <hip/hip_bf16.h>

#define N_TOK 32768
#define DIM   512
#define NE    2048

#define IDX_OFF  (N_TOK * DIM)
#define LOSS_OFF (IDX_OFF + N_TOK)
#define PERP_OFF (LOSS_OFF + 1)

#define KB(x) ((size_t)(x) << 10)
#define EPS 4e-4f

typedef __attribute__((ext_vector_type(8))) short bf16x8;
typedef __attribute__((ext_vector_type(4))) float f32x4;

__device__ inline unsigned short f2bf(float f) {
  unsigned int x = __float_as_uint(f);
  x = x + 0x7fffu + ((x >> 16) & 1u);
  return (unsigned short)(x >> 16);
}
__device__ inline float bfround(float f) {
  return __uint_as_float((unsigned int)f2bf(f) << 16);
}

__global__ void init_kernel(int* counts) {
  int g = blockIdx.x * 256 + threadIdx.x;
  if (g < NE) counts[g] = 0;
}

// np.sum(x*x, axis=1) exact replication (validated round 4) — do not touch.
__global__ __launch_bounds__(256) void npsum_sq(const float* __restrict__ x,
                                                float* __restrict__ out, int nrows) {
#pragma clang fp contract(off)
  int wave = threadIdx.x >> 6;
  int lane = threadIdx.x & 63;
  int grp = lane >> 4, l = lane & 15;
  int row = blockIdx.x * 16 + wave * 4 + grp;
  if (row >= nrows) return;
  const float* a = x + (size_t)row * DIM;
  float L[4];
  #pragma unroll
  for (int b = 0; b < 4; ++b) {
    const float* p = a + b * 128 + l;
    float q[8];
    #pragma unroll
    for (int j = 0; j < 8; ++j) {
      float t = p[16 * j];
      float s = t * t;
      asm volatile("" : "+v"(s));
      q[j] = s;
    }
    float v = ((q[0] + q[1]) + (q[2] + q[3])) + ((q[4] + q[5]) + (q[6] + q[7]));
    v += __shfl_xor(v, 8);
    v += __shfl_xor(v, 4);
    v += __shfl_xor(v, 2);
    v += __shfl_xor(v, 1);
    L[b] = v;
  }
  if (l == 0) out[row] = (L[0] + L[1]) + (L[2] + L[3]);
}

__global__ __launch_bounds__(256) void cvt_bf(const float* __restrict__ x,
                                              unsigned short* __restrict__ xbf) {
  size_t g = ((size_t)blockIdx.x * 256 + threadIdx.x) * 8;
  float4 a = *(const float4*)(x + g);
  float4 b = *(const float4*)(x + g + 4);
  unsigned short h[8] = {f2bf(a.x), f2bf(a.y), f2bf(a.z), f2bf(a.w),
                         f2bf(b.x), f2bf(b.y), f2bf(b.z), f2bf(b.w)};
  *(uint4*)(xbf + g) = *(uint4*)h;
}

// Stage a 128x64-bf16 tile (16KB) into LDS via global_load_lds width 16.
__device__ inline void stage_tile(const unsigned short* __restrict__ gsrc,
                                  unsigned short* lds_base, int w, int l) {
  const int swz_col = ((l & 7) ^ (l >> 3)) * 8;
  const int rsub = l >> 3;
  #pragma unroll
  for (int s4 = 0; s4 < 4; ++s4) {
    int s = w * 4 + s4;
    const unsigned short* g = gsrc + (size_t)(s * 8 + rsub) * DIM + swz_col;
    __builtin_amdgcn_global_load_lds(
        (const __attribute__((address_space(1))) unsigned int*)g,
        (__attribute__((address_space(3))) unsigned int*)(lds_base + s * 512),
        16, 0, 0);
  }
}

// MFMA GEMM. Block = 128 codes x 128 tokens, K=512 in 8 steps of 64,
// double-buffered LDS, 2-phase. Epilogue: per-16-code-group min.
__global__ __launch_bounds__(256, 2) void gemm_groupmin(
    const unsigned short* __restrict__ ebf, const unsigned short* __restrict__ zbf,
    const float* __restrict__ esum, float* __restrict__ groupmin) {
  __shared__ unsigned short smem[2 * 16384];

  const int tid = threadIdx.x;
  const int cb = blockIdx.x;
  const int tb = blockIdx.y;
  const int w = tid >> 6, l = tid & 63;
  const int lr = l & 15, lk = l >> 4;
  const int wrow = (w >> 1) * 64;
  const int wcol = (w & 1) * 64;

  float esr[4][4];
  #pragma unroll
  for (int i = 0; i < 4; ++i)
    #pragma unroll
    for (int q = 0; q < 4; ++q)
      esr[i][q] = esum[cb * 128 + wrow + i * 16 + lk * 4 + q];

  f32x4 acc[4][4];
  #pragma unroll
  for (int i = 0; i < 4; ++i)
    #pragma unroll
    for (int j = 0; j < 4; ++j) acc[i][j] = (f32x4)(0.f);

  const unsigned short* Ag = ebf + (size_t)(cb * 128) * DIM;
  const unsigned short* Bg = zbf + (size_t)(tb * 128) * DIM;

  stage_tile(Ag, &smem[0], w, l);
  stage_tile(Bg, &smem[8192], w, l);
  asm volatile("s_waitcnt vmcnt(0)" ::: "memory");
  __syncthreads();

  for (int kt = 0; kt < 8; ++kt) {
    const int cur = kt & 1;
    if (kt < 7) {
      stage_tile(Ag + (kt + 1) * 64, &smem[(cur ^ 1) * 16384], w, l);
      stage_tile(Bg + (kt + 1) * 64, &smem[(cur ^ 1) * 16384 + 8192], w, l);
    }
    const unsigned short* Ab = &smem[cur * 16384];
    const unsigned short* Bb = Ab + 8192;
    #pragma unroll
    for (int ks = 0; ks < 2; ++ks) {
      bf16x8 a[4], b[4];
      #pragma unroll
      for (int i = 0; i < 4; ++i) {
        int row = wrow + i * 16 + lr;
        a[i] = *(const bf16x8*)&Ab[row * 64 + (((ks * 4 + lk) ^ (lr & 7)) * 8)];
      }
      #pragma unroll
      for (int j = 0; j < 4; ++j) {
        int row = wcol + j * 16 + lr;
        b[j] = *(const bf16x8*)&Bb[row * 64 + (((ks * 4 + lk) ^ (lr & 7)) * 8)];
      }
      #pragma unroll
      for (int i = 0; i < 4; ++i)
        #pragma unroll
        for (int j = 0; j < 4; ++j)
          acc[i][j] = __builtin_amdgcn_mfma_f32_16x16x32_bf16(a[i], b[j], acc[i][j], 0, 0, 0);
    }
    if (kt < 7) {
      asm volatile("s_waitcnt vmcnt(0)" ::: "memory");
      __syncthreads();
    }
  }

  #pragma unroll
  for (int i = 0; i < 4; ++i) {
    const int g = cb * 8 + (wrow >> 4) + i;
    #pragma unroll
    for (int j = 0; j < 4; ++j) {
      float v0 = fmaf(-2.f, acc[i][j][0], esr[i][0]);
      float v1 = fmaf(-2.f, acc[i][j][1], esr[i][1]);
      float v2 = fmaf(-2.f, acc[i][j][2], esr[i][2]);
      float v3 = fmaf(-2.f, acc[i][j][3], esr[i][3]);
      float m = fminf(fminf(v0, v1), fminf(v2, v3));
      m = fminf(m, __shfl_xor(m, 16));
      m = fminf(m, __shfl_xor(m, 32));
      if (lk == 0) {
        int token = tb * 128 + wcol + j * 16 + lr;
        groupmin[(size_t)token * 128 + g] = m;
      }
    }
  }
}

// One wave per token. Exact np-replica rescan. z-row staged in LDS (wave-
// uniform broadcast reads); e loaded in batches of 8 float4 (32 VGPRs, no
// spill). Candidate group ids packed in a u32 (no runtime-indexed array).
// fmaf chain order (ascending k, sequential) bit-identical to round 4.
__global__ __launch_bounds__(256) void select_exact(
    const float* __restrict__ z, const float* __restrict__ e,
    const float* __restrict__ zsum, const float* __restrict__ esum,
    const float* __restrict__ groupmin,
    int* __restrict__ idx_final, int* __restrict__ counts,
    float* __restrict__ out) {
  __shared__ float zs[4][512];
  const int wid = threadIdx.x >> 6;
  const int t = blockIdx.x * 4 + wid;
  const int lane = threadIdx.x & 63;
  const float* zr = z + (size_t)t * DIM;

  // stage this wave's z row into LDS (8 floats per lane)
  {
    float4 a = *(const float4*)(zr + lane * 8);
    float4 b = *(const float4*)(zr + lane * 8 + 4);
    *(float4*)&zs[wid][lane * 8] = a;
    *(float4*)&zs[wid][lane * 8 + 4] = b;
  }
  __syncthreads();

  float g0 = groupmin[(size_t)t * 128 + lane];
  float g1 = groupmin[(size_t)t * 128 + 64 + lane];
  float m = fminf(g0, g1);
  #pragma unroll
  for (int s = 32; s >= 1; s >>= 1) m = fminf(m, __shfl_xor(m, s));
  float lim = m + EPS;
  unsigned long long mm0 = __ballot(g0 <= lim);
  unsigned long long mm1 = __ballot(g1 <= lim);
  float zst = zsum[t];
  const float* zl = zs[wid];
  float bd = 3.402823466e38f; int bc = 0x7fffffff;

  #pragma unroll 1
  for (int half = 0; half < 2; ++half) {
    unsigned long long mk = half ? mm1 : mm0;
    while (mk) {
      unsigned packed = 0u; int np = 0;
      while (mk && np < 4) {
        int b = __ffsll((unsigned long long)mk) - 1;
        mk &= mk - 1;
        packed |= (unsigned)(half * 64 + b) << (8 * np);
        ++np;
      }
      int sub = lane >> 4;
      bool valid = sub < np;
      int grp = (int)((packed >> (8 * sub)) & 127u);
      int c = grp * 16 + (lane & 15);
      const float* er = e + (size_t)c * DIM;
      float acc = 0.f;
      #pragma unroll 1
      for (int kb = 0; kb < DIM; kb += 32) {
        float4 ev[8];
        #pragma unroll
        for (int u = 0; u < 8; ++u) ev[u] = *(const float4*)(er + kb + 4 * u);
        #pragma unroll
        for (int u = 0; u < 8; ++u) {
          float4 zv = *(const float4*)&zl[kb + 4 * u];
          acc = fmaf(zv.x, ev[u].x, acc);
          acc = fmaf(zv.y, ev[u].y, acc);
          acc = fmaf(zv.z, ev[u].z, acc);
          acc = fmaf(zv.w, ev[u].w, acc);
        }
      }
      float s = zst + esum[c];
      float d = s - 2.f * acc;
      if (!valid) { d = 3.402823466e38f; c = 0x7fffffff; }
      if (d < bd || (d == bd && c < bc)) { bd = d; bc = c; }
    }
  }
  #pragma unroll
  for (int s = 32; s >= 1; s >>= 1) {
    float od = __shfl_xor(bd, s); int oc = __shfl_xor(bc, s);
    if (od < bd || (od == bd && oc < bc)) { bd = od; bc = oc; }
  }
  if (lane == 0) {
    idx_final[t] = bc;
    out[IDX_OFF + t] = bfround((float)bc);
    atomicAdd(&counts[bc], 1);
  }
}

// 8 tokens/block, 32 threads/token; per-block loss partial (no atomics).
__global__ __launch_bounds__(256) void gather_loss(
    const float* __restrict__ z, const float* __restrict__ e,
    const int* __restrict__ idx_final, float* __restrict__ out,
    float* __restrict__ lossp) {
  __shared__ float red[4];
  int t = blockIdx.x * 8 + (threadIdx.x >> 5);
  int g = threadIdx.x & 31;
  int idx = idx_final[t] & (NE - 1);
  const float* zr = z + (size_t)t * DIM;
  const float* er = e + (size_t)idx * DIM;
  float* op = out + (size_t)t * DIM;
  float s = 0.f;
  #pragma unroll
  for (int p = 0; p < 4; ++p) {
    int c = p * 128 + g * 4;
    float4 ev = *(const float4*)(er + c);
    float4 zv = *(const float4*)(zr + c);
    float4 ov;
    ov.x = bfround(ev.x); ov.y = bfround(ev.y);
    ov.z = bfround(ev.z); ov.w = bfround(ev.w);
    *(float4*)(op + c) = ov;
    float dx = ev.x - zv.x, dy = ev.y - zv.y, dz2 = ev.z - zv.z, dw = ev.w - zv.w;
    s += dx*dx + dy*dy + dz2*dz2 + dw*dw;
  }
  #pragma unroll
  for (int m = 32; m >= 1; m >>= 1) s += __shfl_xor(s, m);
  if ((threadIdx.x & 63) == 0) red[threadIdx.x >> 6] = s;
  __syncthreads();
  if (threadIdx.x == 0)
    lossp[blockIdx.x] = red[0] + red[1] + red[2] + red[3];
}

__global__ void finalize_kernel(const int* __restrict__ counts,
                                const float* __restrict__ lossp,
                                float* __restrict__ out) {
  __shared__ float red[4], red2[4];
  int tid = threadIdx.x;
  float s = 0.f;
  for (int j = tid; j < NE; j += 256) {
    float p = (float)counts[j] * (1.0f / (float)N_TOK);
    s += p * logf(p + 1e-10f);
  }
  float ls = 0.f;
  for (int j = tid; j < 4096; j += 256) ls += lossp[j];
  #pragma unroll
  for (int m = 32; m >= 1; m >>= 1) {
    s += __shfl_xor(s, m);
    ls += __shfl_xor(ls, m);
  }
  if ((tid & 63) == 0) { red[tid >> 6] = s; red2[tid >> 6] = ls; }
  __syncthreads();
  if (tid == 0) {
    float tot = red[0] + red[1] + red[2] + red[3];
    float lt = red2[0] + red2[1] + red2[2] + red2[3];
    out[PERP_OFF] = bfround(expf(-tot));
    out[LOSS_OFF] = bfround(lt * 1.25f / (float)(N_TOK * DIM));
  }
}

extern "C" void kernel_launch(void* const* d_in, const int* in_sizes, int n_in,
                              void* d_out, int out_size, void* d_ws, size_t ws_size,
                              hipStream_t stream) {
  const float* z = (const float*)d_in[0];
  const float* e = (const float*)d_in[1];
  float* out = (float*)d_out;
  char* ws = (char*)d_ws;

  float*    zsum      = (float*)(ws + KB(0));      // 128 KB
  float*    esum      = (float*)(ws + KB(128));    // 8 KB
  int*      counts    = (int*)(ws + KB(136));      // 8 KB
  float*    lossp     = (float*)(ws + KB(144));    // 16 KB
  int*      idx_final = (int*)(ws + KB(160));      // 128 KB
  unsigned short* ebf = (unsigned short*)(ws + KB(288)); // 2 MB

  unsigned short* zbf = (unsigned short*)out;      // 32 MB scratch in d_out
  float* groupmin = out + 8388608;                 // 16 MB scratch in d_out

  init_kernel<<<8, 256, 0, stream>>>(counts);
  npsum_sq<<<N_TOK / 16, 256, 0, stream>>>(z, zsum, N_TOK);
  npsum_sq<<<NE / 16, 256, 0, stream>>>(e, esum, NE);
  cvt_bf<<<(NE * DIM) / (256 * 8), 256, 0, stream>>>(e, ebf);
  cvt_bf<<<(N_TOK * DIM) / (256 * 8), 256, 0, stream>>>(z, zbf);
  gemm_groupmin<<<dim3(NE / 128, N_TOK / 128), 256, 0, stream>>>(ebf, zbf, esum, groupmin);
  select_exact<<<N_TOK / 4, 256, 0, stream>>>(z, e, zsum, esum, groupmin,
                                              idx_final, counts, out);
  gather_loss<<<N_TOK / 8, 256, 0, stream>>>(z, e, idx_final, out, lossp);
  finalize_kernel<<<1, 256, 0, stream>>>(counts, lossp, out);
}

// Round 11
// 227.492 us; speedup vs baseline: 5.2193x; 2.9640x over previous
//
#include <hip/hip_runtime.h>
#include <hip/hip_bf16.h>

#define N_TOK 32768
#define DIM   512
#define NE    2048

#define IDX_OFF  (N_TOK * DIM)
#define LOSS_OFF (IDX_OFF + N_TOK)
#define PERP_OFF (LOSS_OFF + 1)

#define KB(x) ((size_t)(x) << 10)
#define EPS 4e-4f

typedef __attribute__((ext_vector_type(8))) short bf16x8;
typedef __attribute__((ext_vector_type(4))) float f32x4;

__device__ inline unsigned short f2bf(float f) {
  unsigned int x = __float_as_uint(f);
  x = x + 0x7fffu + ((x >> 16) & 1u);
  return (unsigned short)(x >> 16);
}
__device__ inline float bfround(float f) {
  return __uint_as_float((unsigned int)f2bf(f) << 16);
}

__global__ void init_kernel(int* counts) {
  int g = blockIdx.x * 256 + threadIdx.x;
  if (g < NE) counts[g] = 0;
}

// np.sum(x*x, axis=1) exact replication (validated round 4) — do not touch.
__global__ __launch_bounds__(256) void npsum_sq(const float* __restrict__ x,
                                                float* __restrict__ out, int nrows) {
#pragma clang fp contract(off)
  int wave = threadIdx.x >> 6;
  int lane = threadIdx.x & 63;
  int grp = lane >> 4, l = lane & 15;
  int row = blockIdx.x * 16 + wave * 4 + grp;
  if (row >= nrows) return;
  const float* a = x + (size_t)row * DIM;
  float L[4];
  #pragma unroll
  for (int b = 0; b < 4; ++b) {
    const float* p = a + b * 128 + l;
    float q[8];
    #pragma unroll
    for (int j = 0; j < 8; ++j) {
      float t = p[16 * j];
      float s = t * t;
      asm volatile("" : "+v"(s));
      q[j] = s;
    }
    float v = ((q[0] + q[1]) + (q[2] + q[3])) + ((q[4] + q[5]) + (q[6] + q[7]));
    v += __shfl_xor(v, 8);
    v += __shfl_xor(v, 4);
    v += __shfl_xor(v, 2);
    v += __shfl_xor(v, 1);
    L[b] = v;
  }
  if (l == 0) out[row] = (L[0] + L[1]) + (L[2] + L[3]);
}

__global__ __launch_bounds__(256) void cvt_bf(const float* __restrict__ x,
                                              unsigned short* __restrict__ xbf) {
  size_t g = ((size_t)blockIdx.x * 256 + threadIdx.x) * 8;
  float4 a = *(const float4*)(x + g);
  float4 b = *(const float4*)(x + g + 4);
  unsigned short h[8] = {f2bf(a.x), f2bf(a.y), f2bf(a.z), f2bf(a.w),
                         f2bf(b.x), f2bf(b.y), f2bf(b.z), f2bf(b.w)};
  *(uint4*)(xbf + g) = *(uint4*)h;
}

// Stage a 128x64-bf16 tile (16KB) into LDS via global_load_lds width 16.
__device__ inline void stage_tile(const unsigned short* __restrict__ gsrc,
                                  unsigned short* lds_base, int w, int l) {
  const int swz_col = ((l & 7) ^ (l >> 3)) * 8;
  const int rsub = l >> 3;
  #pragma unroll
  for (int s4 = 0; s4 < 4; ++s4) {
    int s = w * 4 + s4;
    const unsigned short* g = gsrc + (size_t)(s * 8 + rsub) * DIM + swz_col;
    __builtin_amdgcn_global_load_lds(
        (const __attribute__((address_space(1))) unsigned int*)g,
        (__attribute__((address_space(3))) unsigned int*)(lds_base + s * 512),
        16, 0, 0);
  }
}

// MFMA GEMM. Block = 128 codes x 128 tokens, K=512 in 8 steps of 64,
// double-buffered LDS, 2-phase. Epilogue: per-16-code-group min.
__global__ __launch_bounds__(256, 2) void gemm_groupmin(
    const unsigned short* __restrict__ ebf, const unsigned short* __restrict__ zbf,
    const float* __restrict__ esum, float* __restrict__ groupmin) {
  __shared__ unsigned short smem[2 * 16384];

  const int tid = threadIdx.x;
  const int cb = blockIdx.x;
  const int tb = blockIdx.y;
  const int w = tid >> 6, l = tid & 63;
  const int lr = l & 15, lk = l >> 4;
  const int wrow = (w >> 1) * 64;
  const int wcol = (w & 1) * 64;

  float esr[4][4];
  #pragma unroll
  for (int i = 0; i < 4; ++i)
    #pragma unroll
    for (int q = 0; q < 4; ++q)
      esr[i][q] = esum[cb * 128 + wrow + i * 16 + lk * 4 + q];

  f32x4 acc[4][4];
  #pragma unroll
  for (int i = 0; i < 4; ++i)
    #pragma unroll
    for (int j = 0; j < 4; ++j) acc[i][j] = (f32x4)(0.f);

  const unsigned short* Ag = ebf + (size_t)(cb * 128) * DIM;
  const unsigned short* Bg = zbf + (size_t)(tb * 128) * DIM;

  stage_tile(Ag, &smem[0], w, l);
  stage_tile(Bg, &smem[8192], w, l);
  asm volatile("s_waitcnt vmcnt(0)" ::: "memory");
  __syncthreads();

  for (int kt = 0; kt < 8; ++kt) {
    const int cur = kt & 1;
    if (kt < 7) {
      stage_tile(Ag + (kt + 1) * 64, &smem[(cur ^ 1) * 16384], w, l);
      stage_tile(Bg + (kt + 1) * 64, &smem[(cur ^ 1) * 16384 + 8192], w, l);
    }
    const unsigned short* Ab = &smem[cur * 16384];
    const unsigned short* Bb = Ab + 8192;
    #pragma unroll
    for (int ks = 0; ks < 2; ++ks) {
      bf16x8 a[4], b[4];
      #pragma unroll
      for (int i = 0; i < 4; ++i) {
        int row = wrow + i * 16 + lr;
        a[i] = *(const bf16x8*)&Ab[row * 64 + (((ks * 4 + lk) ^ (lr & 7)) * 8)];
      }
      #pragma unroll
      for (int j = 0; j < 4; ++j) {
        int row = wcol + j * 16 + lr;
        b[j] = *(const bf16x8*)&Bb[row * 64 + (((ks * 4 + lk) ^ (lr & 7)) * 8)];
      }
      #pragma unroll
      for (int i = 0; i < 4; ++i)
        #pragma unroll
        for (int j = 0; j < 4; ++j)
          acc[i][j] = __builtin_amdgcn_mfma_f32_16x16x32_bf16(a[i], b[j], acc[i][j], 0, 0, 0);
    }
    if (kt < 7) {
      asm volatile("s_waitcnt vmcnt(0)" ::: "memory");
      __syncthreads();
    }
  }

  #pragma unroll
  for (int i = 0; i < 4; ++i) {
    const int g = cb * 8 + (wrow >> 4) + i;
    #pragma unroll
    for (int j = 0; j < 4; ++j) {
      float v0 = fmaf(-2.f, acc[i][j][0], esr[i][0]);
      float v1 = fmaf(-2.f, acc[i][j][1], esr[i][1]);
      float v2 = fmaf(-2.f, acc[i][j][2], esr[i][2]);
      float v3 = fmaf(-2.f, acc[i][j][3], esr[i][3]);
      float m = fminf(fminf(v0, v1), fminf(v2, v3));
      m = fminf(m, __shfl_xor(m, 16));
      m = fminf(m, __shfl_xor(m, 32));
      if (lk == 0) {
        int token = tb * 128 + wcol + j * 16 + lr;
        groupmin[(size_t)token * 128 + g] = m;
      }
    }
  }
}

// One wave per token. Wave-COOPERATIVE exact rescan: whole wave processes one
// candidate code at a time with perfectly coalesced e-row loads (lane covers
// k = lane*4..+3 and 256+lane*4..+3). Per-lane sequential fmaf + butterfly
// tree sum (all lanes get the bitwise-identical total). Ascending code order
// + strict < gives np first-index tie semantics. Dot rounding delta vs the
// validated chain (~1e-8) is absorbed by the ulp(512)=6.1e-5 quantization
// of d (same risk class as sequential-vs-np-sgemm, which has passed 7x).
__global__ __launch_bounds__(256) void select_exact(
    const float* __restrict__ z, const float* __restrict__ e,
    const float* __restrict__ zsum, const float* __restrict__ esum,
    const float* __restrict__ groupmin,
    int* __restrict__ idx_final, int* __restrict__ counts,
    float* __restrict__ out) {
  const int wid = threadIdx.x >> 6;
  const int t = blockIdx.x * 4 + wid;
  const int lane = threadIdx.x & 63;
  const float* zr = z + (size_t)t * DIM;

  // this lane's fixed z chunks (k = lane*4.., 256+lane*4..), coalesced
  float4 za = *(const float4*)(zr + lane * 4);
  float4 zb = *(const float4*)(zr + 256 + lane * 4);

  float g0 = groupmin[(size_t)t * 128 + lane];
  float g1 = groupmin[(size_t)t * 128 + 64 + lane];
  float m = fminf(g0, g1);
  #pragma unroll
  for (int s = 32; s >= 1; s >>= 1) m = fminf(m, __shfl_xor(m, s));
  float lim = m + EPS;
  unsigned long long mm0 = __ballot(g0 <= lim);
  unsigned long long mm1 = __ballot(g1 <= lim);
  float zst = zsum[t];
  float bd = 3.402823466e38f; int bc = 0x7fffffff;

  #pragma unroll 1
  for (int half = 0; half < 2; ++half) {
    unsigned long long mk = half ? mm1 : mm0;
    while (mk) {
      int b = __ffsll((unsigned long long)mk) - 1;
      mk &= mk - 1;
      const int base = (half * 64 + b) * 16;
      const float* eg = e + (size_t)base * DIM;
      #pragma unroll 4
      for (int ci = 0; ci < 16; ++ci) {
        int c = base + ci;
        const float* er = eg + (size_t)ci * DIM;
        float4 ea = *(const float4*)(er + lane * 4);
        float4 eb = *(const float4*)(er + 256 + lane * 4);
        float p = 0.f;
        p = fmaf(za.x, ea.x, p); p = fmaf(za.y, ea.y, p);
        p = fmaf(za.z, ea.z, p); p = fmaf(za.w, ea.w, p);
        p = fmaf(zb.x, eb.x, p); p = fmaf(zb.y, eb.y, p);
        p = fmaf(zb.z, eb.z, p); p = fmaf(zb.w, eb.w, p);
        #pragma unroll
        for (int s = 1; s <= 32; s <<= 1) p += __shfl_xor(p, s);
        float d = (zst + esum[c]) - 2.f * p;
        if (d < bd) { bd = d; bc = c; }   // ascending c => first-index ties
      }
    }
  }
  if (lane == 0) {
    idx_final[t] = bc;
    out[IDX_OFF + t] = bfround((float)bc);
    atomicAdd(&counts[bc], 1);
  }
}

// 8 tokens/block, 32 threads/token; per-block loss partial (no atomics).
__global__ __launch_bounds__(256) void gather_loss(
    const float* __restrict__ z, const float* __restrict__ e,
    const int* __restrict__ idx_final, float* __restrict__ out,
    float* __restrict__ lossp) {
  __shared__ float red[4];
  int t = blockIdx.x * 8 + (threadIdx.x >> 5);
  int g = threadIdx.x & 31;
  int idx = idx_final[t] & (NE - 1);
  const float* zr = z + (size_t)t * DIM;
  const float* er = e + (size_t)idx * DIM;
  float* op = out + (size_t)t * DIM;
  float s = 0.f;
  #pragma unroll
  for (int p = 0; p < 4; ++p) {
    int c = p * 128 + g * 4;
    float4 ev = *(const float4*)(er + c);
    float4 zv = *(const float4*)(zr + c);
    float4 ov;
    ov.x = bfround(ev.x); ov.y = bfround(ev.y);
    ov.z = bfround(ev.z); ov.w = bfround(ev.w);
    *(float4*)(op + c) = ov;
    float dx = ev.x - zv.x, dy = ev.y - zv.y, dz2 = ev.z - zv.z, dw = ev.w - zv.w;
    s += dx*dx + dy*dy + dz2*dz2 + dw*dw;
  }
  #pragma unroll
  for (int m = 32; m >= 1; m >>= 1) s += __shfl_xor(s, m);
  if ((threadIdx.x & 63) == 0) red[threadIdx.x >> 6] = s;
  __syncthreads();
  if (threadIdx.x == 0)
    lossp[blockIdx.x] = red[0] + red[1] + red[2] + red[3];
}

__global__ void finalize_kernel(const int* __restrict__ counts,
                                const float* __restrict__ lossp,
                                float* __restrict__ out) {
  __shared__ float red[4], red2[4];
  int tid = threadIdx.x;
  float s = 0.f;
  for (int j = tid; j < NE; j += 256) {
    float p = (float)counts[j] * (1.0f / (float)N_TOK);
    s += p * logf(p + 1e-10f);
  }
  float ls = 0.f;
  for (int j = tid; j < 4096; j += 256) ls += lossp[j];
  #pragma unroll
  for (int m = 32; m >= 1; m >>= 1) {
    s += __shfl_xor(s, m);
    ls += __shfl_xor(ls, m);
  }
  if ((tid & 63) == 0) { red[tid >> 6] = s; red2[tid >> 6] = ls; }
  __syncthreads();
  if (tid == 0) {
    float tot = red[0] + red[1] + red[2] + red[3];
    float lt = red2[0] + red2[1] + red2[2] + red2[3];
    out[PERP_OFF] = bfround(expf(-tot));
    out[LOSS_OFF] = bfround(lt * 1.25f / (float)(N_TOK * DIM));
  }
}

extern "C" void kernel_launch(void* const* d_in, const int* in_sizes, int n_in,
                              void* d_out, int out_size, void* d_ws, size_t ws_size,
                              hipStream_t stream) {
  const float* z = (const float*)d_in[0];
  const float* e = (const float*)d_in[1];
  float* out = (float*)d_out;
  char* ws = (char*)d_ws;

  float*    zsum      = (float*)(ws + KB(0));      // 128 KB
  float*    esum      = (float*)(ws + KB(128));    // 8 KB
  int*      counts    = (int*)(ws + KB(136));      // 8 KB
  float*    lossp     = (float*)(ws + KB(144));    // 16 KB
  int*      idx_final = (int*)(ws + KB(160));      // 128 KB
  unsigned short* ebf = (unsigned short*)(ws + KB(288)); // 2 MB

  unsigned short* zbf = (unsigned short*)out;      // 32 MB scratch in d_out
  float* groupmin = out + 8388608;                 // 16 MB scratch in d_out

  init_kernel<<<8, 256, 0, stream>>>(counts);
  npsum_sq<<<N_TOK / 16, 256, 0, stream>>>(z, zsum, N_TOK);
  npsum_sq<<<NE / 16, 256, 0, stream>>>(e, esum, NE);
  cvt_bf<<<(NE * DIM) / (256 * 8), 256, 0, stream>>>(e, ebf);
  cvt_bf<<<(N_TOK * DIM) / (256 * 8), 256, 0, stream>>>(z, zbf);
  gemm_groupmin<<<dim3(NE / 128, N_TOK / 128), 256, 0, stream>>>(ebf, zbf, esum, groupmin);
  select_exact<<<N_TOK / 4, 256, 0, stream>>>(z, e, zsum, esum, groupmin,
                                              idx_final, counts, out);
  gather_loss<<<N_TOK / 8, 256, 0, stream>>>(z, e, idx_final, out, lossp);
  finalize_kernel<<<1, 256, 0, stream>>>(counts, lossp, out);
}

// Round 12
// 225.086 us; speedup vs baseline: 5.2751x; 1.0107x over previous
//
#include <hip/hip_runtime.h>
#include <hip/hip_bf16.h>

#define N_TOK 32768
#define DIM   512
#define NE    2048

#define IDX_OFF  (N_TOK * DIM)
#define LOSS_OFF (IDX_OFF + N_TOK)
#define PERP_OFF (LOSS_OFF + 1)

#define KB(x) ((size_t)(x) << 10)
#define EPS 4e-4f

typedef __attribute__((ext_vector_type(8))) short bf16x8;
typedef __attribute__((ext_vector_type(4))) float f32x4;

__device__ inline unsigned short f2bf(float f) {
  unsigned int x = __float_as_uint(f);
  x = x + 0x7fffu + ((x >> 16) & 1u);
  return (unsigned short)(x >> 16);
}
__device__ inline float bfround(float f) {
  return __uint_as_float((unsigned int)f2bf(f) << 16);
}

__global__ void init_kernel(int* counts) {
  int g = blockIdx.x * 256 + threadIdx.x;
  if (g < NE) counts[g] = 0;
}

// np.sum(x*x, axis=1) exact replication (validated round 4) — do not touch.
__global__ __launch_bounds__(256) void npsum_sq(const float* __restrict__ x,
                                                float* __restrict__ out, int nrows) {
#pragma clang fp contract(off)
  int wave = threadIdx.x >> 6;
  int lane = threadIdx.x & 63;
  int grp = lane >> 4, l = lane & 15;
  int row = blockIdx.x * 16 + wave * 4 + grp;
  if (row >= nrows) return;
  const float* a = x + (size_t)row * DIM;
  float L[4];
  #pragma unroll
  for (int b = 0; b < 4; ++b) {
    const float* p = a + b * 128 + l;
    float q[8];
    #pragma unroll
    for (int j = 0; j < 8; ++j) {
      float t = p[16 * j];
      float s = t * t;
      asm volatile("" : "+v"(s));
      q[j] = s;
    }
    float v = ((q[0] + q[1]) + (q[2] + q[3])) + ((q[4] + q[5]) + (q[6] + q[7]));
    v += __shfl_xor(v, 8);
    v += __shfl_xor(v, 4);
    v += __shfl_xor(v, 2);
    v += __shfl_xor(v, 1);
    L[b] = v;
  }
  if (l == 0) out[row] = (L[0] + L[1]) + (L[2] + L[3]);
}

__global__ __launch_bounds__(256) void cvt_bf(const float* __restrict__ x,
                                              unsigned short* __restrict__ xbf) {
  size_t g = ((size_t)blockIdx.x * 256 + threadIdx.x) * 8;
  float4 a = *(const float4*)(x + g);
  float4 b = *(const float4*)(x + g + 4);
  unsigned short h[8] = {f2bf(a.x), f2bf(a.y), f2bf(a.z), f2bf(a.w),
                         f2bf(b.x), f2bf(b.y), f2bf(b.z), f2bf(b.w)};
  *(uint4*)(xbf + g) = *(uint4*)h;
}

// Stage a 256x64-bf16 K-tile (32KB) into LDS via global_load_lds width 16.
// 512 threads: s = w*4+s4 (0..31), each s covers 8 rows; LDS dest is
// wave-uniform base (HW adds lane*16B). Global src pre-swizzled (involution
// slot^=(row&7)) so the swizzled ds_read is bank-conflict-free (validated:
// SQ_LDS_BANK_CONFLICT = 0 in rounds 7-11).
__device__ inline void stage_tile256(const unsigned short* __restrict__ gsrc,
                                     unsigned short* lds_base, int w, int l) {
  const int swz_col = ((l & 7) ^ (l >> 3)) * 8;
  const int rsub = l >> 3;
  #pragma unroll
  for (int s4 = 0; s4 < 4; ++s4) {
    int s = w * 4 + s4;
    const unsigned short* g = gsrc + (size_t)(s * 8 + rsub) * DIM + swz_col;
    __builtin_amdgcn_global_load_lds(
        (const __attribute__((address_space(1))) unsigned int*)g,
        (__attribute__((address_space(3))) unsigned int*)(lds_base + s * 512),
        16, 0, 0);
  }
}

// MFMA GEMM, 256x256 tile, 8 waves (2M x 4N), K=512 in 8 tiles of 64.
// 2-deep prefetch + COUNTED vmcnt(8): tile t+2 staged at end of iter t,
// consumed at t+2; before computing t+1 we wait only its own 8 loads
// (issued one full iter earlier) — no vmcnt(0) drain in the main loop.
// MFMA accumulation chunk order per code (k=0,32,...,480) identical to
// validated rounds 6-11. Epilogue: per-16-code-group min.
__global__ __launch_bounds__(512, 2) void gemm_groupmin(
    const unsigned short* __restrict__ ebf, const unsigned short* __restrict__ zbf,
    const float* __restrict__ esum, float* __restrict__ groupmin) {
  extern __shared__ unsigned short smem[];   // 128KB: A[2][16384] | B[2][16384]

  const int tid = threadIdx.x;
  const int cb = blockIdx.x;   // code block (8)
  const int tb = blockIdx.y;   // token block (128)
  const int w = tid >> 6, l = tid & 63;
  const int lr = l & 15, lk = l >> 4;
  const int wrow = (w >> 2) * 128;   // code side (2 waves)
  const int wcol = (w & 3) * 64;     // token side (4 waves)

  f32x4 acc[8][4];
  #pragma unroll
  for (int i = 0; i < 8; ++i)
    #pragma unroll
    for (int j = 0; j < 4; ++j) acc[i][j] = (f32x4)(0.f);

  const unsigned short* Ag = ebf + (size_t)(cb * 256) * DIM;
  const unsigned short* Bg = zbf + (size_t)(tb * 256) * DIM;

  // prologue: tile0 -> buf0, tile1 -> buf1 (tile0's 8 loads are oldest)
  stage_tile256(Ag, smem, w, l);
  stage_tile256(Bg, smem + 32768, w, l);
  stage_tile256(Ag + 64, smem + 16384, w, l);
  stage_tile256(Bg + 64, smem + 49152, w, l);
  asm volatile("s_waitcnt vmcnt(8)" ::: "memory");   // tile0 landed (per-wave)
  __syncthreads();

  for (int t = 0; t < 8; ++t) {
    const int cur = t & 1;
    const unsigned short* Ab = smem + cur * 16384;
    const unsigned short* Bb = smem + 32768 + cur * 16384;
    #pragma unroll
    for (int ks = 0; ks < 2; ++ks) {
      bf16x8 b[4];
      #pragma unroll
      for (int j = 0; j < 4; ++j) {
        int row = wcol + j * 16 + lr;
        b[j] = *(const bf16x8*)&Bb[row * 64 + (((ks * 4 + lk) ^ (lr & 7)) * 8)];
      }
      #pragma unroll
      for (int ih = 0; ih < 2; ++ih) {
        bf16x8 a[4];
        #pragma unroll
        for (int i2 = 0; i2 < 4; ++i2) {
          int row = wrow + (ih * 4 + i2) * 16 + lr;
          a[i2] = *(const bf16x8*)&Ab[row * 64 + (((ks * 4 + lk) ^ (lr & 7)) * 8)];
        }
        #pragma unroll
        for (int i2 = 0; i2 < 4; ++i2)
          #pragma unroll
          for (int j = 0; j < 4; ++j)
            acc[ih * 4 + i2][j] =
                __builtin_amdgcn_mfma_f32_16x16x32_bf16(a[i2], b[j],
                                                        acc[ih * 4 + i2][j], 0, 0, 0);
      }
    }
    __syncthreads();   // all waves done reading buf[cur]
    if (t + 2 < 8) {
      stage_tile256(Ag + (t + 2) * 64, smem + cur * 16384, w, l);
      stage_tile256(Bg + (t + 2) * 64, smem + 32768 + cur * 16384, w, l);
    }
    if (t < 7) {
      if (t + 2 < 8) {
        asm volatile("s_waitcnt vmcnt(8)" ::: "memory");   // tile t+1 landed
      } else {
        asm volatile("s_waitcnt vmcnt(0)" ::: "memory");   // t==6: tile7 landed
      }
      __syncthreads();   // publish every wave's share of tile t+1
    }
  }

  // epilogue: val = esum - 2*dot; min over q and lk -> groupmin[token][g]
  float esr[8][4];
  #pragma unroll
  for (int i = 0; i < 8; ++i)
    #pragma unroll
    for (int q = 0; q < 4; ++q)
      esr[i][q] = esum[cb * 256 + wrow + i * 16 + lk * 4 + q];

  #pragma unroll
  for (int i = 0; i < 8; ++i) {
    const int g = cb * 16 + (w >> 2) * 8 + i;
    #pragma unroll
    for (int j = 0; j < 4; ++j) {
      float v0 = fmaf(-2.f, acc[i][j][0], esr[i][0]);
      float v1 = fmaf(-2.f, acc[i][j][1], esr[i][1]);
      float v2 = fmaf(-2.f, acc[i][j][2], esr[i][2]);
      float v3 = fmaf(-2.f, acc[i][j][3], esr[i][3]);
      float m = fminf(fminf(v0, v1), fminf(v2, v3));
      m = fminf(m, __shfl_xor(m, 16));
      m = fminf(m, __shfl_xor(m, 32));
      if (lk == 0) {
        int token = tb * 256 + wcol + j * 16 + lr;
        groupmin[(size_t)token * 128 + g] = m;
      }
    }
  }
}

// One wave per token. Wave-cooperative exact rescan (validated round 11).
__global__ __launch_bounds__(256) void select_exact(
    const float* __restrict__ z, const float* __restrict__ e,
    const float* __restrict__ zsum, const float* __restrict__ esum,
    const float* __restrict__ groupmin,
    int* __restrict__ idx_final, int* __restrict__ counts,
    float* __restrict__ out) {
  const int wid = threadIdx.x >> 6;
  const int t = blockIdx.x * 4 + wid;
  const int lane = threadIdx.x & 63;
  const float* zr = z + (size_t)t * DIM;

  float4 za = *(const float4*)(zr + lane * 4);
  float4 zb = *(const float4*)(zr + 256 + lane * 4);

  float g0 = groupmin[(size_t)t * 128 + lane];
  float g1 = groupmin[(size_t)t * 128 + 64 + lane];
  float m = fminf(g0, g1);
  #pragma unroll
  for (int s = 32; s >= 1; s >>= 1) m = fminf(m, __shfl_xor(m, s));
  float lim = m + EPS;
  unsigned long long mm0 = __ballot(g0 <= lim);
  unsigned long long mm1 = __ballot(g1 <= lim);
  float zst = zsum[t];
  float bd = 3.402823466e38f; int bc = 0x7fffffff;

  #pragma unroll 1
  for (int half = 0; half < 2; ++half) {
    unsigned long long mk = half ? mm1 : mm0;
    while (mk) {
      int b = __ffsll((unsigned long long)mk) - 1;
      mk &= mk - 1;
      const int base = (half * 64 + b) * 16;
      const float* eg = e + (size_t)base * DIM;
      #pragma unroll 4
      for (int ci = 0; ci < 16; ++ci) {
        int c = base + ci;
        const float* er = eg + (size_t)ci * DIM;
        float4 ea = *(const float4*)(er + lane * 4);
        float4 eb = *(const float4*)(er + 256 + lane * 4);
        float p = 0.f;
        p = fmaf(za.x, ea.x, p); p = fmaf(za.y, ea.y, p);
        p = fmaf(za.z, ea.z, p); p = fmaf(za.w, ea.w, p);
        p = fmaf(zb.x, eb.x, p); p = fmaf(zb.y, eb.y, p);
        p = fmaf(zb.z, eb.z, p); p = fmaf(zb.w, eb.w, p);
        #pragma unroll
        for (int s = 1; s <= 32; s <<= 1) p += __shfl_xor(p, s);
        float d = (zst + esum[c]) - 2.f * p;
        if (d < bd) { bd = d; bc = c; }   // ascending c => first-index ties
      }
    }
  }
  if (lane == 0) {
    idx_final[t] = bc;
    out[IDX_OFF + t] = bfround((float)bc);
    atomicAdd(&counts[bc], 1);
  }
}

// 8 tokens/block, 32 threads/token; per-block loss partial (no atomics).
__global__ __launch_bounds__(256) void gather_loss(
    const float* __restrict__ z, const float* __restrict__ e,
    const int* __restrict__ idx_final, float* __restrict__ out,
    float* __restrict__ lossp) {
  __shared__ float red[4];
  int t = blockIdx.x * 8 + (threadIdx.x >> 5);
  int g = threadIdx.x & 31;
  int idx = idx_final[t] & (NE - 1);
  const float* zr = z + (size_t)t * DIM;
  const float* er = e + (size_t)idx * DIM;
  float* op = out + (size_t)t * DIM;
  float s = 0.f;
  #pragma unroll
  for (int p = 0; p < 4; ++p) {
    int c = p * 128 + g * 4;
    float4 ev = *(const float4*)(er + c);
    float4 zv = *(const float4*)(zr + c);
    float4 ov;
    ov.x = bfround(ev.x); ov.y = bfround(ev.y);
    ov.z = bfround(ev.z); ov.w = bfround(ev.w);
    *(float4*)(op + c) = ov;
    float dx = ev.x - zv.x, dy = ev.y - zv.y, dz2 = ev.z - zv.z, dw = ev.w - zv.w;
    s += dx*dx + dy*dy + dz2*dz2 + dw*dw;
  }
  #pragma unroll
  for (int m = 32; m >= 1; m >>= 1) s += __shfl_xor(s, m);
  if ((threadIdx.x & 63) == 0) red[threadIdx.x >> 6] = s;
  __syncthreads();
  if (threadIdx.x == 0)
    lossp[blockIdx.x] = red[0] + red[1] + red[2] + red[3];
}

__global__ void finalize_kernel(const int* __restrict__ counts,
                                const float* __restrict__ lossp,
                                float* __restrict__ out) {
  __shared__ float red[4], red2[4];
  int tid = threadIdx.x;
  float s = 0.f;
  for (int j = tid; j < NE; j += 256) {
    float p = (float)counts[j] * (1.0f / (float)N_TOK);
    s += p * logf(p + 1e-10f);
  }
  float ls = 0.f;
  for (int j = tid; j < 4096; j += 256) ls += lossp[j];
  #pragma unroll
  for (int m = 32; m >= 1; m >>= 1) {
    s += __shfl_xor(s, m);
    ls += __shfl_xor(ls, m);
  }
  if ((tid & 63) == 0) { red[tid >> 6] = s; red2[tid >> 6] = ls; }
  __syncthreads();
  if (tid == 0) {
    float tot = red[0] + red[1] + red[2] + red[3];
    float lt = red2[0] + red2[1] + red2[2] + red2[3];
    out[PERP_OFF] = bfround(expf(-tot));
    out[LOSS_OFF] = bfround(lt * 1.25f / (float)(N_TOK * DIM));
  }
}

extern "C" void kernel_launch(void* const* d_in, const int* in_sizes, int n_in,
                              void* d_out, int out_size, void* d_ws, size_t ws_size,
                              hipStream_t stream) {
  const float* z = (const float*)d_in[0];
  const float* e = (const float*)d_in[1];
  float* out = (float*)d_out;
  char* ws = (char*)d_ws;

  float*    zsum      = (float*)(ws + KB(0));      // 128 KB
  float*    esum      = (float*)(ws + KB(128));    // 8 KB
  int*      counts    = (int*)(ws + KB(136));      // 8 KB
  float*    lossp     = (float*)(ws + KB(144));    // 16 KB
  int*      idx_final = (int*)(ws + KB(160));      // 128 KB
  unsigned short* ebf = (unsigned short*)(ws + KB(288)); // 2 MB

  unsigned short* zbf = (unsigned short*)out;      // 32 MB scratch in d_out
  float* groupmin = out + 8388608;                 // 16 MB scratch in d_out

  init_kernel<<<8, 256, 0, stream>>>(counts);
  npsum_sq<<<N_TOK / 16, 256, 0, stream>>>(z, zsum, N_TOK);
  npsum_sq<<<NE / 16, 256, 0, stream>>>(e, esum, NE);
  cvt_bf<<<(NE * DIM) / (256 * 8), 256, 0, stream>>>(e, ebf);
  cvt_bf<<<(N_TOK * DIM) / (256 * 8), 256, 0, stream>>>(z, zbf);
  gemm_groupmin<<<dim3(NE / 256, N_TOK / 256), 512, 131072, stream>>>(ebf, zbf, esum, groupmin);
  select_exact<<<N_TOK / 4, 256, 0, stream>>>(z, e, zsum, esum, groupmin,
                                              idx_final, counts, out);
  gather_loss<<<N_TOK / 8, 256, 0, stream>>>(z, e, idx_final, out, lossp);
  finalize_kernel<<<1, 256, 0, stream>>>(counts, lossp, out);
}

// Round 13
// 216.440 us; speedup vs baseline: 5.4858x; 1.0399x over previous
//
#include <hip/hip_runtime.h>
#include <hip/hip_bf16.h>

#define N_TOK 32768
#define DIM   512
#define NE    2048

#define IDX_OFF  (N_TOK * DIM)
#define LOSS_OFF (IDX_OFF + N_TOK)
#define PERP_OFF (LOSS_OFF + 1)

#define KB(x) ((size_t)(x) << 10)
#define EPS 4e-4f

typedef __attribute__((ext_vector_type(8))) short bf16x8;
typedef __attribute__((ext_vector_type(4))) float f32x4;

__device__ inline unsigned short f2bf(float f) {
  unsigned int x = __float_as_uint(f);
  x = x + 0x7fffu + ((x >> 16) & 1u);
  return (unsigned short)(x >> 16);
}
__device__ inline float bfround(float f) {
  return __uint_as_float((unsigned int)f2bf(f) << 16);
}

__global__ void init_kernel(int* counts) {
  int g = blockIdx.x * 256 + threadIdx.x;
  if (g < NE) counts[g] = 0;
}

// np.sum(x*x, axis=1) exact replication (validated round 4) — do not touch.
__global__ __launch_bounds__(256) void npsum_sq(const float* __restrict__ x,
                                                float* __restrict__ out, int nrows) {
#pragma clang fp contract(off)
  int wave = threadIdx.x >> 6;
  int lane = threadIdx.x & 63;
  int grp = lane >> 4, l = lane & 15;
  int row = blockIdx.x * 16 + wave * 4 + grp;
  if (row >= nrows) return;
  const float* a = x + (size_t)row * DIM;
  float L[4];
  #pragma unroll
  for (int b = 0; b < 4; ++b) {
    const float* p = a + b * 128 + l;
    float q[8];
    #pragma unroll
    for (int j = 0; j < 8; ++j) {
      float t = p[16 * j];
      float s = t * t;
      asm volatile("" : "+v"(s));
      q[j] = s;
    }
    float v = ((q[0] + q[1]) + (q[2] + q[3])) + ((q[4] + q[5]) + (q[6] + q[7]));
    v += __shfl_xor(v, 8);
    v += __shfl_xor(v, 4);
    v += __shfl_xor(v, 2);
    v += __shfl_xor(v, 1);
    L[b] = v;
  }
  if (l == 0) out[row] = (L[0] + L[1]) + (L[2] + L[3]);
}

__global__ __launch_bounds__(256) void cvt_bf(const float* __restrict__ x,
                                              unsigned short* __restrict__ xbf) {
  size_t g = ((size_t)blockIdx.x * 256 + threadIdx.x) * 8;
  float4 a = *(const float4*)(x + g);
  float4 b = *(const float4*)(x + g + 4);
  unsigned short h[8] = {f2bf(a.x), f2bf(a.y), f2bf(a.z), f2bf(a.w),
                         f2bf(b.x), f2bf(b.y), f2bf(b.z), f2bf(b.w)};
  *(uint4*)(xbf + g) = *(uint4*)h;
}

// Stage one 128x64-bf16 half-tile (16KB) via global_load_lds width 16.
// 512 threads x 2 loads. Linear LDS dest; global src pre-swizzled with the
// validated involution (slot ^= row&7) -> swizzled ds_read conflict-free.
__device__ inline void stage_half(const unsigned short* __restrict__ gsrc,
                                  unsigned short* lds, int w, int l) {
  const int swz_col = ((l & 7) ^ (l >> 3)) * 8;
  const int rsub = l >> 3;
  #pragma unroll
  for (int s4 = 0; s4 < 2; ++s4) {
    int s = w * 2 + s4;
    const unsigned short* g = gsrc + (size_t)(s * 8 + rsub) * DIM + swz_col;
    __builtin_amdgcn_global_load_lds(
        (const __attribute__((address_space(1))) unsigned int*)g,
        (__attribute__((address_space(3))) unsigned int*)(lds + s * 512),
        16, 0, 0);
  }
}

#define BAR()   asm volatile("s_barrier" ::: "memory")
#define VMCNT4  asm volatile("s_waitcnt vmcnt(4)" ::: "memory")
#define VMCNT0  asm volatile("s_waitcnt vmcnt(0)" ::: "memory")

// 8-phase MFMA GEMM (T3+T4+T5), 256x256 tile, 8 waves (2M x 4N), BK=64,
// K=512 = 4 iters x 2 K-tiles. LDS 128KB: A[2slot][2half][128][64] | B same.
// Per phase: {ds-subtile->regs | stage 1 half-tile | s_barrier | MFMA(16) |
// s_barrier}; raw barriers (no vmcnt drain); vmcnt(4) gates only at phase
// 3/7 ends. Stage targets freed >=1 full barrier earlier (race-safe rule).
// MFMA accumulation order (k ascending per acc) identical to rounds 6-12.
__global__ __launch_bounds__(512, 2) void gemm_groupmin(
    const unsigned short* __restrict__ ebf, const unsigned short* __restrict__ zbf,
    const float* __restrict__ esum, float* __restrict__ groupmin) {
  extern __shared__ unsigned short smem[];
  unsigned short* As = smem;           // 32768 els
  unsigned short* Bs = smem + 32768;   // 32768 els

  const int tid = threadIdx.x;
  const int cb = blockIdx.x;   // code block (8)
  const int tb = blockIdx.y;   // token block (128)
  const int w = tid >> 6, l = tid & 63;
  const int lr = l & 15, lk = l >> 4;
  const int wrow = (w >> 2) * 128;   // code side (2 wave-groups)
  const int wcol = (w & 3) * 64;     // token side (4)

  f32x4 acc[8][4];
  #pragma unroll
  for (int i = 0; i < 8; ++i)
    #pragma unroll
    for (int j = 0; j < 4; ++j) acc[i][j] = (f32x4)(0.f);

  bf16x8 aR[8], bA[4], bB[4];

  const unsigned short* Ag = ebf + (size_t)(cb * 256) * DIM;
  const unsigned short* Bg = zbf + (size_t)(tb * 256) * DIM;

#define LOADA(slot, qm) do { \
  _Pragma("unroll") for (int i2 = 0; i2 < 4; ++i2) { \
    int R = wrow + (qm)*64 + i2*16 + lr; \
    int rbase = ((slot)*2 + (R>>7))*8192 + (R&127)*64; \
    aR[i2*2+0] = *(const bf16x8*)&As[rbase + (((lk    ) ^ (R&7))*8)]; \
    aR[i2*2+1] = *(const bf16x8*)&As[rbase + (((4 + lk) ^ (R&7))*8)]; \
  } } while (0)

#define LOADB(dst, slot, qn) do { \
  _Pragma("unroll") for (int j = 0; j < 2; ++j) { \
    int C = wcol + (qn)*32 + j*16 + lr; \
    int cbase = ((slot)*2 + (C>>7))*8192 + (C&127)*64; \
    dst[j*2+0] = *(const bf16x8*)&Bs[cbase + (((lk    ) ^ (C&7))*8)]; \
    dst[j*2+1] = *(const bf16x8*)&Bs[cbase + (((4 + lk) ^ (C&7))*8)]; \
  } } while (0)

#define MFMA16(qm, qn, bX) do { \
  __builtin_amdgcn_s_setprio(1); \
  _Pragma("unroll") for (int i2 = 0; i2 < 4; ++i2) \
    _Pragma("unroll") for (int j = 0; j < 2; ++j) { \
      acc[(qm)*4+i2][(qn)*2+j] = __builtin_amdgcn_mfma_f32_16x16x32_bf16( \
          aR[i2*2+0], bX[j*2+0], acc[(qm)*4+i2][(qn)*2+j], 0, 0, 0); \
      acc[(qm)*4+i2][(qn)*2+j] = __builtin_amdgcn_mfma_f32_16x16x32_bf16( \
          aR[i2*2+1], bX[j*2+1], acc[(qm)*4+i2][(qn)*2+j], 0, 0, 0); \
    } \
  __builtin_amdgcn_s_setprio(0); \
} while (0)

  // prologue: B[0,h0] B[0,h1] A[0,h0] A[0,h1] B[1,h0] B[1,h1] (12 loads)
  stage_half(Bg,                 Bs,             w, l);
  stage_half(Bg + 128 * DIM,     Bs + 8192,      w, l);
  stage_half(Ag,                 As,             w, l);
  stage_half(Ag + 128 * DIM,     As + 8192,      w, l);
  stage_half(Bg + 64,            Bs + 2 * 8192,  w, l);
  stage_half(Bg + 128 * DIM + 64, Bs + 3 * 8192, w, l);
  VMCNT4;          // tile 0 (oldest 8 loads) landed
  BAR();

  #pragma unroll
  for (int i = 0; i < 4; ++i) {
    const int t1k = (2 * i + 1) * 64;
    const int u0k = (2 * i + 2) * 64;
    const int u1k = (2 * i + 3) * 64;
    // ph0: read slot0 A(qm0), B(qn0); stage A[t1,h0] -> slot1 h0
    LOADA(0, 0); LOADB(bA, 0, 0);
    stage_half(Ag + t1k, As + 2 * 8192, w, l);
    BAR(); MFMA16(0, 0, bA); BAR();
    // ph1: read B(qn1); stage A[t1,h1]
    LOADB(bB, 0, 1);
    stage_half(Ag + 128 * DIM + t1k, As + 3 * 8192, w, l);
    BAR(); MFMA16(0, 1, bB); BAR();
    // ph2: read A(qm1); stage B[u0,h0] -> slot0 (B slot0 freed at ph1)
    LOADA(0, 1);
    if (i < 3) stage_half(Bg + u0k, Bs, w, l);
    BAR(); MFMA16(1, 0, bA); BAR();
    // ph3: stage B[u0,h1]; MFMA; gate tile t1 (4 loads newer than its last)
    if (i < 3) stage_half(Bg + 128 * DIM + u0k, Bs + 8192, w, l);
    BAR(); MFMA16(1, 1, bB);
    if (i < 3) { VMCNT4; } else { VMCNT0; }
    BAR();
    // ph4: read slot1 A(qm0), B(qn0); stage A[u0,h0] (A slot0 freed at ph2)
    LOADA(1, 0); LOADB(bA, 1, 0);
    if (i < 3) stage_half(Ag + u0k, As, w, l);
    BAR(); MFMA16(0, 0, bA); BAR();
    // ph5: read B(qn1); stage A[u0,h1]
    LOADB(bB, 1, 1);
    if (i < 3) stage_half(Ag + 128 * DIM + u0k, As + 8192, w, l);
    BAR(); MFMA16(0, 1, bB); BAR();
    // ph6: read A(qm1); stage B[u1,h0] -> slot1 (B slot1 freed at ph5)
    LOADA(1, 1);
    if (i < 3) stage_half(Bg + u1k, Bs + 2 * 8192, w, l);
    BAR(); MFMA16(1, 0, bA); BAR();
    // ph7: stage B[u1,h1]; MFMA; gate tile u0 for next iter's ph0
    if (i < 3) stage_half(Bg + 128 * DIM + u1k, Bs + 3 * 8192, w, l);
    BAR(); MFMA16(1, 1, bB);
    if (i < 3) { VMCNT4; }
    BAR();
  }

  // epilogue: val = esum - 2*dot; per-16-code-group min (same as round 12)
  float esr[8][4];
  #pragma unroll
  for (int i = 0; i < 8; ++i)
    #pragma unroll
    for (int q = 0; q < 4; ++q)
      esr[i][q] = esum[cb * 256 + wrow + i * 16 + lk * 4 + q];

  #pragma unroll
  for (int i = 0; i < 8; ++i) {
    const int g = cb * 16 + (w >> 2) * 8 + i;
    #pragma unroll
    for (int j = 0; j < 4; ++j) {
      float v0 = fmaf(-2.f, acc[i][j][0], esr[i][0]);
      float v1 = fmaf(-2.f, acc[i][j][1], esr[i][1]);
      float v2 = fmaf(-2.f, acc[i][j][2], esr[i][2]);
      float v3 = fmaf(-2.f, acc[i][j][3], esr[i][3]);
      float m = fminf(fminf(v0, v1), fminf(v2, v3));
      m = fminf(m, __shfl_xor(m, 16));
      m = fminf(m, __shfl_xor(m, 32));
      if (lk == 0) {
        int token = tb * 256 + wcol + j * 16 + lr;
        groupmin[(size_t)token * 128 + g] = m;
      }
    }
  }
#undef LOADA
#undef LOADB
#undef MFMA16
}

// One wave per token: wave-cooperative exact rescan (validated round 11).
// Adds per-block loss partial: winner bd == np-semantic ||z - zq||^2.
__global__ __launch_bounds__(256) void select_exact(
    const float* __restrict__ z, const float* __restrict__ e,
    const float* __restrict__ zsum, const float* __restrict__ esum,
    const float* __restrict__ groupmin,
    int* __restrict__ idx_final, int* __restrict__ counts,
    float* __restrict__ out, float* __restrict__ lossp) {
  __shared__ float lred[4];
  const int wid = threadIdx.x >> 6;
  const int t = blockIdx.x * 4 + wid;
  const int lane = threadIdx.x & 63;
  const float* zr = z + (size_t)t * DIM;

  float4 za = *(const float4*)(zr + lane * 4);
  float4 zb = *(const float4*)(zr + 256 + lane * 4);

  float g0 = groupmin[(size_t)t * 128 + lane];
  float g1 = groupmin[(size_t)t * 128 + 64 + lane];
  float m = fminf(g0, g1);
  #pragma unroll
  for (int s = 32; s >= 1; s >>= 1) m = fminf(m, __shfl_xor(m, s));
  float lim = m + EPS;
  unsigned long long mm0 = __ballot(g0 <= lim);
  unsigned long long mm1 = __ballot(g1 <= lim);
  float zst = zsum[t];
  float bd = 3.402823466e38f; int bc = 0x7fffffff;

  #pragma unroll 1
  for (int half = 0; half < 2; ++half) {
    unsigned long long mk = half ? mm1 : mm0;
    while (mk) {
      int b = __ffsll((unsigned long long)mk) - 1;
      mk &= mk - 1;
      const int base = (half * 64 + b) * 16;
      const float* eg = e + (size_t)base * DIM;
      #pragma unroll 4
      for (int ci = 0; ci < 16; ++ci) {
        int c = base + ci;
        const float* er = eg + (size_t)ci * DIM;
        float4 ea = *(const float4*)(er + lane * 4);
        float4 eb = *(const float4*)(er + 256 + lane * 4);
        float p = 0.f;
        p = fmaf(za.x, ea.x, p); p = fmaf(za.y, ea.y, p);
        p = fmaf(za.z, ea.z, p); p = fmaf(za.w, ea.w, p);
        p = fmaf(zb.x, eb.x, p); p = fmaf(zb.y, eb.y, p);
        p = fmaf(zb.z, eb.z, p); p = fmaf(zb.w, eb.w, p);
        #pragma unroll
        for (int s = 1; s <= 32; s <<= 1) p += __shfl_xor(p, s);
        float d = (zst + esum[c]) - 2.f * p;
        if (d < bd) { bd = d; bc = c; }   // ascending c => first-index ties
      }
    }
  }
  if (lane == 0) {
    idx_final[t] = bc;
    out[IDX_OFF + t] = bfround((float)bc);
    atomicAdd(&counts[bc], 1);
    lred[wid] = bd;
  }
  __syncthreads();
  if (threadIdx.x == 0)
    lossp[blockIdx.x] = (lred[0] + lred[1]) + (lred[2] + lred[3]);
}

// 8 tokens/block, 32 threads/token: gather e[idx] -> bf16-rounded z_q write.
__global__ __launch_bounds__(256) void scatter_zq(
    const float* __restrict__ e, const int* __restrict__ idx_final,
    float* __restrict__ out) {
  int t = blockIdx.x * 8 + (threadIdx.x >> 5);
  int g = threadIdx.x & 31;
  int idx = idx_final[t] & (NE - 1);
  const float* er = e + (size_t)idx * DIM;
  float* op = out + (size_t)t * DIM;
  #pragma unroll
  for (int p = 0; p < 4; ++p) {
    int c = p * 128 + g * 4;
    float4 ev = *(const float4*)(er + c);
    float4 ov;
    ov.x = bfround(ev.x); ov.y = bfround(ev.y);
    ov.z = bfround(ev.z); ov.w = bfround(ev.w);
    *(float4*)(op + c) = ov;
  }
}

__global__ void finalize_kernel(const int* __restrict__ counts,
                                const float* __restrict__ lossp,
                                float* __restrict__ out) {
  __shared__ float red[4], red2[4];
  int tid = threadIdx.x;
  float s = 0.f;
  for (int j = tid; j < NE; j += 256) {
    float p = (float)counts[j] * (1.0f / (float)N_TOK);
    s += p * logf(p + 1e-10f);
  }
  float ls = 0.f;
  for (int j = tid; j < N_TOK / 4; j += 256) ls += lossp[j];
  #pragma unroll
  for (int m = 32; m >= 1; m >>= 1) {
    s += __shfl_xor(s, m);
    ls += __shfl_xor(ls, m);
  }
  if ((tid & 63) == 0) { red[tid >> 6] = s; red2[tid >> 6] = ls; }
  __syncthreads();
  if (tid == 0) {
    float tot = red[0] + red[1] + red[2] + red[3];
    float lt = red2[0] + red2[1] + red2[2] + red2[3];
    out[PERP_OFF] = bfround(expf(-tot));
    out[LOSS_OFF] = bfround(lt * 1.25f / (float)(N_TOK * DIM));
  }
}

extern "C" void kernel_launch(void* const* d_in, const int* in_sizes, int n_in,
                              void* d_out, int out_size, void* d_ws, size_t ws_size,
                              hipStream_t stream) {
  const float* z = (const float*)d_in[0];
  const float* e = (const float*)d_in[1];
  float* out = (float*)d_out;
  char* ws = (char*)d_ws;

  float*    zsum      = (float*)(ws + KB(0));      // 128 KB
  float*    esum      = (float*)(ws + KB(128));    // 8 KB
  int*      counts    = (int*)(ws + KB(136));      // 8 KB
  float*    lossp     = (float*)(ws + KB(144));    // 32 KB
  int*      idx_final = (int*)(ws + KB(176));      // 128 KB
  unsigned short* ebf = (unsigned short*)(ws + KB(304)); // 2 MB

  unsigned short* zbf = (unsigned short*)out;      // 32 MB scratch in d_out
  float* groupmin = out + 8388608;                 // 16 MB scratch in d_out

  init_kernel<<<8, 256, 0, stream>>>(counts);
  npsum_sq<<<N_TOK / 16, 256, 0, stream>>>(z, zsum, N_TOK);
  npsum_sq<<<NE / 16, 256, 0, stream>>>(e, esum, NE);
  cvt_bf<<<(NE * DIM) / (256 * 8), 256, 0, stream>>>(e, ebf);
  cvt_bf<<<(N_TOK * DIM) / (256 * 8), 256, 0, stream>>>(z, zbf);
  gemm_groupmin<<<dim3(NE / 256, N_TOK / 256), 512, 131072, stream>>>(ebf, zbf, esum, groupmin);
  select_exact<<<N_TOK / 4, 256, 0, stream>>>(z, e, zsum, esum, groupmin,
                                              idx_final, counts, out, lossp);
  scatter_zq<<<N_TOK / 8, 256, 0, stream>>>(e, idx_final, out);
  finalize_kernel<<<1, 256, 0, stream>>>(counts, lossp, out);
}

// Round 14
// 206.717 us; speedup vs baseline: 5.7438x; 1.0470x over previous
//
#include <hip/hip_runtime.h>
#include <hip/hip_bf16.h>

#define N_TOK 32768
#define DIM   512
#define NE    2048

#define IDX_OFF  (N_TOK * DIM)
#define LOSS_OFF (IDX_OFF + N_TOK)
#define PERP_OFF (LOSS_OFF + 1)

#define KB(x) ((size_t)(x) << 10)
#define EPS 4e-4f

typedef __attribute__((ext_vector_type(8))) short bf16x8;
typedef __attribute__((ext_vector_type(4))) float f32x4;

__device__ inline unsigned short f2bf(float f) {
  unsigned int x = __float_as_uint(f);
  x = x + 0x7fffu + ((x >> 16) & 1u);
  return (unsigned short)(x >> 16);
}
__device__ inline float bfround(float f) {
  return __uint_as_float((unsigned int)f2bf(f) << 16);
}

__global__ void init_kernel(int* counts) {
  int g = blockIdx.x * 256 + threadIdx.x;
  if (g < NE) counts[g] = 0;
}

// np.sum(x*x, axis=1) exact replication (validated round 4) — sum path
// untouched. FUSED: also emits the bf16 copy of the block's 16 rows
// (rows are L1/L2-hot from the sum reads; kills a standalone 64MB pass).
__global__ __launch_bounds__(256) void npsum_cvt(const float* __restrict__ x,
                                                 float* __restrict__ out,
                                                 unsigned short* __restrict__ xbf,
                                                 int nrows) {
#pragma clang fp contract(off)
  int wave = threadIdx.x >> 6;
  int lane = threadIdx.x & 63;
  int grp = lane >> 4, l = lane & 15;
  int row = blockIdx.x * 16 + wave * 4 + grp;
  if (row < nrows) {
    const float* a = x + (size_t)row * DIM;
    float L[4];
    #pragma unroll
    for (int b = 0; b < 4; ++b) {
      const float* p = a + b * 128 + l;
      float q[8];
      #pragma unroll
      for (int j = 0; j < 8; ++j) {
        float t = p[16 * j];
        float s = t * t;
        asm volatile("" : "+v"(s));
        q[j] = s;
      }
      float v = ((q[0] + q[1]) + (q[2] + q[3])) + ((q[4] + q[5]) + (q[6] + q[7]));
      v += __shfl_xor(v, 8);
      v += __shfl_xor(v, 4);
      v += __shfl_xor(v, 2);
      v += __shfl_xor(v, 1);
      L[b] = v;
    }
    if (l == 0) out[row] = (L[0] + L[1]) + (L[2] + L[3]);
  }
  // fused bf16 conversion of the same 16 rows
  const float* blk = x + (size_t)blockIdx.x * 16 * DIM;
  unsigned short* ob = xbf + (size_t)blockIdx.x * 16 * DIM;
  #pragma unroll
  for (int u = 0; u < 4; ++u) {
    size_t off = (size_t)(u * 256 + threadIdx.x) * 8;
    float4 a2 = *(const float4*)(blk + off);
    float4 b2 = *(const float4*)(blk + off + 4);
    unsigned short h[8] = {f2bf(a2.x), f2bf(a2.y), f2bf(a2.z), f2bf(a2.w),
                           f2bf(b2.x), f2bf(b2.y), f2bf(b2.z), f2bf(b2.w)};
    *(uint4*)(ob + off) = *(uint4*)h;
  }
}

// Stage one 128x64-bf16 half-tile (16KB) via global_load_lds width 16.
__device__ inline void stage_half(const unsigned short* __restrict__ gsrc,
                                  unsigned short* lds, int w, int l) {
  const int swz_col = ((l & 7) ^ (l >> 3)) * 8;
  const int rsub = l >> 3;
  #pragma unroll
  for (int s4 = 0; s4 < 2; ++s4) {
    int s = w * 2 + s4;
    const unsigned short* g = gsrc + (size_t)(s * 8 + rsub) * DIM + swz_col;
    __builtin_amdgcn_global_load_lds(
        (const __attribute__((address_space(1))) unsigned int*)g,
        (__attribute__((address_space(3))) unsigned int*)(lds + s * 512),
        16, 0, 0);
  }
}

#define BAR()   asm volatile("s_barrier" ::: "memory")
#define VMCNT4  asm volatile("s_waitcnt vmcnt(4)" ::: "memory")
#define VMCNT0  asm volatile("s_waitcnt vmcnt(0)" ::: "memory")

// 8-phase MFMA GEMM (round 13 structure, unchanged numerics).
// GRID SWAPPED: blockIdx.x = token block (128), blockIdx.y = code block (8)
// -> linear id % 8 == tb % 8: all 8 cb-blocks sharing a zbf token-panel land
// on the SAME XCD; concurrent pairs share the panel in that XCD's L2
// (16 panels x 256KB = 4MB = L2). Cuts zbf refetch ~4x.
__global__ __launch_bounds__(512, 2) void gemm_groupmin(
    const unsigned short* __restrict__ ebf, const unsigned short* __restrict__ zbf,
    const float* __restrict__ esum, float* __restrict__ groupmin) {
  extern __shared__ unsigned short smem[];
  unsigned short* As = smem;           // 32768 els
  unsigned short* Bs = smem + 32768;   // 32768 els

  const int tid = threadIdx.x;
  const int tb = blockIdx.x;   // token block (128)  [swapped]
  const int cb = blockIdx.y;   // code block (8)
  const int w = tid >> 6, l = tid & 63;
  const int lr = l & 15, lk = l >> 4;
  const int wrow = (w >> 2) * 128;   // code side
  const int wcol = (w & 3) * 64;     // token side

  f32x4 acc[8][4];
  #pragma unroll
  for (int i = 0; i < 8; ++i)
    #pragma unroll
    for (int j = 0; j < 4; ++j) acc[i][j] = (f32x4)(0.f);

  bf16x8 aR[8], bA[4], bB[4];

  const unsigned short* Ag = ebf + (size_t)(cb * 256) * DIM;
  const unsigned short* Bg = zbf + (size_t)(tb * 256) * DIM;

#define LOADA(slot, qm) do { \
  _Pragma("unroll") for (int i2 = 0; i2 < 4; ++i2) { \
    int R = wrow + (qm)*64 + i2*16 + lr; \
    int rbase = ((slot)*2 + (R>>7))*8192 + (R&127)*64; \
    aR[i2*2+0] = *(const bf16x8*)&As[rbase + (((lk    ) ^ (R&7))*8)]; \
    aR[i2*2+1] = *(const bf16x8*)&As[rbase + (((4 + lk) ^ (R&7))*8)]; \
  } } while (0)

#define LOADB(dst, slot, qn) do { \
  _Pragma("unroll") for (int j = 0; j < 2; ++j) { \
    int C = wcol + (qn)*32 + j*16 + lr; \
    int cbase = ((slot)*2 + (C>>7))*8192 + (C&127)*64; \
    dst[j*2+0] = *(const bf16x8*)&Bs[cbase + (((lk    ) ^ (C&7))*8)]; \
    dst[j*2+1] = *(const bf16x8*)&Bs[cbase + (((4 + lk) ^ (C&7))*8)]; \
  } } while (0)

#define MFMA16(qm, qn, bX) do { \
  __builtin_amdgcn_s_setprio(1); \
  _Pragma("unroll") for (int i2 = 0; i2 < 4; ++i2) \
    _Pragma("unroll") for (int j = 0; j < 2; ++j) { \
      acc[(qm)*4+i2][(qn)*2+j] = __builtin_amdgcn_mfma_f32_16x16x32_bf16( \
          aR[i2*2+0], bX[j*2+0], acc[(qm)*4+i2][(qn)*2+j], 0, 0, 0); \
      acc[(qm)*4+i2][(qn)*2+j] = __builtin_amdgcn_mfma_f32_16x16x32_bf16( \
          aR[i2*2+1], bX[j*2+1], acc[(qm)*4+i2][(qn)*2+j], 0, 0, 0); \
    } \
  __builtin_amdgcn_s_setprio(0); \
} while (0)

  stage_half(Bg,                 Bs,             w, l);
  stage_half(Bg + 128 * DIM,     Bs + 8192,      w, l);
  stage_half(Ag,                 As,             w, l);
  stage_half(Ag + 128 * DIM,     As + 8192,      w, l);
  stage_half(Bg + 64,            Bs + 2 * 8192,  w, l);
  stage_half(Bg + 128 * DIM + 64, Bs + 3 * 8192, w, l);
  VMCNT4;
  BAR();

  #pragma unroll
  for (int i = 0; i < 4; ++i) {
    const int t1k = (2 * i + 1) * 64;
    const int u0k = (2 * i + 2) * 64;
    const int u1k = (2 * i + 3) * 64;
    LOADA(0, 0); LOADB(bA, 0, 0);
    stage_half(Ag + t1k, As + 2 * 8192, w, l);
    BAR(); MFMA16(0, 0, bA); BAR();
    LOADB(bB, 0, 1);
    stage_half(Ag + 128 * DIM + t1k, As + 3 * 8192, w, l);
    BAR(); MFMA16(0, 1, bB); BAR();
    LOADA(0, 1);
    if (i < 3) stage_half(Bg + u0k, Bs, w, l);
    BAR(); MFMA16(1, 0, bA); BAR();
    if (i < 3) stage_half(Bg + 128 * DIM + u0k, Bs + 8192, w, l);
    BAR(); MFMA16(1, 1, bB);
    if (i < 3) { VMCNT4; } else { VMCNT0; }
    BAR();
    LOADA(1, 0); LOADB(bA, 1, 0);
    if (i < 3) stage_half(Ag + u0k, As, w, l);
    BAR(); MFMA16(0, 0, bA); BAR();
    LOADB(bB, 1, 1);
    if (i < 3) stage_half(Ag + 128 * DIM + u0k, As + 8192, w, l);
    BAR(); MFMA16(0, 1, bB); BAR();
    LOADA(1, 1);
    if (i < 3) stage_half(Bg + u1k, Bs + 2 * 8192, w, l);
    BAR(); MFMA16(1, 0, bA); BAR();
    if (i < 3) stage_half(Bg + 128 * DIM + u1k, Bs + 3 * 8192, w, l);
    BAR(); MFMA16(1, 1, bB);
    if (i < 3) { VMCNT4; }
    BAR();
  }

  float esr[8][4];
  #pragma unroll
  for (int i = 0; i < 8; ++i)
    #pragma unroll
    for (int q = 0; q < 4; ++q)
      esr[i][q] = esum[cb * 256 + wrow + i * 16 + lk * 4 + q];

  #pragma unroll
  for (int i = 0; i < 8; ++i) {
    const int g = cb * 16 + (w >> 2) * 8 + i;
    #pragma unroll
    for (int j = 0; j < 4; ++j) {
      float v0 = fmaf(-2.f, acc[i][j][0], esr[i][0]);
      float v1 = fmaf(-2.f, acc[i][j][1], esr[i][1]);
      float v2 = fmaf(-2.f, acc[i][j][2], esr[i][2]);
      float v3 = fmaf(-2.f, acc[i][j][3], esr[i][3]);
      float m = fminf(fminf(v0, v1), fminf(v2, v3));
      m = fminf(m, __shfl_xor(m, 16));
      m = fminf(m, __shfl_xor(m, 32));
      if (lk == 0) {
        int token = tb * 256 + wcol + j * 16 + lr;
        groupmin[(size_t)token * 128 + g] = m;
      }
    }
  }
#undef LOADA
#undef LOADB
#undef MFMA16
}

// One wave per token: wave-cooperative exact rescan (validated round 11).
__global__ __launch_bounds__(256) void select_exact(
    const float* __restrict__ z, const float* __restrict__ e,
    const float* __restrict__ zsum, const float* __restrict__ esum,
    const float* __restrict__ groupmin,
    int* __restrict__ idx_final, int* __restrict__ counts,
    float* __restrict__ out, float* __restrict__ lossp) {
  __shared__ float lred[4];
  const int wid = threadIdx.x >> 6;
  const int t = blockIdx.x * 4 + wid;
  const int lane = threadIdx.x & 63;
  const float* zr = z + (size_t)t * DIM;

  float4 za = *(const float4*)(zr + lane * 4);
  float4 zb = *(const float4*)(zr + 256 + lane * 4);

  float g0 = groupmin[(size_t)t * 128 + lane];
  float g1 = groupmin[(size_t)t * 128 + 64 + lane];
  float m = fminf(g0, g1);
  #pragma unroll
  for (int s = 32; s >= 1; s >>= 1) m = fminf(m, __shfl_xor(m, s));
  float lim = m + EPS;
  unsigned long long mm0 = __ballot(g0 <= lim);
  unsigned long long mm1 = __ballot(g1 <= lim);
  float zst = zsum[t];
  float bd = 3.402823466e38f; int bc = 0x7fffffff;

  #pragma unroll 1
  for (int half = 0; half < 2; ++half) {
    unsigned long long mk = half ? mm1 : mm0;
    while (mk) {
      int b = __ffsll((unsigned long long)mk) - 1;
      mk &= mk - 1;
      const int base = (half * 64 + b) * 16;
      const float* eg = e + (size_t)base * DIM;
      #pragma unroll 4
      for (int ci = 0; ci < 16; ++ci) {
        int c = base + ci;
        const float* er = eg + (size_t)ci * DIM;
        float4 ea = *(const float4*)(er + lane * 4);
        float4 eb = *(const float4*)(er + 256 + lane * 4);
        float p = 0.f;
        p = fmaf(za.x, ea.x, p); p = fmaf(za.y, ea.y, p);
        p = fmaf(za.z, ea.z, p); p = fmaf(za.w, ea.w, p);
        p = fmaf(zb.x, eb.x, p); p = fmaf(zb.y, eb.y, p);
        p = fmaf(zb.z, eb.z, p); p = fmaf(zb.w, eb.w, p);
        #pragma unroll
        for (int s = 1; s <= 32; s <<= 1) p += __shfl_xor(p, s);
        float d = (zst + esum[c]) - 2.f * p;
        if (d < bd) { bd = d; bc = c; }
      }
    }
  }
  if (lane == 0) {
    idx_final[t] = bc;
    out[IDX_OFF + t] = bfround((float)bc);
    atomicAdd(&counts[bc], 1);
    lred[wid] = bd;
  }
  __syncthreads();
  if (threadIdx.x == 0)
    lossp[blockIdx.x] = (lred[0] + lred[1]) + (lred[2] + lred[3]);
}

// 8 tokens/block, 32 threads/token: gather e[idx] -> bf16-rounded z_q write.
__global__ __launch_bounds__(256) void scatter_zq(
    const float* __restrict__ e, const int* __restrict__ idx_final,
    float* __restrict__ out) {
  int t = blockIdx.x * 8 + (threadIdx.x >> 5);
  int g = threadIdx.x & 31;
  int idx = idx_final[t] & (NE - 1);
  const float* er = e + (size_t)idx * DIM;
  float* op = out + (size_t)t * DIM;
  #pragma unroll
  for (int p = 0; p < 4; ++p) {
    int c = p * 128 + g * 4;
    float4 ev = *(const float4*)(er + c);
    float4 ov;
    ov.x = bfround(ev.x); ov.y = bfround(ev.y);
    ov.z = bfround(ev.z); ov.w = bfround(ev.w);
    *(float4*)(op + c) = ov;
  }
}

__global__ void finalize_kernel(const int* __restrict__ counts,
                                const float* __restrict__ lossp,
                                float* __restrict__ out) {
  __shared__ float red[4], red2[4];
  int tid = threadIdx.x;
  float s = 0.f;
  for (int j = tid; j < NE; j += 256) {
    float p = (float)counts[j] * (1.0f / (float)N_TOK);
    s += p * logf(p + 1e-10f);
  }
  float ls = 0.f;
  for (int j = tid; j < N_TOK / 4; j += 256) ls += lossp[j];
  #pragma unroll
  for (int m = 32; m >= 1; m >>= 1) {
    s += __shfl_xor(s, m);
    ls += __shfl_xor(ls, m);
  }
  if ((tid & 63) == 0) { red[tid >> 6] = s; red2[tid >> 6] = ls; }
  __syncthreads();
  if (tid == 0) {
    float tot = red[0] + red[1] + red[2] + red[3];
    float lt = red2[0] + red2[1] + red2[2] + red2[3];
    out[PERP_OFF] = bfround(expf(-tot));
    out[LOSS_OFF] = bfround(lt * 1.25f / (float)(N_TOK * DIM));
  }
}

extern "C" void kernel_launch(void* const* d_in, const int* in_sizes, int n_in,
                              void* d_out, int out_size, void* d_ws, size_t ws_size,
                              hipStream_t stream) {
  const float* z = (const float*)d_in[0];
  const float* e = (const float*)d_in[1];
  float* out = (float*)d_out;
  char* ws = (char*)d_ws;

  float*    zsum      = (float*)(ws + KB(0));      // 128 KB
  float*    esum      = (float*)(ws + KB(128));    // 8 KB
  int*      counts    = (int*)(ws + KB(136));      // 8 KB
  float*    lossp     = (float*)(ws + KB(144));    // 32 KB
  int*      idx_final = (int*)(ws + KB(176));      // 128 KB
  unsigned short* ebf = (unsigned short*)(ws + KB(304)); // 2 MB

  unsigned short* zbf = (unsigned short*)out;      // 32 MB scratch in d_out
  float* groupmin = out + 8388608;                 // 16 MB scratch in d_out

  init_kernel<<<8, 256, 0, stream>>>(counts);
  npsum_cvt<<<N_TOK / 16, 256, 0, stream>>>(z, zsum, zbf, N_TOK);
  npsum_cvt<<<NE / 16, 256, 0, stream>>>(e, esum, ebf, NE);
  gemm_groupmin<<<dim3(N_TOK / 256, NE / 256), 512, 131072, stream>>>(ebf, zbf, esum, groupmin);
  select_exact<<<N_TOK / 4, 256, 0, stream>>>(z, e, zsum, esum, groupmin,
                                              idx_final, counts, out, lossp);
  scatter_zq<<<N_TOK / 8, 256, 0, stream>>>(e, idx_final, out);
  finalize_kernel<<<1, 256, 0, stream>>>(counts, lossp, out);
}

// Round 15
// 206.664 us; speedup vs baseline: 5.7453x; 1.0003x over previous
//
#include <hip/hip_runtime.h>
#include <hip/hip_bf16.h>

#define N_TOK 32768
#define DIM   512
#define NE    2048

#define IDX_OFF  (N_TOK * DIM)
#define LOSS_OFF (IDX_OFF + N_TOK)
#define PERP_OFF (LOSS_OFF + 1)

#define KB(x) ((size_t)(x) << 10)
#define EPS 4e-4f

typedef __attribute__((ext_vector_type(8))) short bf16x8;
typedef __attribute__((ext_vector_type(4))) float f32x4;

__device__ inline unsigned short f2bf(float f) {
  unsigned int x = __float_as_uint(f);
  x = x + 0x7fffu + ((x >> 16) & 1u);
  return (unsigned short)(x >> 16);
}
__device__ inline float bfround(float f) {
  return __uint_as_float((unsigned int)f2bf(f) << 16);
}

__global__ void init_kernel(int* counts) {
  int g = blockIdx.x * 256 + threadIdx.x;
  if (g < NE) counts[g] = 0;
}

// np.sum(x*x, axis=1) exact replication (validated round 4) — sum path
// untouched. FUSED: also emits the bf16 copy of the block's 16 rows.
__global__ __launch_bounds__(256) void npsum_cvt(const float* __restrict__ x,
                                                 float* __restrict__ out,
                                                 unsigned short* __restrict__ xbf,
                                                 int nrows) {
#pragma clang fp contract(off)
  int wave = threadIdx.x >> 6;
  int lane = threadIdx.x & 63;
  int grp = lane >> 4, l = lane & 15;
  int row = blockIdx.x * 16 + wave * 4 + grp;
  if (row < nrows) {
    const float* a = x + (size_t)row * DIM;
    float L[4];
    #pragma unroll
    for (int b = 0; b < 4; ++b) {
      const float* p = a + b * 128 + l;
      float q[8];
      #pragma unroll
      for (int j = 0; j < 8; ++j) {
        float t = p[16 * j];
        float s = t * t;
        asm volatile("" : "+v"(s));
        q[j] = s;
      }
      float v = ((q[0] + q[1]) + (q[2] + q[3])) + ((q[4] + q[5]) + (q[6] + q[7]));
      v += __shfl_xor(v, 8);
      v += __shfl_xor(v, 4);
      v += __shfl_xor(v, 2);
      v += __shfl_xor(v, 1);
      L[b] = v;
    }
    if (l == 0) out[row] = (L[0] + L[1]) + (L[2] + L[3]);
  }
  const float* blk = x + (size_t)blockIdx.x * 16 * DIM;
  unsigned short* ob = xbf + (size_t)blockIdx.x * 16 * DIM;
  #pragma unroll
  for (int u = 0; u < 4; ++u) {
    size_t off = (size_t)(u * 256 + threadIdx.x) * 8;
    float4 a2 = *(const float4*)(blk + off);
    float4 b2 = *(const float4*)(blk + off + 4);
    unsigned short h[8] = {f2bf(a2.x), f2bf(a2.y), f2bf(a2.z), f2bf(a2.w),
                           f2bf(b2.x), f2bf(b2.y), f2bf(b2.z), f2bf(b2.w)};
    *(uint4*)(ob + off) = *(uint4*)h;
  }
}

// Stage one 128x64-bf16 half-tile (16KB) via global_load_lds width 16.
__device__ inline void stage_half(const unsigned short* __restrict__ gsrc,
                                  unsigned short* lds, int w, int l) {
  const int swz_col = ((l & 7) ^ (l >> 3)) * 8;
  const int rsub = l >> 3;
  #pragma unroll
  for (int s4 = 0; s4 < 2; ++s4) {
    int s = w * 2 + s4;
    const unsigned short* g = gsrc + (size_t)(s * 8 + rsub) * DIM + swz_col;
    __builtin_amdgcn_global_load_lds(
        (const __attribute__((address_space(1))) unsigned int*)g,
        (__attribute__((address_space(3))) unsigned int*)(lds + s * 512),
        16, 0, 0);
  }
}

#define BAR()   asm volatile("s_barrier" ::: "memory")
#define VMCNT4  asm volatile("s_waitcnt vmcnt(4)" ::: "memory")
#define VMCNT0  asm volatile("s_waitcnt vmcnt(0)" ::: "memory")

// 8-phase MFMA GEMM, barrier-reduced (round 15):
// - bB loaded EARLY (ph0/ph4) so every stage targets a slot last-read >=2
//   phases back -> single barrier per phase is race-free (all waves passing
//   BAR(p-1) have issued MFMA(p-2) incl. its lgkm wait => reads complete).
// - Double barrier kept ONLY at ph3/ph7 (vmcnt publication points).
// Barriers/iter: 16 -> 10. Numerics/accumulation order identical to R13/14.
__global__ __launch_bounds__(512, 2) void gemm_groupmin(
    const unsigned short* __restrict__ ebf, const unsigned short* __restrict__ zbf,
    const float* __restrict__ esum, float* __restrict__ groupmin) {
  extern __shared__ unsigned short smem[];
  unsigned short* As = smem;           // 32768 els
  unsigned short* Bs = smem + 32768;   // 32768 els

  const int tid = threadIdx.x;
  const int tb = blockIdx.x;   // token block (128) — XCD-swizzled grid
  const int cb = blockIdx.y;   // code block (8)
  const int w = tid >> 6, l = tid & 63;
  const int lr = l & 15, lk = l >> 4;
  const int wrow = (w >> 2) * 128;
  const int wcol = (w & 3) * 64;

  f32x4 acc[8][4];
  #pragma unroll
  for (int i = 0; i < 8; ++i)
    #pragma unroll
    for (int j = 0; j < 4; ++j) acc[i][j] = (f32x4)(0.f);

  bf16x8 aR[8], bA[4], bB[4];

  const unsigned short* Ag = ebf + (size_t)(cb * 256) * DIM;
  const unsigned short* Bg = zbf + (size_t)(tb * 256) * DIM;

#define LOADA(slot, qm) do { \
  _Pragma("unroll") for (int i2 = 0; i2 < 4; ++i2) { \
    int R = wrow + (qm)*64 + i2*16 + lr; \
    int rbase = ((slot)*2 + (R>>7))*8192 + (R&127)*64; \
    aR[i2*2+0] = *(const bf16x8*)&As[rbase + (((lk    ) ^ (R&7))*8)]; \
    aR[i2*2+1] = *(const bf16x8*)&As[rbase + (((4 + lk) ^ (R&7))*8)]; \
  } } while (0)

#define LOADB(dst, slot, qn) do { \
  _Pragma("unroll") for (int j = 0; j < 2; ++j) { \
    int C = wcol + (qn)*32 + j*16 + lr; \
    int cbase = ((slot)*2 + (C>>7))*8192 + (C&127)*64; \
    dst[j*2+0] = *(const bf16x8*)&Bs[cbase + (((lk    ) ^ (C&7))*8)]; \
    dst[j*2+1] = *(const bf16x8*)&Bs[cbase + (((4 + lk) ^ (C&7))*8)]; \
  } } while (0)

#define MFMA16(qm, qn, bX) do { \
  __builtin_amdgcn_s_setprio(1); \
  _Pragma("unroll") for (int i2 = 0; i2 < 4; ++i2) \
    _Pragma("unroll") for (int j = 0; j < 2; ++j) { \
      acc[(qm)*4+i2][(qn)*2+j] = __builtin_amdgcn_mfma_f32_16x16x32_bf16( \
          aR[i2*2+0], bX[j*2+0], acc[(qm)*4+i2][(qn)*2+j], 0, 0, 0); \
      acc[(qm)*4+i2][(qn)*2+j] = __builtin_amdgcn_mfma_f32_16x16x32_bf16( \
          aR[i2*2+1], bX[j*2+1], acc[(qm)*4+i2][(qn)*2+j], 0, 0, 0); \
    } \
  __builtin_amdgcn_s_setprio(0); \
} while (0)

  // prologue: B[0] (2 halves), A[0] (2 halves), B[1] (2 halves) = 12 loads
  stage_half(Bg,                 Bs,             w, l);
  stage_half(Bg + 128 * DIM,     Bs + 8192,      w, l);
  stage_half(Ag,                 As,             w, l);
  stage_half(Ag + 128 * DIM,     As + 8192,      w, l);
  stage_half(Bg + 64,            Bs + 2 * 8192,  w, l);
  stage_half(Bg + 128 * DIM + 64, Bs + 3 * 8192, w, l);
  VMCNT4;   // tile0 (oldest 8) landed
  BAR();

  #pragma unroll
  for (int i = 0; i < 4; ++i) {
    const int t1k = (2 * i + 1) * 64;
    const int u0k = (2 * i + 2) * 64;
    const int u1k = (2 * i + 3) * 64;
    // ph0: all slot0 reads for qm0 + BOTH B quads; stage A[t1]h0 (dist 2)
    LOADA(0, 0); LOADB(bA, 0, 0); LOADB(bB, 0, 1);
    stage_half(Ag + t1k, As + 2 * 8192, w, l);
    BAR(); MFMA16(0, 0, bA);
    // ph1: stage A[t1]h1 (dist 3)
    stage_half(Ag + 128 * DIM + t1k, As + 3 * 8192, w, l);
    BAR(); MFMA16(0, 1, bB);
    // ph2: read A qm1; stage B[u0]h0 (Bs slot0 last read ph0 -> dist 2)
    LOADA(0, 1);
    if (i < 3) stage_half(Bg + u0k, Bs, w, l);
    BAR(); MFMA16(1, 0, bA);
    // ph3: stage B[u0]h1 (dist 3); publication point for tile t1
    if (i < 3) stage_half(Bg + 128 * DIM + u0k, Bs + 8192, w, l);
    BAR(); MFMA16(1, 1, bB);
    if (i < 3) { VMCNT4; } else { VMCNT0; }
    BAR();
    // ph4: slot1 reads qm0 + both B quads; stage A[u0]h0 (dist 2)
    LOADA(1, 0); LOADB(bA, 1, 0); LOADB(bB, 1, 1);
    if (i < 3) stage_half(Ag + u0k, As, w, l);
    BAR(); MFMA16(0, 0, bA);
    // ph5: stage A[u0]h1 (dist 3)
    if (i < 3) stage_half(Ag + 128 * DIM + u0k, As + 8192, w, l);
    BAR(); MFMA16(0, 1, bB);
    // ph6: read A qm1; stage B[u1]h0 (Bs slot1 last read ph4 -> dist 2)
    LOADA(1, 1);
    if (i < 3) stage_half(Bg + u1k, Bs + 2 * 8192, w, l);
    BAR(); MFMA16(1, 0, bA);
    // ph7: stage B[u1]h1 (dist 3); publication point for tile u0
    if (i < 3) stage_half(Bg + 128 * DIM + u1k, Bs + 3 * 8192, w, l);
    BAR(); MFMA16(1, 1, bB);
    if (i < 3) { VMCNT4; BAR(); }
  }

  float esr[8][4];
  #pragma unroll
  for (int i = 0; i < 8; ++i)
    #pragma unroll
    for (int q = 0; q < 4; ++q)
      esr[i][q] = esum[cb * 256 + wrow + i * 16 + lk * 4 + q];

  #pragma unroll
  for (int i = 0; i < 8; ++i) {
    const int g = cb * 16 + (w >> 2) * 8 + i;
    #pragma unroll
    for (int j = 0; j < 4; ++j) {
      float v0 = fmaf(-2.f, acc[i][j][0], esr[i][0]);
      float v1 = fmaf(-2.f, acc[i][j][1], esr[i][1]);
      float v2 = fmaf(-2.f, acc[i][j][2], esr[i][2]);
      float v3 = fmaf(-2.f, acc[i][j][3], esr[i][3]);
      float m = fminf(fminf(v0, v1), fminf(v2, v3));
      m = fminf(m, __shfl_xor(m, 16));
      m = fminf(m, __shfl_xor(m, 32));
      if (lk == 0) {
        int token = tb * 256 + wcol + j * 16 + lr;
        groupmin[(size_t)token * 128 + g] = m;
      }
    }
  }
#undef LOADA
#undef LOADB
#undef MFMA16
}

// One wave per token: wave-cooperative exact rescan (validated round 11).
__global__ __launch_bounds__(256) void select_exact(
    const float* __restrict__ z, const float* __restrict__ e,
    const float* __restrict__ zsum, const float* __restrict__ esum,
    const float* __restrict__ groupmin,
    int* __restrict__ idx_final, int* __restrict__ counts,
    float* __restrict__ out, float* __restrict__ lossp) {
  __shared__ float lred[4];
  const int wid = threadIdx.x >> 6;
  const int t = blockIdx.x * 4 + wid;
  const int lane = threadIdx.x & 63;
  const float* zr = z + (size_t)t * DIM;

  float4 za = *(const float4*)(zr + lane * 4);
  float4 zb = *(const float4*)(zr + 256 + lane * 4);

  float g0 = groupmin[(size_t)t * 128 + lane];
  float g1 = groupmin[(size_t)t * 128 + 64 + lane];
  float m = fminf(g0, g1);
  #pragma unroll
  for (int s = 32; s >= 1; s >>= 1) m = fminf(m, __shfl_xor(m, s));
  float lim = m + EPS;
  unsigned long long mm0 = __ballot(g0 <= lim);
  unsigned long long mm1 = __ballot(g1 <= lim);
  float zst = zsum[t];
  float bd = 3.402823466e38f; int bc = 0x7fffffff;

  #pragma unroll 1
  for (int half = 0; half < 2; ++half) {
    unsigned long long mk = half ? mm1 : mm0;
    while (mk) {
      int b = __ffsll((unsigned long long)mk) - 1;
      mk &= mk - 1;
      const int base = (half * 64 + b) * 16;
      const float* eg = e + (size_t)base * DIM;
      #pragma unroll 4
      for (int ci = 0; ci < 16; ++ci) {
        int c = base + ci;
        const float* er = eg + (size_t)ci * DIM;
        float4 ea = *(const float4*)(er + lane * 4);
        float4 eb = *(const float4*)(er + 256 + lane * 4);
        float p = 0.f;
        p = fmaf(za.x, ea.x, p); p = fmaf(za.y, ea.y, p);
        p = fmaf(za.z, ea.z, p); p = fmaf(za.w, ea.w, p);
        p = fmaf(zb.x, eb.x, p); p = fmaf(zb.y, eb.y, p);
        p = fmaf(zb.z, eb.z, p); p = fmaf(zb.w, eb.w, p);
        #pragma unroll
        for (int s = 1; s <= 32; s <<= 1) p += __shfl_xor(p, s);
        float d = (zst + esum[c]) - 2.f * p;
        if (d < bd) { bd = d; bc = c; }
      }
    }
  }
  if (lane == 0) {
    idx_final[t] = bc;
    out[IDX_OFF + t] = bfround((float)bc);
    atomicAdd(&counts[bc], 1);
    lred[wid] = bd;
  }
  __syncthreads();
  if (threadIdx.x == 0)
    lossp[blockIdx.x] = (lred[0] + lred[1]) + (lred[2] + lred[3]);
}

// 8 tokens/block, 32 threads/token: gather e[idx] -> bf16-rounded z_q write.
__global__ __launch_bounds__(256) void scatter_zq(
    const float* __restrict__ e, const int* __restrict__ idx_final,
    float* __restrict__ out) {
  int t = blockIdx.x * 8 + (threadIdx.x >> 5);
  int g = threadIdx.x & 31;
  int idx = idx_final[t] & (NE - 1);
  const float* er = e + (size_t)idx * DIM;
  float* op = out + (size_t)t * DIM;
  #pragma unroll
  for (int p = 0; p < 4; ++p) {
    int c = p * 128 + g * 4;
    float4 ev = *(const float4*)(er + c);
    float4 ov;
    ov.x = bfround(ev.x); ov.y = bfround(ev.y);
    ov.z = bfround(ev.z); ov.w = bfround(ev.w);
    *(float4*)(op + c) = ov;
  }
}

__global__ void finalize_kernel(const int* __restrict__ counts,
                                const float* __restrict__ lossp,
                                float* __restrict__ out) {
  __shared__ float red[4], red2[4];
  int tid = threadIdx.x;
  float s = 0.f;
  for (int j = tid; j < NE; j += 256) {
    float p = (float)counts[j] * (1.0f / (float)N_TOK);
    s += p * logf(p + 1e-10f);
  }
  float ls = 0.f;
  for (int j = tid; j < N_TOK / 4; j += 256) ls += lossp[j];
  #pragma unroll
  for (int m = 32; m >= 1; m >>= 1) {
    s += __shfl_xor(s, m);
    ls += __shfl_xor(ls, m);
  }
  if ((tid & 63) == 0) { red[tid >> 6] = s; red2[tid >> 6] = ls; }
  __syncthreads();
  if (tid == 0) {
    float tot = red[0] + red[1] + red[2] + red[3];
    float lt = red2[0] + red2[1] + red2[2] + red2[3];
    out[PERP_OFF] = bfround(expf(-tot));
    out[LOSS_OFF] = bfround(lt * 1.25f / (float)(N_TOK * DIM));
  }
}

extern "C" void kernel_launch(void* const* d_in, const int* in_sizes, int n_in,
                              void* d_out, int out_size, void* d_ws, size_t ws_size,
                              hipStream_t stream) {
  const float* z = (const float*)d_in[0];
  const float* e = (const float*)d_in[1];
  float* out = (float*)d_out;
  char* ws = (char*)d_ws;

  float*    zsum      = (float*)(ws + KB(0));      // 128 KB
  float*    esum      = (float*)(ws + KB(128));    // 8 KB
  int*      counts    = (int*)(ws + KB(136));      // 8 KB
  float*    lossp     = (float*)(ws + KB(144));    // 32 KB
  int*      idx_final = (int*)(ws + KB(176));      // 128 KB
  unsigned short* ebf = (unsigned short*)(ws + KB(304)); // 2 MB

  unsigned short* zbf = (unsigned short*)out;      // 32 MB scratch in d_out
  float* groupmin = out + 8388608;                 // 16 MB scratch in d_out

  init_kernel<<<8, 256, 0, stream>>>(counts);
  npsum_cvt<<<N_TOK / 16, 256, 0, stream>>>(z, zsum, zbf, N_TOK);
  npsum_cvt<<<NE / 16, 256, 0, stream>>>(e, esum, ebf, NE);
  gemm_groupmin<<<dim3(N_TOK / 256, NE / 256), 512, 131072, stream>>>(ebf, zbf, esum, groupmin);
  select_exact<<<N_TOK / 4, 256, 0, stream>>>(z, e, zsum, esum, groupmin,
                                              idx_final, counts, out, lossp);
  scatter_zq<<<N_TOK / 8, 256, 0, stream>>>(e, idx_final, out);
  finalize_kernel<<<1, 256, 0, stream>>>(counts, lossp, out);
}

// Round 17
// 206.531 us; speedup vs baseline: 5.7490x; 1.0006x over previous
//
#include <hip/hip_runtime.h>
#include <hip/hip_bf16.h>

#define N_TOK 32768
#define DIM   512
#define NE    2048

#define IDX_OFF  (N_TOK * DIM)
#define LOSS_OFF (IDX_OFF + N_TOK)
#define PERP_OFF (LOSS_OFF + 1)

#define KB(x) ((size_t)(x) << 10)
#define EPS 4e-4f

typedef __attribute__((ext_vector_type(8))) short bf16x8;
typedef __attribute__((ext_vector_type(4))) float f32x4;

__device__ inline unsigned short f2bf(float f) {
  unsigned int x = __float_as_uint(f);
  x = x + 0x7fffu + ((x >> 16) & 1u);
  return (unsigned short)(x >> 16);
}
__device__ inline float bfround(float f) {
  return __uint_as_float((unsigned int)f2bf(f) << 16);
}

// Combined: np.sum(x*x) exact replication (validated round 4 — sum chain
// untouched) + fused bf16 conversion, for BOTH z (blocks 0..2047) and e
// (blocks 2048..2175). Blocks 0..7 also zero counts.
__global__ __launch_bounds__(256) void npsum_cvt_all(
    const float* __restrict__ z, const float* __restrict__ e,
    float* __restrict__ zsum, float* __restrict__ esum,
    unsigned short* __restrict__ zbf, unsigned short* __restrict__ ebf,
    int* __restrict__ counts) {
#pragma clang fp contract(off)
  const int bz = blockIdx.x;
  if (bz < 8) counts[bz * 256 + threadIdx.x] = 0;
  const bool isz = bz < (N_TOK / 16);
  const int blk = isz ? bz : bz - (N_TOK / 16);
  const float* x = isz ? z : e;
  float* outs = isz ? zsum : esum;
  unsigned short* xbf = isz ? zbf : ebf;

  int wave = threadIdx.x >> 6;
  int lane = threadIdx.x & 63;
  int grp = lane >> 4, l = lane & 15;
  int row = blk * 16 + wave * 4 + grp;
  {
    const float* a = x + (size_t)row * DIM;
    float L[4];
    #pragma unroll
    for (int b = 0; b < 4; ++b) {
      const float* p = a + b * 128 + l;
      float q[8];
      #pragma unroll
      for (int j = 0; j < 8; ++j) {
        float t = p[16 * j];
        float s = t * t;
        asm volatile("" : "+v"(s));
        q[j] = s;
      }
      float v = ((q[0] + q[1]) + (q[2] + q[3])) + ((q[4] + q[5]) + (q[6] + q[7]));
      v += __shfl_xor(v, 8);
      v += __shfl_xor(v, 4);
      v += __shfl_xor(v, 2);
      v += __shfl_xor(v, 1);
      L[b] = v;
    }
    if (l == 0) outs[row] = (L[0] + L[1]) + (L[2] + L[3]);
  }
  const float* blkp = x + (size_t)blk * 16 * DIM;
  unsigned short* ob = xbf + (size_t)blk * 16 * DIM;
  #pragma unroll
  for (int u = 0; u < 4; ++u) {
    size_t off = (size_t)(u * 256 + threadIdx.x) * 8;
    float4 a2 = *(const float4*)(blkp + off);
    float4 b2 = *(const float4*)(blkp + off + 4);
    unsigned short h[8] = {f2bf(a2.x), f2bf(a2.y), f2bf(a2.z), f2bf(a2.w),
                           f2bf(b2.x), f2bf(b2.y), f2bf(b2.z), f2bf(b2.w)};
    *(uint4*)(ob + off) = *(uint4*)h;
  }
}

#define BAR()   asm volatile("s_barrier" ::: "memory")
#define VMCNT3  asm volatile("s_waitcnt vmcnt(3)" ::: "memory")
#define VMCNT0  asm volatile("s_waitcnt vmcnt(0)" ::: "memory")

// Line-paired LDS layout (round 16): K-tile (R rows x 32 k) stored as R/2
// lines of 64 els; line L holds rows 2L,2L+1; chunk swizzle p = q ^ (L&7),
// q>>2 = row parity, q&3 = k-chunk. LDS dest linear (wave-uniform base +
// lane*16B per global_load_lds HW rule); global source carries the swizzle.
__device__ inline void stage_chunk(const unsigned short* __restrict__ gbase,
                                   unsigned short* lds, int c, int ktofs) {
  int L = c >> 3, p = c & 7, q = p ^ (L & 7);
  int row = 2 * L + (q >> 2), kc = q & 3;
  const unsigned short* g = gbase + (size_t)row * DIM + ktofs + kc * 8;
  __builtin_amdgcn_global_load_lds(
      (const __attribute__((address_space(1))) unsigned int*)g,
      (__attribute__((address_space(3))) unsigned int*)(lds + c * 8),
      16, 0, 0);
}

// MFMA GEMM v2: 256 codes x 128 tokens per block, 8 waves of 64x64 tiles
// (acc=64 VGPR -> 2 blocks/CU), BK=32, double-buffered 48KB LDS, counted
// vmcnt(3), setprio. Per-acc accumulation sequence (16 x mfma_16x16x32,
// k ascending) bit-identical to rounds 6-15.
__global__ __launch_bounds__(512, 4) void gemm_groupmin(
    const unsigned short* __restrict__ ebf, const unsigned short* __restrict__ zbf,
    const float* __restrict__ esum, float* __restrict__ groupmin) {
  extern __shared__ unsigned short smem[];
  unsigned short* As = smem;            // 2 slots x 8192 els
  unsigned short* Bs = smem + 16384;    // 2 slots x 4096 els

  const int tid = threadIdx.x;
  const int tb = blockIdx.x;   // token block (256; %8 fixes XCD)
  const int cb = blockIdx.y;   // code block (8)
  const int w = tid >> 6, l = tid & 63;
  const int lr = l & 15, lk = l >> 4;
  const int wrow = (w >> 1) * 64;   // code side (4 groups)
  const int wcol = (w & 1) * 64;    // token side (2 groups)

  f32x4 acc[4][4];
  #pragma unroll
  for (int i = 0; i < 4; ++i)
    #pragma unroll
    for (int j = 0; j < 4; ++j) acc[i][j] = (f32x4)(0.f);

  const unsigned short* Ag = ebf + (size_t)(cb * 256) * DIM;
  const unsigned short* Bg = zbf + (size_t)(tb * 128) * DIM;

  const int ca0 = tid, ca1 = tid + 512, cb0 = tid;

#define STAGE(slot, t) do { \
  stage_chunk(Ag, As + (slot) * 8192, ca0, (t) * 32); \
  stage_chunk(Ag, As + (slot) * 8192, ca1, (t) * 32); \
  stage_chunk(Bg, Bs + (slot) * 4096, cb0, (t) * 32); \
} while (0)

  STAGE(0, 0);
  STAGE(1, 1);
  VMCNT3;   // tile0's 3 loads landed
  BAR();

  #pragma unroll 2
  for (int t = 0; t < 16; ++t) {
    const int cur = t & 1;
    const unsigned short* Ab = As + cur * 8192;
    const unsigned short* Bb = Bs + cur * 4096;
    bf16x8 aR[4], bB[4];
    #pragma unroll
    for (int i2 = 0; i2 < 4; ++i2) {
      int R = wrow + i2 * 16 + lr;
      int p = ((R & 1) * 4 + lk) ^ ((R >> 1) & 7);
      aR[i2] = *(const bf16x8*)&Ab[(R >> 1) * 64 + p * 8];
    }
    #pragma unroll
    for (int j = 0; j < 4; ++j) {
      int C = wcol + j * 16 + lr;
      int p = ((C & 1) * 4 + lk) ^ ((C >> 1) & 7);
      bB[j] = *(const bf16x8*)&Bb[(C >> 1) * 64 + p * 8];
    }
    __builtin_amdgcn_s_setprio(1);
    #pragma unroll
    for (int i2 = 0; i2 < 4; ++i2)
      #pragma unroll
      for (int j = 0; j < 4; ++j)
        acc[i2][j] = __builtin_amdgcn_mfma_f32_16x16x32_bf16(aR[i2], bB[j],
                                                             acc[i2][j], 0, 0, 0);
    __builtin_amdgcn_s_setprio(0);
    BAR();   // all waves done reading buf[cur]
    if (t + 2 < 16) STAGE(cur, t + 2);
    if (t < 15) {
      if (t + 2 < 16) { VMCNT3; } else { VMCNT0; }
      BAR();
    }
  }
#undef STAGE

  float esr[4][4];
  #pragma unroll
  for (int i = 0; i < 4; ++i)
    #pragma unroll
    for (int q = 0; q < 4; ++q)
      esr[i][q] = esum[cb * 256 + wrow + i * 16 + lk * 4 + q];

  #pragma unroll
  for (int i = 0; i < 4; ++i) {
    const int g = cb * 16 + (wrow >> 4) + i;
    #pragma unroll
    for (int j = 0; j < 4; ++j) {
      float v0 = fmaf(-2.f, acc[i][j][0], esr[i][0]);
      float v1 = fmaf(-2.f, acc[i][j][1], esr[i][1]);
      float v2 = fmaf(-2.f, acc[i][j][2], esr[i][2]);
      float v3 = fmaf(-2.f, acc[i][j][3], esr[i][3]);
      float m = fminf(fminf(v0, v1), fminf(v2, v3));
      m = fminf(m, __shfl_xor(m, 16));
      m = fminf(m, __shfl_xor(m, 32));
      if (lk == 0) {
        int token = tb * 128 + wcol + j * 16 + lr;
        groupmin[(size_t)token * 128 + g] = m;
      }
    }
  }
}

// One wave per token: wave-cooperative exact rescan (validated round 11).
// NOT fused with z_q write: groupmin lives in d_out's z_q region, so the
// z_q store must happen strictly after ALL blocks' groupmin reads (R16 bug).
__global__ __launch_bounds__(256) void select_exact(
    const float* __restrict__ z, const float* __restrict__ e,
    const float* __restrict__ zsum, const float* __restrict__ esum,
    const float* __restrict__ groupmin,
    int* __restrict__ idx_final, int* __restrict__ counts,
    float* __restrict__ out, float* __restrict__ lossp) {
  __shared__ float lred[4];
  const int wid = threadIdx.x >> 6;
  const int t = blockIdx.x * 4 + wid;
  const int lane = threadIdx.x & 63;
  const float* zr = z + (size_t)t * DIM;

  float4 za = *(const float4*)(zr + lane * 4);
  float4 zb = *(const float4*)(zr + 256 + lane * 4);

  float g0 = groupmin[(size_t)t * 128 + lane];
  float g1 = groupmin[(size_t)t * 128 + 64 + lane];
  float m = fminf(g0, g1);
  #pragma unroll
  for (int s = 32; s >= 1; s >>= 1) m = fminf(m, __shfl_xor(m, s));
  float lim = m + EPS;
  unsigned long long mm0 = __ballot(g0 <= lim);
  unsigned long long mm1 = __ballot(g1 <= lim);
  float zst = zsum[t];
  float bd = 3.402823466e38f; int bc = 0x7fffffff;

  #pragma unroll 1
  for (int half = 0; half < 2; ++half) {
    unsigned long long mk = half ? mm1 : mm0;
    while (mk) {
      int b = __ffsll((unsigned long long)mk) - 1;
      mk &= mk - 1;
      const int base = (half * 64 + b) * 16;
      const float* eg = e + (size_t)base * DIM;
      #pragma unroll 4
      for (int ci = 0; ci < 16; ++ci) {
        int c = base + ci;
        const float* er = eg + (size_t)ci * DIM;
        float4 ea = *(const float4*)(er + lane * 4);
        float4 eb = *(const float4*)(er + 256 + lane * 4);
        float p = 0.f;
        p = fmaf(za.x, ea.x, p); p = fmaf(za.y, ea.y, p);
        p = fmaf(za.z, ea.z, p); p = fmaf(za.w, ea.w, p);
        p = fmaf(zb.x, eb.x, p); p = fmaf(zb.y, eb.y, p);
        p = fmaf(zb.z, eb.z, p); p = fmaf(zb.w, eb.w, p);
        #pragma unroll
        for (int s = 1; s <= 32; s <<= 1) p += __shfl_xor(p, s);
        float d = (zst + esum[c]) - 2.f * p;
        if (d < bd) { bd = d; bc = c; }   // ascending c => first-index ties
      }
    }
  }
  if (lane == 0) {
    idx_final[t] = bc;
    out[IDX_OFF + t] = bfround((float)bc);
    atomicAdd(&counts[bc], 1);
    lred[wid] = bd;
  }
  __syncthreads();
  if (threadIdx.x == 0)
    lossp[blockIdx.x] = (lred[0] + lred[1]) + (lred[2] + lred[3]);
}

// 8 tokens/block, 32 threads/token: gather e[idx] -> bf16-rounded z_q write.
// Runs after select_exact; may freely overwrite the groupmin scratch region.
__global__ __launch_bounds__(256) void scatter_zq(
    const float* __restrict__ e, const int* __restrict__ idx_final,
    float* __restrict__ out) {
  int t = blockIdx.x * 8 + (threadIdx.x >> 5);
  int g = threadIdx.x & 31;
  int idx = idx_final[t] & (NE - 1);
  const float* er = e + (size_t)idx * DIM;
  float* op = out + (size_t)t * DIM;
  #pragma unroll
  for (int p = 0; p < 4; ++p) {
    int c = p * 128 + g * 4;
    float4 ev = *(const float4*)(er + c);
    float4 ov;
    ov.x = bfround(ev.x); ov.y = bfround(ev.y);
    ov.z = bfround(ev.z); ov.w = bfround(ev.w);
    *(float4*)(op + c) = ov;
  }
}

__global__ void finalize_kernel(const int* __restrict__ counts,
                                const float* __restrict__ lossp,
                                float* __restrict__ out) {
  __shared__ float red[4], red2[4];
  int tid = threadIdx.x;
  float s = 0.f;
  for (int j = tid; j < NE; j += 256) {
    float p = (float)counts[j] * (1.0f / (float)N_TOK);
    s += p * logf(p + 1e-10f);
  }
  float ls = 0.f;
  for (int j = tid; j < N_TOK / 4; j += 256) ls += lossp[j];
  #pragma unroll
  for (int m = 32; m >= 1; m >>= 1) {
    s += __shfl_xor(s, m);
    ls += __shfl_xor(ls, m);
  }
  if ((tid & 63) == 0) { red[tid >> 6] = s; red2[tid >> 6] = ls; }
  __syncthreads();
  if (tid == 0) {
    float tot = red[0] + red[1] + red[2] + red[3];
    float lt = red2[0] + red2[1] + red2[2] + red2[3];
    out[PERP_OFF] = bfround(expf(-tot));
    out[LOSS_OFF] = bfround(lt * 1.25f / (float)(N_TOK * DIM));
  }
}

extern "C" void kernel_launch(void* const* d_in, const int* in_sizes, int n_in,
                              void* d_out, int out_size, void* d_ws, size_t ws_size,
                              hipStream_t stream) {
  const float* z = (const float*)d_in[0];
  const float* e = (const float*)d_in[1];
  float* out = (float*)d_out;
  char* ws = (char*)d_ws;

  float*    zsum      = (float*)(ws + KB(0));      // 128 KB
  float*    esum      = (float*)(ws + KB(128));    // 8 KB
  int*      counts    = (int*)(ws + KB(136));      // 8 KB
  float*    lossp     = (float*)(ws + KB(144));    // 32 KB
  int*      idx_final = (int*)(ws + KB(176));      // 128 KB
  unsigned short* ebf = (unsigned short*)(ws + KB(304)); // 2 MB

  unsigned short* zbf = (unsigned short*)out;   // 32 MB scratch in d_out
  float* groupmin = out + 8388608;              // 16 MB scratch in d_out

  npsum_cvt_all<<<N_TOK / 16 + NE / 16, 256, 0, stream>>>(
      z, e, zsum, esum, zbf, ebf, counts);
  gemm_groupmin<<<dim3(N_TOK / 128, NE / 256), 512, 49152, stream>>>(
      ebf, zbf, esum, groupmin);
  select_exact<<<N_TOK / 4, 256, 0, stream>>>(z, e, zsum, esum, groupmin,
                                              idx_final, counts, out, lossp);
  scatter_zq<<<N_TOK / 8, 256, 0, stream>>>(e, idx_final, out);
  finalize_kernel<<<1, 256, 0, stream>>>(counts, lossp, out);
}

// Round 18
// 185.316 us; speedup vs baseline: 6.4072x; 1.1145x over previous
//
#include <hip/hip_runtime.h>
#include <hip/hip_bf16.h>

#define N_TOK 32768
#define DIM   512
#define NE    2048

#define IDX_OFF  (N_TOK * DIM)
#define LOSS_OFF (IDX_OFF + N_TOK)
#define PERP_OFF (LOSS_OFF + 1)

#define KB(x) ((size_t)(x) << 10)
#define EPS 4e-4f

typedef __attribute__((ext_vector_type(8))) short bf16x8;
typedef __attribute__((ext_vector_type(4))) float f32x4;

__device__ inline unsigned short f2bf(float f) {
  unsigned int x = __float_as_uint(f);
  x = x + 0x7fffu + ((x >> 16) & 1u);
  return (unsigned short)(x >> 16);
}
__device__ inline float bfround(float f) {
  return __uint_as_float((unsigned int)f2bf(f) << 16);
}

// Combined: np.sum(x*x) exact replication (validated round 4 — sum chain
// untouched) + fused bf16 conversion for z and e. Blocks 0..7 zero counts.
__global__ __launch_bounds__(256) void npsum_cvt_all(
    const float* __restrict__ z, const float* __restrict__ e,
    float* __restrict__ zsum, float* __restrict__ esum,
    unsigned short* __restrict__ zbf, unsigned short* __restrict__ ebf,
    int* __restrict__ counts) {
#pragma clang fp contract(off)
  const int bz = blockIdx.x;
  if (bz < 8) counts[bz * 256 + threadIdx.x] = 0;
  const bool isz = bz < (N_TOK / 16);
  const int blk = isz ? bz : bz - (N_TOK / 16);
  const float* x = isz ? z : e;
  float* outs = isz ? zsum : esum;
  unsigned short* xbf = isz ? zbf : ebf;

  int wave = threadIdx.x >> 6;
  int lane = threadIdx.x & 63;
  int grp = lane >> 4, l = lane & 15;
  int row = blk * 16 + wave * 4 + grp;
  {
    const float* a = x + (size_t)row * DIM;
    float L[4];
    #pragma unroll
    for (int b = 0; b < 4; ++b) {
      const float* p = a + b * 128 + l;
      float q[8];
      #pragma unroll
      for (int j = 0; j < 8; ++j) {
        float t = p[16 * j];
        float s = t * t;
        asm volatile("" : "+v"(s));
        q[j] = s;
      }
      float v = ((q[0] + q[1]) + (q[2] + q[3])) + ((q[4] + q[5]) + (q[6] + q[7]));
      v += __shfl_xor(v, 8);
      v += __shfl_xor(v, 4);
      v += __shfl_xor(v, 2);
      v += __shfl_xor(v, 1);
      L[b] = v;
    }
    if (l == 0) outs[row] = (L[0] + L[1]) + (L[2] + L[3]);
  }
  const float* blkp = x + (size_t)blk * 16 * DIM;
  unsigned short* ob = xbf + (size_t)blk * 16 * DIM;
  #pragma unroll
  for (int u = 0; u < 4; ++u) {
    size_t off = (size_t)(u * 256 + threadIdx.x) * 8;
    float4 a2 = *(const float4*)(blkp + off);
    float4 b2 = *(const float4*)(blkp + off + 4);
    unsigned short h[8] = {f2bf(a2.x), f2bf(a2.y), f2bf(a2.z), f2bf(a2.w),
                           f2bf(b2.x), f2bf(b2.y), f2bf(b2.z), f2bf(b2.w)};
    *(uint4*)(ob + off) = *(uint4*)h;
  }
}

// Stage one 128x64-bf16 half-tile (16KB) via global_load_lds width 16.
__device__ inline void stage_half(const unsigned short* __restrict__ gsrc,
                                  unsigned short* lds, int w, int l) {
  const int swz_col = ((l & 7) ^ (l >> 3)) * 8;
  const int rsub = l >> 3;
  #pragma unroll
  for (int s4 = 0; s4 < 2; ++s4) {
    int s = w * 2 + s4;
    const unsigned short* g = gsrc + (size_t)(s * 8 + rsub) * DIM + swz_col;
    __builtin_amdgcn_global_load_lds(
        (const __attribute__((address_space(1))) unsigned int*)g,
        (__attribute__((address_space(3))) unsigned int*)(lds + s * 512),
        16, 0, 0);
  }
}

#define BAR()   asm volatile("s_barrier" ::: "memory")
#define VMCNT4  asm volatile("s_waitcnt vmcnt(4)" ::: "memory")
#define VMCNT0  asm volatile("s_waitcnt vmcnt(0)" ::: "memory")

// 8-phase MFMA GEMM — exact R15 structure (measured best: 79us), 256x256
// tile, 8 waves (2Mx4N, 128x64 wave tiles), BK=64, 10 barriers/iter,
// counted vmcnt(4). Numerics/accumulation order identical to rounds 6-17.
// EPILOGUE ADDITION: per-16-code-group candidate bitmask (u16): bit c set
// iff v_c <= groupmin_g + EPS (containment: np winner always flagged).
__global__ __launch_bounds__(512, 2) void gemm_groupmin(
    const unsigned short* __restrict__ ebf, const unsigned short* __restrict__ zbf,
    const float* __restrict__ esum, float* __restrict__ groupmin,
    unsigned short* __restrict__ gmask) {
  extern __shared__ unsigned short smem[];
  unsigned short* As = smem;
  unsigned short* Bs = smem + 32768;

  const int tid = threadIdx.x;
  const int tb = blockIdx.x;   // token block (128) — XCD-swizzled grid
  const int cb = blockIdx.y;   // code block (8)
  const int w = tid >> 6, l = tid & 63;
  const int lr = l & 15, lk = l >> 4;
  const int wrow = (w >> 2) * 128;
  const int wcol = (w & 3) * 64;

  f32x4 acc[8][4];
  #pragma unroll
  for (int i = 0; i < 8; ++i)
    #pragma unroll
    for (int j = 0; j < 4; ++j) acc[i][j] = (f32x4)(0.f);

  bf16x8 aR[8], bA[4], bB[4];

  const unsigned short* Ag = ebf + (size_t)(cb * 256) * DIM;
  const unsigned short* Bg = zbf + (size_t)(tb * 256) * DIM;

#define LOADA(slot, qm) do { \
  _Pragma("unroll") for (int i2 = 0; i2 < 4; ++i2) { \
    int R = wrow + (qm)*64 + i2*16 + lr; \
    int rbase = ((slot)*2 + (R>>7))*8192 + (R&127)*64; \
    aR[i2*2+0] = *(const bf16x8*)&As[rbase + (((lk    ) ^ (R&7))*8)]; \
    aR[i2*2+1] = *(const bf16x8*)&As[rbase + (((4 + lk) ^ (R&7))*8)]; \
  } } while (0)

#define LOADB(dst, slot, qn) do { \
  _Pragma("unroll") for (int j = 0; j < 2; ++j) { \
    int C = wcol + (qn)*32 + j*16 + lr; \
    int cbase = ((slot)*2 + (C>>7))*8192 + (C&127)*64; \
    dst[j*2+0] = *(const bf16x8*)&Bs[cbase + (((lk    ) ^ (C&7))*8)]; \
    dst[j*2+1] = *(const bf16x8*)&Bs[cbase + (((4 + lk) ^ (C&7))*8)]; \
  } } while (0)

#define MFMA16(qm, qn, bX) do { \
  __builtin_amdgcn_s_setprio(1); \
  _Pragma("unroll") for (int i2 = 0; i2 < 4; ++i2) \
    _Pragma("unroll") for (int j = 0; j < 2; ++j) { \
      acc[(qm)*4+i2][(qn)*2+j] = __builtin_amdgcn_mfma_f32_16x16x32_bf16( \
          aR[i2*2+0], bX[j*2+0], acc[(qm)*4+i2][(qn)*2+j], 0, 0, 0); \
      acc[(qm)*4+i2][(qn)*2+j] = __builtin_amdgcn_mfma_f32_16x16x32_bf16( \
          aR[i2*2+1], bX[j*2+1], acc[(qm)*4+i2][(qn)*2+j], 0, 0, 0); \
    } \
  __builtin_amdgcn_s_setprio(0); \
} while (0)

  stage_half(Bg,                 Bs,             w, l);
  stage_half(Bg + 128 * DIM,     Bs + 8192,      w, l);
  stage_half(Ag,                 As,             w, l);
  stage_half(Ag + 128 * DIM,     As + 8192,      w, l);
  stage_half(Bg + 64,            Bs + 2 * 8192,  w, l);
  stage_half(Bg + 128 * DIM + 64, Bs + 3 * 8192, w, l);
  VMCNT4;
  BAR();

  #pragma unroll
  for (int i = 0; i < 4; ++i) {
    const int t1k = (2 * i + 1) * 64;
    const int u0k = (2 * i + 2) * 64;
    const int u1k = (2 * i + 3) * 64;
    LOADA(0, 0); LOADB(bA, 0, 0); LOADB(bB, 0, 1);
    stage_half(Ag + t1k, As + 2 * 8192, w, l);
    BAR(); MFMA16(0, 0, bA);
    stage_half(Ag + 128 * DIM + t1k, As + 3 * 8192, w, l);
    BAR(); MFMA16(0, 1, bB);
    LOADA(0, 1);
    if (i < 3) stage_half(Bg + u0k, Bs, w, l);
    BAR(); MFMA16(1, 0, bA);
    if (i < 3) stage_half(Bg + 128 * DIM + u0k, Bs + 8192, w, l);
    BAR(); MFMA16(1, 1, bB);
    if (i < 3) { VMCNT4; } else { VMCNT0; }
    BAR();
    LOADA(1, 0); LOADB(bA, 1, 0); LOADB(bB, 1, 1);
    if (i < 3) stage_half(Ag + u0k, As, w, l);
    BAR(); MFMA16(0, 0, bA);
    if (i < 3) stage_half(Ag + 128 * DIM + u0k, As + 8192, w, l);
    BAR(); MFMA16(0, 1, bB);
    LOADA(1, 1);
    if (i < 3) stage_half(Bg + u1k, Bs + 2 * 8192, w, l);
    BAR(); MFMA16(1, 0, bA);
    if (i < 3) stage_half(Bg + 128 * DIM + u1k, Bs + 3 * 8192, w, l);
    BAR(); MFMA16(1, 1, bB);
    if (i < 3) { VMCNT4; BAR(); }
  }

  float esr[8][4];
  #pragma unroll
  for (int i = 0; i < 8; ++i)
    #pragma unroll
    for (int q = 0; q < 4; ++q)
      esr[i][q] = esum[cb * 256 + wrow + i * 16 + lk * 4 + q];

  #pragma unroll
  for (int i = 0; i < 8; ++i) {
    const int g = cb * 16 + (w >> 2) * 8 + i;
    #pragma unroll
    for (int j = 0; j < 4; ++j) {
      float v0 = fmaf(-2.f, acc[i][j][0], esr[i][0]);
      float v1 = fmaf(-2.f, acc[i][j][1], esr[i][1]);
      float v2 = fmaf(-2.f, acc[i][j][2], esr[i][2]);
      float v3 = fmaf(-2.f, acc[i][j][3], esr[i][3]);
      float m = fminf(fminf(v0, v1), fminf(v2, v3));
      m = fminf(m, __shfl_xor(m, 16));
      m = fminf(m, __shfl_xor(m, 32));
      // per-code candidate mask: bit (lk*4+q) iff v_q <= m + EPS
      float gl = m + EPS;
      int mk = (((v0 <= gl) ? 1 : 0) | ((v1 <= gl) ? 2 : 0) |
                ((v2 <= gl) ? 4 : 0) | ((v3 <= gl) ? 8 : 0)) << (lk * 4);
      mk |= __shfl_xor(mk, 16);
      mk |= __shfl_xor(mk, 32);
      if (lk == 0) {
        int token = tb * 256 + wcol + j * 16 + lr;
        groupmin[(size_t)token * 128 + g] = m;
        gmask[(size_t)token * 128 + g] = (unsigned short)mk;
      }
    }
  }
#undef LOADA
#undef LOADB
#undef MFMA16
}

// One wave per token: mask-guided exact rescan. Qualified groups (groupmin
// <= min+EPS) ascending, then mask bits ascending -> first-index ties with
// strict <. Rescans only flagged codes (~2/token instead of 16+/token).
__global__ __launch_bounds__(256) void select_exact(
    const float* __restrict__ z, const float* __restrict__ e,
    const float* __restrict__ zsum, const float* __restrict__ esum,
    const float* __restrict__ groupmin, const unsigned short* __restrict__ gmask,
    int* __restrict__ idx_final, int* __restrict__ counts,
    float* __restrict__ out, float* __restrict__ lossp) {
  __shared__ float lred[4];
  const int wid = threadIdx.x >> 6;
  const int t = blockIdx.x * 4 + wid;
  const int lane = threadIdx.x & 63;
  const float* zr = z + (size_t)t * DIM;

  float4 za = *(const float4*)(zr + lane * 4);
  float4 zb = *(const float4*)(zr + 256 + lane * 4);

  float g0 = groupmin[(size_t)t * 128 + lane];
  float g1 = groupmin[(size_t)t * 128 + 64 + lane];
  int msk0 = gmask[(size_t)t * 128 + lane];
  int msk1 = gmask[(size_t)t * 128 + 64 + lane];
  float m = fminf(g0, g1);
  #pragma unroll
  for (int s = 32; s >= 1; s >>= 1) m = fminf(m, __shfl_xor(m, s));
  float lim = m + EPS;
  unsigned long long mm0 = __ballot(g0 <= lim);
  unsigned long long mm1 = __ballot(g1 <= lim);
  float zst = zsum[t];
  float bd = 3.402823466e38f; int bc = 0x7fffffff;

  #pragma unroll 1
  for (int half = 0; half < 2; ++half) {
    unsigned long long mk = half ? mm1 : mm0;
    while (mk) {
      int b = __ffsll((unsigned long long)mk) - 1;
      mk &= mk - 1;
      const int base = (half * 64 + b) * 16;
      unsigned gm = (unsigned)__shfl(half ? msk1 : msk0, b) & 0xFFFFu;
      while (gm) {
        int ci = __ffs(gm) - 1;
        gm &= gm - 1;
        int c = base + ci;
        const float* er = e + (size_t)c * DIM;
        float4 ea = *(const float4*)(er + lane * 4);
        float4 eb = *(const float4*)(er + 256 + lane * 4);
        float p = 0.f;
        p = fmaf(za.x, ea.x, p); p = fmaf(za.y, ea.y, p);
        p = fmaf(za.z, ea.z, p); p = fmaf(za.w, ea.w, p);
        p = fmaf(zb.x, eb.x, p); p = fmaf(zb.y, eb.y, p);
        p = fmaf(zb.z, eb.z, p); p = fmaf(zb.w, eb.w, p);
        #pragma unroll
        for (int s = 1; s <= 32; s <<= 1) p += __shfl_xor(p, s);
        float d = (zst + esum[c]) - 2.f * p;
        if (d < bd) { bd = d; bc = c; }   // ascending c => first-index ties
      }
    }
  }
  if (lane == 0) {
    idx_final[t] = bc;
    out[IDX_OFF + t] = bfround((float)bc);
    atomicAdd(&counts[bc], 1);
    lred[wid] = bd;
  }
  __syncthreads();
  if (threadIdx.x == 0)
    lossp[blockIdx.x] = (lred[0] + lred[1]) + (lred[2] + lred[3]);
}

// 8 tokens/block, 32 threads/token: gather e[idx] -> bf16-rounded z_q write.
// Runs after select_exact; may overwrite the groupmin/gmask scratch region.
__global__ __launch_bounds__(256) void scatter_zq(
    const float* __restrict__ e, const int* __restrict__ idx_final,
    float* __restrict__ out) {
  int t = blockIdx.x * 8 + (threadIdx.x >> 5);
  int g = threadIdx.x & 31;
  int idx = idx_final[t] & (NE - 1);
  const float* er = e + (size_t)idx * DIM;
  float* op = out + (size_t)t * DIM;
  #pragma unroll
  for (int p = 0; p < 4; ++p) {
    int c = p * 128 + g * 4;
    float4 ev = *(const float4*)(er + c);
    float4 ov;
    ov.x = bfround(ev.x); ov.y = bfround(ev.y);
    ov.z = bfround(ev.z); ov.w = bfround(ev.w);
    *(float4*)(op + c) = ov;
  }
}

__global__ void finalize_kernel(const int* __restrict__ counts,
                                const float* __restrict__ lossp,
                                float* __restrict__ out) {
  __shared__ float red[4], red2[4];
  int tid = threadIdx.x;
  float s = 0.f;
  for (int j = tid; j < NE; j += 256) {
    float p = (float)counts[j] * (1.0f / (float)N_TOK);
    s += p * logf(p + 1e-10f);
  }
  float ls = 0.f;
  for (int j = tid; j < N_TOK / 4; j += 256) ls += lossp[j];
  #pragma unroll
  for (int m = 32; m >= 1; m >>= 1) {
    s += __shfl_xor(s, m);
    ls += __shfl_xor(ls, m);
  }
  if ((tid & 63) == 0) { red[tid >> 6] = s; red2[tid >> 6] = ls; }
  __syncthreads();
  if (tid == 0) {
    float tot = red[0] + red[1] + red[2] + red[3];
    float lt = red2[0] + red2[1] + red2[2] + red2[3];
    out[PERP_OFF] = bfround(expf(-tot));
    out[LOSS_OFF] = bfround(lt * 1.25f / (float)(N_TOK * DIM));
  }
}

extern "C" void kernel_launch(void* const* d_in, const int* in_sizes, int n_in,
                              void* d_out, int out_size, void* d_ws, size_t ws_size,
                              hipStream_t stream) {
  const float* z = (const float*)d_in[0];
  const float* e = (const float*)d_in[1];
  float* out = (float*)d_out;
  char* ws = (char*)d_ws;

  float*    zsum      = (float*)(ws + KB(0));      // 128 KB
  float*    esum      = (float*)(ws + KB(128));    // 8 KB
  int*      counts    = (int*)(ws + KB(136));      // 8 KB
  float*    lossp     = (float*)(ws + KB(144));    // 32 KB
  int*      idx_final = (int*)(ws + KB(176));      // 128 KB
  unsigned short* ebf = (unsigned short*)(ws + KB(304)); // 2 MB

  // scratch parked in d_out's z_q region (overwritten only after select):
  unsigned short* zbf = (unsigned short*)out;              // 32 MB
  float* groupmin = out + 8388608;                         // 16 MB
  unsigned short* gmask = (unsigned short*)(out + 12582912); // 8 MB

  npsum_cvt_all<<<N_TOK / 16 + NE / 16, 256, 0, stream>>>(
      z, e, zsum, esum, zbf, ebf, counts);
  gemm_groupmin<<<dim3(N_TOK / 256, NE / 256), 512, 131072, stream>>>(
      ebf, zbf, esum, groupmin, gmask);
  select_exact<<<N_TOK / 4, 256, 0, stream>>>(z, e, zsum, esum, groupmin, gmask,
                                              idx_final, counts, out, lossp);
  scatter_zq<<<N_TOK / 8, 256, 0, stream>>>(e, idx_final, out);
  finalize_kernel<<<1, 256, 0, stream>>>(counts, lossp, out);
}

// Round 19
// 171.923 us; speedup vs baseline: 6.9063x; 1.0779x over previous
//
#include <hip/hip_runtime.h>
#include <hip/hip_bf16.h>

#define N_TOK 32768
#define DIM   512
#define NE    2048

#define IDX_OFF  (N_TOK * DIM)
#define LOSS_OFF (IDX_OFF + N_TOK)
#define PERP_OFF (LOSS_OFF + 1)

#define KB(x) ((size_t)(x) << 10)
#define EPS 4e-4f

typedef __attribute__((ext_vector_type(8))) short bf16x8;
typedef __attribute__((ext_vector_type(4))) float f32x4;

__device__ inline unsigned short f2bf(float f) {
  unsigned int x = __float_as_uint(f);
  x = x + 0x7fffu + ((x >> 16) & 1u);
  return (unsigned short)(x >> 16);
}
__device__ inline float bfround(float f) {
  return __uint_as_float((unsigned int)f2bf(f) << 16);
}

// Combined: np.sum(x*x) exact replication (validated round 4 — sum chain
// untouched) + fused bf16 conversion for z and e. Blocks 0..7 zero counts.
__global__ __launch_bounds__(256) void npsum_cvt_all(
    const float* __restrict__ z, const float* __restrict__ e,
    float* __restrict__ zsum, float* __restrict__ esum,
    unsigned short* __restrict__ zbf, unsigned short* __restrict__ ebf,
    int* __restrict__ counts) {
#pragma clang fp contract(off)
  const int bz = blockIdx.x;
  if (bz < 8) counts[bz * 256 + threadIdx.x] = 0;
  const bool isz = bz < (N_TOK / 16);
  const int blk = isz ? bz : bz - (N_TOK / 16);
  const float* x = isz ? z : e;
  float* outs = isz ? zsum : esum;
  unsigned short* xbf = isz ? zbf : ebf;

  int wave = threadIdx.x >> 6;
  int lane = threadIdx.x & 63;
  int grp = lane >> 4, l = lane & 15;
  int row = blk * 16 + wave * 4 + grp;
  {
    const float* a = x + (size_t)row * DIM;
    float L[4];
    #pragma unroll
    for (int b = 0; b < 4; ++b) {
      const float* p = a + b * 128 + l;
      float q[8];
      #pragma unroll
      for (int j = 0; j < 8; ++j) {
        float t = p[16 * j];
        float s = t * t;
        asm volatile("" : "+v"(s));
        q[j] = s;
      }
      float v = ((q[0] + q[1]) + (q[2] + q[3])) + ((q[4] + q[5]) + (q[6] + q[7]));
      v += __shfl_xor(v, 8);
      v += __shfl_xor(v, 4);
      v += __shfl_xor(v, 2);
      v += __shfl_xor(v, 1);
      L[b] = v;
    }
    if (l == 0) outs[row] = (L[0] + L[1]) + (L[2] + L[3]);
  }
  const float* blkp = x + (size_t)blk * 16 * DIM;
  unsigned short* ob = xbf + (size_t)blk * 16 * DIM;
  #pragma unroll
  for (int u = 0; u < 4; ++u) {
    size_t off = (size_t)(u * 256 + threadIdx.x) * 8;
    float4 a2 = *(const float4*)(blkp + off);
    float4 b2 = *(const float4*)(blkp + off + 4);
    unsigned short h[8] = {f2bf(a2.x), f2bf(a2.y), f2bf(a2.z), f2bf(a2.w),
                           f2bf(b2.x), f2bf(b2.y), f2bf(b2.z), f2bf(b2.w)};
    *(uint4*)(ob + off) = *(uint4*)h;
  }
}

// Stage one 128x64-bf16 half-tile (16KB) via global_load_lds width 16.
__device__ inline void stage_half(const unsigned short* __restrict__ gsrc,
                                  unsigned short* lds, int w, int l) {
  const int swz_col = ((l & 7) ^ (l >> 3)) * 8;
  const int rsub = l >> 3;
  #pragma unroll
  for (int s4 = 0; s4 < 2; ++s4) {
    int s = w * 2 + s4;
    const unsigned short* g = gsrc + (size_t)(s * 8 + rsub) * DIM + swz_col;
    __builtin_amdgcn_global_load_lds(
        (const __attribute__((address_space(1))) unsigned int*)g,
        (__attribute__((address_space(3))) unsigned int*)(lds + s * 512),
        16, 0, 0);
  }
}

#define BAR()   asm volatile("s_barrier" ::: "memory")
#define VMCNT4  asm volatile("s_waitcnt vmcnt(4)" ::: "memory")
#define VMCNT0  asm volatile("s_waitcnt vmcnt(0)" ::: "memory")

// 8-phase MFMA GEMM — R15 structure (measured best: 79us), 256x256 tile,
// 8 waves (2Mx4N), BK=64, 10 barriers/iter, counted vmcnt(4). Numerics /
// accumulation order identical to rounds 6-18. Epilogue: groupmin + code
// candidate bitmask, staged via LDS and dumped with FULL-LINE coalesced
// writes (R18's direct scattered stores caused 110MB write amplification).
__global__ __launch_bounds__(512, 2) void gemm_groupmin(
    const unsigned short* __restrict__ ebf, const unsigned short* __restrict__ zbf,
    const float* __restrict__ esum, float* __restrict__ groupmin,
    unsigned short* __restrict__ gmask) {
  extern __shared__ unsigned short smem[];
  unsigned short* As = smem;
  unsigned short* Bs = smem + 32768;

  const int tid = threadIdx.x;
  const int tb = blockIdx.x;   // token block (128) — XCD-swizzled grid
  const int cb = blockIdx.y;   // code block (8)
  const int w = tid >> 6, l = tid & 63;
  const int lr = l & 15, lk = l >> 4;
  const int wrow = (w >> 2) * 128;
  const int wcol = (w & 3) * 64;

  f32x4 acc[8][4];
  #pragma unroll
  for (int i = 0; i < 8; ++i)
    #pragma unroll
    for (int j = 0; j < 4; ++j) acc[i][j] = (f32x4)(0.f);

  bf16x8 aR[8], bA[4], bB[4];

  const unsigned short* Ag = ebf + (size_t)(cb * 256) * DIM;
  const unsigned short* Bg = zbf + (size_t)(tb * 256) * DIM;

#define LOADA(slot, qm) do { \
  _Pragma("unroll") for (int i2 = 0; i2 < 4; ++i2) { \
    int R = wrow + (qm)*64 + i2*16 + lr; \
    int rbase = ((slot)*2 + (R>>7))*8192 + (R&127)*64; \
    aR[i2*2+0] = *(const bf16x8*)&As[rbase + (((lk    ) ^ (R&7))*8)]; \
    aR[i2*2+1] = *(const bf16x8*)&As[rbase + (((4 + lk) ^ (R&7))*8)]; \
  } } while (0)

#define LOADB(dst, slot, qn) do { \
  _Pragma("unroll") for (int j = 0; j < 2; ++j) { \
    int C = wcol + (qn)*32 + j*16 + lr; \
    int cbase = ((slot)*2 + (C>>7))*8192 + (C&127)*64; \
    dst[j*2+0] = *(const bf16x8*)&Bs[cbase + (((lk    ) ^ (C&7))*8)]; \
    dst[j*2+1] = *(const bf16x8*)&Bs[cbase + (((4 + lk) ^ (C&7))*8)]; \
  } } while (0)

#define MFMA16(qm, qn, bX) do { \
  __builtin_amdgcn_s_setprio(1); \
  _Pragma("unroll") for (int i2 = 0; i2 < 4; ++i2) \
    _Pragma("unroll") for (int j = 0; j < 2; ++j) { \
      acc[(qm)*4+i2][(qn)*2+j] = __builtin_amdgcn_mfma_f32_16x16x32_bf16( \
          aR[i2*2+0], bX[j*2+0], acc[(qm)*4+i2][(qn)*2+j], 0, 0, 0); \
      acc[(qm)*4+i2][(qn)*2+j] = __builtin_amdgcn_mfma_f32_16x16x32_bf16( \
          aR[i2*2+1], bX[j*2+1], acc[(qm)*4+i2][(qn)*2+j], 0, 0, 0); \
    } \
  __builtin_amdgcn_s_setprio(0); \
} while (0)

  stage_half(Bg,                 Bs,             w, l);
  stage_half(Bg + 128 * DIM,     Bs + 8192,      w, l);
  stage_half(Ag,                 As,             w, l);
  stage_half(Ag + 128 * DIM,     As + 8192,      w, l);
  stage_half(Bg + 64,            Bs + 2 * 8192,  w, l);
  stage_half(Bg + 128 * DIM + 64, Bs + 3 * 8192, w, l);
  VMCNT4;
  BAR();

  #pragma unroll
  for (int i = 0; i < 4; ++i) {
    const int t1k = (2 * i + 1) * 64;
    const int u0k = (2 * i + 2) * 64;
    const int u1k = (2 * i + 3) * 64;
    LOADA(0, 0); LOADB(bA, 0, 0); LOADB(bB, 0, 1);
    stage_half(Ag + t1k, As + 2 * 8192, w, l);
    BAR(); MFMA16(0, 0, bA);
    stage_half(Ag + 128 * DIM + t1k, As + 3 * 8192, w, l);
    BAR(); MFMA16(0, 1, bB);
    LOADA(0, 1);
    if (i < 3) stage_half(Bg + u0k, Bs, w, l);
    BAR(); MFMA16(1, 0, bA);
    if (i < 3) stage_half(Bg + 128 * DIM + u0k, Bs + 8192, w, l);
    BAR(); MFMA16(1, 1, bB);
    if (i < 3) { VMCNT4; } else { VMCNT0; }
    BAR();
    LOADA(1, 0); LOADB(bA, 1, 0); LOADB(bB, 1, 1);
    if (i < 3) stage_half(Ag + u0k, As, w, l);
    BAR(); MFMA16(0, 0, bA);
    if (i < 3) stage_half(Ag + 128 * DIM + u0k, As + 8192, w, l);
    BAR(); MFMA16(0, 1, bB);
    LOADA(1, 1);
    if (i < 3) stage_half(Bg + u1k, Bs + 2 * 8192, w, l);
    BAR(); MFMA16(1, 0, bA);
    if (i < 3) stage_half(Bg + 128 * DIM + u1k, Bs + 3 * 8192, w, l);
    BAR(); MFMA16(1, 1, bB);
    if (i < 3) { VMCNT4; BAR(); }
  }

  float esr[8][4];
  #pragma unroll
  for (int i = 0; i < 8; ++i)
    #pragma unroll
    for (int q = 0; q < 4; ++q)
      esr[i][q] = esum[cb * 256 + wrow + i * 16 + lk * 4 + q];

  // LDS-staged epilogue: lgm [256][20] floats (20KB), lmk [256][24] u16
  // (12KB) — strides chosen for bank spread + 16B dump alignment.
  float* lgm = (float*)smem;
  unsigned short* lmk = (unsigned short*)((char*)smem + 20608);
  BAR();   // all waves done with main-loop LDS reads

  #pragma unroll
  for (int i = 0; i < 8; ++i) {
    #pragma unroll
    for (int j = 0; j < 4; ++j) {
      float v0 = fmaf(-2.f, acc[i][j][0], esr[i][0]);
      float v1 = fmaf(-2.f, acc[i][j][1], esr[i][1]);
      float v2 = fmaf(-2.f, acc[i][j][2], esr[i][2]);
      float v3 = fmaf(-2.f, acc[i][j][3], esr[i][3]);
      float m = fminf(fminf(v0, v1), fminf(v2, v3));
      m = fminf(m, __shfl_xor(m, 16));
      m = fminf(m, __shfl_xor(m, 32));
      float gl = m + EPS;
      int mk = (((v0 <= gl) ? 1 : 0) | ((v1 <= gl) ? 2 : 0) |
                ((v2 <= gl) ? 4 : 0) | ((v3 <= gl) ? 8 : 0)) << (lk * 4);
      mk |= __shfl_xor(mk, 16);
      mk |= __shfl_xor(mk, 32);
      if (lk == 0) {
        int tl = wcol + j * 16 + lr;        // 0..255, disjoint per (w&3, j)
        int gg = (w >> 2) * 8 + i;          // 0..15, disjoint per (w>>2, i)
        lgm[tl * 20 + gg] = m;
        lmk[tl * 24 + gg] = (unsigned short)mk;
      }
    }
  }
  BAR();
  // dump coalesced: 512 threads, each half a token row (8 floats + 8 u16)
  {
    int row = tid >> 1, half = tid & 1;
    float4 f0 = *(float4*)&lgm[row * 20 + half * 8];
    float4 f1 = *(float4*)&lgm[row * 20 + half * 8 + 4];
    uint4 mq = *(uint4*)&lmk[row * 24 + half * 8];
    size_t gb = (size_t)(tb * 256 + row) * 128 + cb * 16 + half * 8;
    *(float4*)&groupmin[gb] = f0;
    *(float4*)&groupmin[gb + 4] = f1;
    *(uint4*)&gmask[gb] = mq;
  }
#undef LOADA
#undef LOADB
#undef MFMA16
}

// One wave per token: mask-guided exact rescan (validated round 18).
__global__ __launch_bounds__(256) void select_exact(
    const float* __restrict__ z, const float* __restrict__ e,
    const float* __restrict__ zsum, const float* __restrict__ esum,
    const float* __restrict__ groupmin, const unsigned short* __restrict__ gmask,
    int* __restrict__ idx_final, int* __restrict__ counts,
    float* __restrict__ out, float* __restrict__ lossp) {
  __shared__ float lred[4];
  const int wid = threadIdx.x >> 6;
  const int t = blockIdx.x * 4 + wid;
  const int lane = threadIdx.x & 63;
  const float* zr = z + (size_t)t * DIM;

  float4 za = *(const float4*)(zr + lane * 4);
  float4 zb = *(const float4*)(zr + 256 + lane * 4);

  float g0 = groupmin[(size_t)t * 128 + lane];
  float g1 = groupmin[(size_t)t * 128 + 64 + lane];
  int msk0 = gmask[(size_t)t * 128 + lane];
  int msk1 = gmask[(size_t)t * 128 + 64 + lane];
  float m = fminf(g0, g1);
  #pragma unroll
  for (int s = 32; s >= 1; s >>= 1) m = fminf(m, __shfl_xor(m, s));
  float lim = m + EPS;
  unsigned long long mm0 = __ballot(g0 <= lim);
  unsigned long long mm1 = __ballot(g1 <= lim);
  float zst = zsum[t];
  float bd = 3.402823466e38f; int bc = 0x7fffffff;

  #pragma unroll 1
  for (int half = 0; half < 2; ++half) {
    unsigned long long mk = half ? mm1 : mm0;
    while (mk) {
      int b = __ffsll((unsigned long long)mk) - 1;
      mk &= mk - 1;
      const int base = (half * 64 + b) * 16;
      unsigned gm = (unsigned)__shfl(half ? msk1 : msk0, b) & 0xFFFFu;
      while (gm) {
        int ci = __ffs(gm) - 1;
        gm &= gm - 1;
        int c = base + ci;
        const float* er = e + (size_t)c * DIM;
        float4 ea = *(const float4*)(er + lane * 4);
        float4 eb = *(const float4*)(er + 256 + lane * 4);
        float p = 0.f;
        p = fmaf(za.x, ea.x, p); p = fmaf(za.y, ea.y, p);
        p = fmaf(za.z, ea.z, p); p = fmaf(za.w, ea.w, p);
        p = fmaf(zb.x, eb.x, p); p = fmaf(zb.y, eb.y, p);
        p = fmaf(zb.z, eb.z, p); p = fmaf(zb.w, eb.w, p);
        #pragma unroll
        for (int s = 1; s <= 32; s <<= 1) p += __shfl_xor(p, s);
        float d = (zst + esum[c]) - 2.f * p;
        if (d < bd) { bd = d; bc = c; }   // ascending c => first-index ties
      }
    }
  }
  if (lane == 0) {
    idx_final[t] = bc;
    out[IDX_OFF + t] = bfround((float)bc);
    atomicAdd(&counts[bc], 1);
    lred[wid] = bd;
  }
  __syncthreads();
  if (threadIdx.x == 0)
    lossp[blockIdx.x] = (lred[0] + lred[1]) + (lred[2] + lred[3]);
}

// 8 tokens/block, 32 threads/token: gather e[idx] -> bf16-rounded z_q write.
// Runs after select_exact; may overwrite the groupmin/gmask scratch region.
__global__ __launch_bounds__(256) void scatter_zq(
    const float* __restrict__ e, const int* __restrict__ idx_final,
    float* __restrict__ out) {
  int t = blockIdx.x * 8 + (threadIdx.x >> 5);
  int g = threadIdx.x & 31;
  int idx = idx_final[t] & (NE - 1);
  const float* er = e + (size_t)idx * DIM;
  float* op = out + (size_t)t * DIM;
  #pragma unroll
  for (int p = 0; p < 4; ++p) {
    int c = p * 128 + g * 4;
    float4 ev = *(const float4*)(er + c);
    float4 ov;
    ov.x = bfround(ev.x); ov.y = bfround(ev.y);
    ov.z = bfround(ev.z); ov.w = bfround(ev.w);
    *(float4*)(op + c) = ov;
  }
}

__global__ void finalize_kernel(const int* __restrict__ counts,
                                const float* __restrict__ lossp,
                                float* __restrict__ out) {
  __shared__ float red[4], red2[4];
  int tid = threadIdx.x;
  float s = 0.f;
  for (int j = tid; j < NE; j += 256) {
    float p = (float)counts[j] * (1.0f / (float)N_TOK);
    s += p * logf(p + 1e-10f);
  }
  float ls = 0.f;
  for (int j = tid; j < N_TOK / 4; j += 256) ls += lossp[j];
  #pragma unroll
  for (int m = 32; m >= 1; m >>= 1) {
    s += __shfl_xor(s, m);
    ls += __shfl_xor(ls, m);
  }
  if ((tid & 63) == 0) { red[tid >> 6] = s; red2[tid >> 6] = ls; }
  __syncthreads();
  if (tid == 0) {
    float tot = red[0] + red[1] + red[2] + red[3];
    float lt = red2[0] + red2[1] + red2[2] + red2[3];
    out[PERP_OFF] = bfround(expf(-tot));
    out[LOSS_OFF] = bfround(lt * 1.25f / (float)(N_TOK * DIM));
  }
}

extern "C" void kernel_launch(void* const* d_in, const int* in_sizes, int n_in,
                              void* d_out, int out_size, void* d_ws, size_t ws_size,
                              hipStream_t stream) {
  const float* z = (const float*)d_in[0];
  const float* e = (const float*)d_in[1];
  float* out = (float*)d_out;
  char* ws = (char*)d_ws;

  float*    zsum      = (float*)(ws + KB(0));      // 128 KB
  float*    esum      = (float*)(ws + KB(128));    // 8 KB
  int*      counts    = (int*)(ws + KB(136));      // 8 KB
  float*    lossp     = (float*)(ws + KB(144));    // 32 KB
  int*      idx_final = (int*)(ws + KB(176));      // 128 KB
  unsigned short* ebf = (unsigned short*)(ws + KB(304)); // 2 MB

  // scratch parked in d_out's z_q region (overwritten only after select):
  unsigned short* zbf = (unsigned short*)out;              // 32 MB
  float* groupmin = out + 8388608;                         // 16 MB
  unsigned short* gmask = (unsigned short*)(out + 12582912); // 8 MB

  npsum_cvt_all<<<N_TOK / 16 + NE / 16, 256, 0, stream>>>(
      z, e, zsum, esum, zbf, ebf, counts);
  gemm_groupmin<<<dim3(N_TOK / 256, NE / 256), 512, 131072, stream>>>(
      ebf, zbf, esum, groupmin, gmask);
  select_exact<<<N_TOK / 4, 256, 0, stream>>>(z, e, zsum, esum, groupmin, gmask,
                                              idx_final, counts, out, lossp);
  scatter_zq<<<N_TOK / 8, 256, 0, stream>>>(e, idx_final, out);
  finalize_kernel<<<1, 256, 0, stream>>>(counts, lossp, out);
}

// Round 20
// 157.814 us; speedup vs baseline: 7.5237x; 1.0894x over previous
//
#include <hip/hip_runtime.h>
#include <hip/hip_bf16.h>

#define N_TOK 32768
#define DIM   512
#define NE    2048

#define IDX_OFF  (N_TOK * DIM)
#define LOSS_OFF (IDX_OFF + N_TOK)
#define PERP_OFF (LOSS_OFF + 1)

#define KB(x) ((size_t)(x) << 10)
#define EPS 4e-4f

typedef __attribute__((ext_vector_type(8))) short bf16x8;
typedef __attribute__((ext_vector_type(4))) float f32x4;

__device__ inline unsigned short f2bf(float f) {
  unsigned int x = __float_as_uint(f);
  x = x + 0x7fffu + ((x >> 16) & 1u);
  return (unsigned short)(x >> 16);
}
__device__ inline float bfround(float f) {
  return __uint_as_float((unsigned int)f2bf(f) << 16);
}

// Combined: np.sum(x*x) exact replication (validated round 4 — sum chain
// untouched) + fused bf16 conversion for z and e. Blocks 0..7 zero counts.
__global__ __launch_bounds__(256) void npsum_cvt_all(
    const float* __restrict__ z, const float* __restrict__ e,
    float* __restrict__ zsum, float* __restrict__ esum,
    unsigned short* __restrict__ zbf, unsigned short* __restrict__ ebf,
    int* __restrict__ counts) {
#pragma clang fp contract(off)
  const int bz = blockIdx.x;
  if (bz < 8) counts[bz * 256 + threadIdx.x] = 0;
  const bool isz = bz < (N_TOK / 16);
  const int blk = isz ? bz : bz - (N_TOK / 16);
  const float* x = isz ? z : e;
  float* outs = isz ? zsum : esum;
  unsigned short* xbf = isz ? zbf : ebf;

  int wave = threadIdx.x >> 6;
  int lane = threadIdx.x & 63;
  int grp = lane >> 4, l = lane & 15;
  int row = blk * 16 + wave * 4 + grp;
  {
    const float* a = x + (size_t)row * DIM;
    float L[4];
    #pragma unroll
    for (int b = 0; b < 4; ++b) {
      const float* p = a + b * 128 + l;
      float q[8];
      #pragma unroll
      for (int j = 0; j < 8; ++j) {
        float t = p[16 * j];
        float s = t * t;
        asm volatile("" : "+v"(s));
        q[j] = s;
      }
      float v = ((q[0] + q[1]) + (q[2] + q[3])) + ((q[4] + q[5]) + (q[6] + q[7]));
      v += __shfl_xor(v, 8);
      v += __shfl_xor(v, 4);
      v += __shfl_xor(v, 2);
      v += __shfl_xor(v, 1);
      L[b] = v;
    }
    if (l == 0) outs[row] = (L[0] + L[1]) + (L[2] + L[3]);
  }
  const float* blkp = x + (size_t)blk * 16 * DIM;
  unsigned short* ob = xbf + (size_t)blk * 16 * DIM;
  #pragma unroll
  for (int u = 0; u < 4; ++u) {
    size_t off = (size_t)(u * 256 + threadIdx.x) * 8;
    float4 a2 = *(const float4*)(blkp + off);
    float4 b2 = *(const float4*)(blkp + off + 4);
    unsigned short h[8] = {f2bf(a2.x), f2bf(a2.y), f2bf(a2.z), f2bf(a2.w),
                           f2bf(b2.x), f2bf(b2.y), f2bf(b2.z), f2bf(b2.w)};
    *(uint4*)(ob + off) = *(uint4*)h;
  }
}

// Stage one 128x64-bf16 half-tile (16KB) via global_load_lds width 16.
__device__ inline void stage_half(const unsigned short* __restrict__ gsrc,
                                  unsigned short* lds, int w, int l) {
  const int swz_col = ((l & 7) ^ (l >> 3)) * 8;
  const int rsub = l >> 3;
  #pragma unroll
  for (int s4 = 0; s4 < 2; ++s4) {
    int s = w * 2 + s4;
    const unsigned short* g = gsrc + (size_t)(s * 8 + rsub) * DIM + swz_col;
    __builtin_amdgcn_global_load_lds(
        (const __attribute__((address_space(1))) unsigned int*)g,
        (__attribute__((address_space(3))) unsigned int*)(lds + s * 512),
        16, 0, 0);
  }
}

#define BAR()   asm volatile("s_barrier" ::: "memory")
#define VMCNT4  asm volatile("s_waitcnt vmcnt(4)" ::: "memory")
#define VMCNT0  asm volatile("s_waitcnt vmcnt(0)" ::: "memory")

// 8-phase MFMA GEMM — R15 structure (measured best: 79us), 256x256 tile,
// 8 waves (2Mx4N), BK=64, 10 barriers/iter, counted vmcnt(4). Numerics /
// accumulation order identical to rounds 6-19. Epilogue: groupmin + code
// candidate bitmask accumulated in REGISTERS (static indexing), stored as
// 32B/16B aligned chunks — same-block line merging in L2 keeps writes at
// data size (R15 evidence); no extra barriers, no LDS round-trip (R19 cost).
__global__ __launch_bounds__(512, 2) void gemm_groupmin(
    const unsigned short* __restrict__ ebf, const unsigned short* __restrict__ zbf,
    const float* __restrict__ esum, float* __restrict__ groupmin,
    unsigned short* __restrict__ gmask) {
  extern __shared__ unsigned short smem[];
  unsigned short* As = smem;
  unsigned short* Bs = smem + 32768;

  const int tid = threadIdx.x;
  const int tb = blockIdx.x;   // token block (128) — XCD-swizzled grid
  const int cb = blockIdx.y;   // code block (8)
  const int w = tid >> 6, l = tid & 63;
  const int lr = l & 15, lk = l >> 4;
  const int wrow = (w >> 2) * 128;
  const int wcol = (w & 3) * 64;

  f32x4 acc[8][4];
  #pragma unroll
  for (int i = 0; i < 8; ++i)
    #pragma unroll
    for (int j = 0; j < 4; ++j) acc[i][j] = (f32x4)(0.f);

  bf16x8 aR[8], bA[4], bB[4];

  const unsigned short* Ag = ebf + (size_t)(cb * 256) * DIM;
  const unsigned short* Bg = zbf + (size_t)(tb * 256) * DIM;

#define LOADA(slot, qm) do { \
  _Pragma("unroll") for (int i2 = 0; i2 < 4; ++i2) { \
    int R = wrow + (qm)*64 + i2*16 + lr; \
    int rbase = ((slot)*2 + (R>>7))*8192 + (R&127)*64; \
    aR[i2*2+0] = *(const bf16x8*)&As[rbase + (((lk    ) ^ (R&7))*8)]; \
    aR[i2*2+1] = *(const bf16x8*)&As[rbase + (((4 + lk) ^ (R&7))*8)]; \
  } } while (0)

#define LOADB(dst, slot, qn) do { \
  _Pragma("unroll") for (int j = 0; j < 2; ++j) { \
    int C = wcol + (qn)*32 + j*16 + lr; \
    int cbase = ((slot)*2 + (C>>7))*8192 + (C&127)*64; \
    dst[j*2+0] = *(const bf16x8*)&Bs[cbase + (((lk    ) ^ (C&7))*8)]; \
    dst[j*2+1] = *(const bf16x8*)&Bs[cbase + (((4 + lk) ^ (C&7))*8)]; \
  } } while (0)

#define MFMA16(qm, qn, bX) do { \
  __builtin_amdgcn_s_setprio(1); \
  _Pragma("unroll") for (int i2 = 0; i2 < 4; ++i2) \
    _Pragma("unroll") for (int j = 0; j < 2; ++j) { \
      acc[(qm)*4+i2][(qn)*2+j] = __builtin_amdgcn_mfma_f32_16x16x32_bf16( \
          aR[i2*2+0], bX[j*2+0], acc[(qm)*4+i2][(qn)*2+j], 0, 0, 0); \
      acc[(qm)*4+i2][(qn)*2+j] = __builtin_amdgcn_mfma_f32_16x16x32_bf16( \
          aR[i2*2+1], bX[j*2+1], acc[(qm)*4+i2][(qn)*2+j], 0, 0, 0); \
    } \
  __builtin_amdgcn_s_setprio(0); \
} while (0)

  stage_half(Bg,                 Bs,             w, l);
  stage_half(Bg + 128 * DIM,     Bs + 8192,      w, l);
  stage_half(Ag,                 As,             w, l);
  stage_half(Ag + 128 * DIM,     As + 8192,      w, l);
  stage_half(Bg + 64,            Bs + 2 * 8192,  w, l);
  stage_half(Bg + 128 * DIM + 64, Bs + 3 * 8192, w, l);
  VMCNT4;
  BAR();

  #pragma unroll
  for (int i = 0; i < 4; ++i) {
    const int t1k = (2 * i + 1) * 64;
    const int u0k = (2 * i + 2) * 64;
    const int u1k = (2 * i + 3) * 64;
    LOADA(0, 0); LOADB(bA, 0, 0); LOADB(bB, 0, 1);
    stage_half(Ag + t1k, As + 2 * 8192, w, l);
    BAR(); MFMA16(0, 0, bA);
    stage_half(Ag + 128 * DIM + t1k, As + 3 * 8192, w, l);
    BAR(); MFMA16(0, 1, bB);
    LOADA(0, 1);
    if (i < 3) stage_half(Bg + u0k, Bs, w, l);
    BAR(); MFMA16(1, 0, bA);
    if (i < 3) stage_half(Bg + 128 * DIM + u0k, Bs + 8192, w, l);
    BAR(); MFMA16(1, 1, bB);
    if (i < 3) { VMCNT4; } else { VMCNT0; }
    BAR();
    LOADA(1, 0); LOADB(bA, 1, 0); LOADB(bB, 1, 1);
    if (i < 3) stage_half(Ag + u0k, As, w, l);
    BAR(); MFMA16(0, 0, bA);
    if (i < 3) stage_half(Ag + 128 * DIM + u0k, As + 8192, w, l);
    BAR(); MFMA16(0, 1, bB);
    LOADA(1, 1);
    if (i < 3) stage_half(Bg + u1k, Bs + 2 * 8192, w, l);
    BAR(); MFMA16(1, 0, bA);
    if (i < 3) stage_half(Bg + 128 * DIM + u1k, Bs + 3 * 8192, w, l);
    BAR(); MFMA16(1, 1, bB);
    if (i < 3) { VMCNT4; BAR(); }
  }

  float esr[8][4];
  #pragma unroll
  for (int i = 0; i < 8; ++i)
    #pragma unroll
    for (int q = 0; q < 4; ++q)
      esr[i][q] = esum[cb * 256 + wrow + i * 16 + lk * 4 + q];

  // register-accumulated epilogue (all static indexing)
  float m8[4][8];
  unsigned short k8[4][8];
  #pragma unroll
  for (int i = 0; i < 8; ++i) {
    #pragma unroll
    for (int j = 0; j < 4; ++j) {
      float v0 = fmaf(-2.f, acc[i][j][0], esr[i][0]);
      float v1 = fmaf(-2.f, acc[i][j][1], esr[i][1]);
      float v2 = fmaf(-2.f, acc[i][j][2], esr[i][2]);
      float v3 = fmaf(-2.f, acc[i][j][3], esr[i][3]);
      float m = fminf(fminf(v0, v1), fminf(v2, v3));
      m = fminf(m, __shfl_xor(m, 16));
      m = fminf(m, __shfl_xor(m, 32));
      float gl = m + EPS;
      int mk = (((v0 <= gl) ? 1 : 0) | ((v1 <= gl) ? 2 : 0) |
                ((v2 <= gl) ? 4 : 0) | ((v3 <= gl) ? 8 : 0)) << (lk * 4);
      mk |= __shfl_xor(mk, 16);
      mk |= __shfl_xor(mk, 32);
      m8[j][i] = m;                    // full-wave values; lk==0 lanes store
      k8[j][i] = (unsigned short)mk;
    }
  }
  if (lk == 0) {
    #pragma unroll
    for (int j = 0; j < 4; ++j) {
      int token = tb * 256 + wcol + j * 16 + lr;
      size_t gb = (size_t)token * 128 + cb * 16 + (w >> 2) * 8;
      float4 f0 = {m8[j][0], m8[j][1], m8[j][2], m8[j][3]};
      float4 f1 = {m8[j][4], m8[j][5], m8[j][6], m8[j][7]};
      *(float4*)&groupmin[gb] = f0;
      *(float4*)&groupmin[gb + 4] = f1;
      *(uint4*)&gmask[gb] = *(uint4*)&k8[j][0];
    }
  }
#undef LOADA
#undef LOADB
#undef MFMA16
}

// One wave per token: mask-guided exact rescan (validated round 18).
__global__ __launch_bounds__(256) void select_exact(
    const float* __restrict__ z, const float* __restrict__ e,
    const float* __restrict__ zsum, const float* __restrict__ esum,
    const float* __restrict__ groupmin, const unsigned short* __restrict__ gmask,
    int* __restrict__ idx_final, int* __restrict__ counts,
    float* __restrict__ out, float* __restrict__ lossp) {
  __shared__ float lred[4];
  const int wid = threadIdx.x >> 6;
  const int t = blockIdx.x * 4 + wid;
  const int lane = threadIdx.x & 63;
  const float* zr = z + (size_t)t * DIM;

  float4 za = *(const float4*)(zr + lane * 4);
  float4 zb = *(const float4*)(zr + 256 + lane * 4);

  float g0 = groupmin[(size_t)t * 128 + lane];
  float g1 = groupmin[(size_t)t * 128 + 64 + lane];
  int msk0 = gmask[(size_t)t * 128 + lane];
  int msk1 = gmask[(size_t)t * 128 + 64 + lane];
  float m = fminf(g0, g1);
  #pragma unroll
  for (int s = 32; s >= 1; s >>= 1) m = fminf(m, __shfl_xor(m, s));
  float lim = m + EPS;
  unsigned long long mm0 = __ballot(g0 <= lim);
  unsigned long long mm1 = __ballot(g1 <= lim);
  float zst = zsum[t];
  float bd = 3.402823466e38f; int bc = 0x7fffffff;

  #pragma unroll 1
  for (int half = 0; half < 2; ++half) {
    unsigned long long mk = half ? mm1 : mm0;
    while (mk) {
      int b = __ffsll((unsigned long long)mk) - 1;
      mk &= mk - 1;
      const int base = (half * 64 + b) * 16;
      unsigned gm = (unsigned)__shfl(half ? msk1 : msk0, b) & 0xFFFFu;
      while (gm) {
        int ci = __ffs(gm) - 1;
        gm &= gm - 1;
        int c = base + ci;
        const float* er = e + (size_t)c * DIM;
        float4 ea = *(const float4*)(er + lane * 4);
        float4 eb = *(const float4*)(er + 256 + lane * 4);
        float p = 0.f;
        p = fmaf(za.x, ea.x, p); p = fmaf(za.y, ea.y, p);
        p = fmaf(za.z, ea.z, p); p = fmaf(za.w, ea.w, p);
        p = fmaf(zb.x, eb.x, p); p = fmaf(zb.y, eb.y, p);
        p = fmaf(zb.z, eb.z, p); p = fmaf(zb.w, eb.w, p);
        #pragma unroll
        for (int s = 1; s <= 32; s <<= 1) p += __shfl_xor(p, s);
        float d = (zst + esum[c]) - 2.f * p;
        if (d < bd) { bd = d; bc = c; }   // ascending c => first-index ties
      }
    }
  }
  if (lane == 0) {
    idx_final[t] = bc;
    out[IDX_OFF + t] = bfround((float)bc);
    atomicAdd(&counts[bc], 1);
    lred[wid] = bd;
  }
  __syncthreads();
  if (threadIdx.x == 0)
    lossp[blockIdx.x] = (lred[0] + lred[1]) + (lred[2] + lred[3]);
}

// Blocks 0..4095: gather e[idx] -> bf16-rounded z_q (after select; free to
// overwrite groupmin/gmask scratch). Block 4096: finalize loss+perplexity.
__global__ __launch_bounds__(256) void scatter_fin(
    const float* __restrict__ e, const int* __restrict__ idx_final,
    const int* __restrict__ counts, const float* __restrict__ lossp,
    float* __restrict__ out) {
  if (blockIdx.x == N_TOK / 8) {
    __shared__ float red[4], red2[4];
    int tid = threadIdx.x;
    float s = 0.f;
    for (int j = tid; j < NE; j += 256) {
      float p = (float)counts[j] * (1.0f / (float)N_TOK);
      s += p * logf(p + 1e-10f);
    }
    float ls = 0.f;
    for (int j = tid; j < N_TOK / 4; j += 256) ls += lossp[j];
    #pragma unroll
    for (int m = 32; m >= 1; m >>= 1) {
      s += __shfl_xor(s, m);
      ls += __shfl_xor(ls, m);
    }
    if ((tid & 63) == 0) { red[tid >> 6] = s; red2[tid >> 6] = ls; }
    __syncthreads();
    if (tid == 0) {
      float tot = red[0] + red[1] + red[2] + red[3];
      float lt = red2[0] + red2[1] + red2[2] + red2[3];
      out[PERP_OFF] = bfround(expf(-tot));
      out[LOSS_OFF] = bfround(lt * 1.25f / (float)(N_TOK * DIM));
    }
    return;
  }
  int t = blockIdx.x * 8 + (threadIdx.x >> 5);
  int g = threadIdx.x & 31;
  int idx = idx_final[t] & (NE - 1);
  const float* er = e + (size_t)idx * DIM;
  float* op = out + (size_t)t * DIM;
  #pragma unroll
  for (int p = 0; p < 4; ++p) {
    int c = p * 128 + g * 4;
    float4 ev = *(const float4*)(er + c);
    float4 ov;
    ov.x = bfround(ev.x); ov.y = bfround(ev.y);
    ov.z = bfround(ev.z); ov.w = bfround(ev.w);
    *(float4*)(op + c) = ov;
  }
}

extern "C" void kernel_launch(void* const* d_in, const int* in_sizes, int n_in,
                              void* d_out, int out_size, void* d_ws, size_t ws_size,
                              hipStream_t stream) {
  const float* z = (const float*)d_in[0];
  const float* e = (const float*)d_in[1];
  float* out = (float*)d_out;
  char* ws = (char*)d_ws;

  float*    zsum      = (float*)(ws + KB(0));      // 128 KB
  float*    esum      = (float*)(ws + KB(128));    // 8 KB
  int*      counts    = (int*)(ws + KB(136));      // 8 KB
  float*    lossp     = (float*)(ws + KB(144));    // 32 KB
  int*      idx_final = (int*)(ws + KB(176));      // 128 KB
  unsigned short* ebf = (unsigned short*)(ws + KB(304)); // 2 MB

  // scratch parked in d_out's z_q region (overwritten only after select):
  unsigned short* zbf = (unsigned short*)out;              // 32 MB
  float* groupmin = out + 8388608;                         // 16 MB
  unsigned short* gmask = (unsigned short*)(out + 12582912); // 8 MB

  npsum_cvt_all<<<N_TOK / 16 + NE / 16, 256, 0, stream>>>(
      z, e, zsum, esum, zbf, ebf, counts);
  gemm_groupmin<<<dim3(N_TOK / 256, NE / 256), 512, 131072, stream>>>(
      ebf, zbf, esum, groupmin, gmask);
  select_exact<<<N_TOK / 4, 256, 0, stream>>>(z, e, zsum, esum, groupmin, gmask,
                                              idx_final, counts, out, lossp);
  scatter_fin<<<N_TOK / 8 + 1, 256, 0, stream>>>(e, idx_final, counts, lossp, out);
}

// Round 21
// 156.574 us; speedup vs baseline: 7.5833x; 1.0079x over previous
//
#include <hip/hip_runtime.h>
#include <hip/hip_bf16.h>

#define N_TOK 32768
#define DIM   512
#define NE    2048

#define IDX_OFF  (N_TOK * DIM)
#define LOSS_OFF (IDX_OFF + N_TOK)
#define PERP_OFF (LOSS_OFF + 1)

#define KB(x) ((size_t)(x) << 10)
#define EPS 4e-4f
#define EPS_SEL 1e-3f   // EPS + 2*bf16-quantization bound on stored group mins

typedef __attribute__((ext_vector_type(8))) short bf16x8;
typedef __attribute__((ext_vector_type(4))) float f32x4;

__device__ inline unsigned short f2bf(float f) {
  unsigned int x = __float_as_uint(f);
  x = x + 0x7fffu + ((x >> 16) & 1u);
  return (unsigned short)(x >> 16);
}
__device__ inline float bfround(float f) {
  return __uint_as_float((unsigned int)f2bf(f) << 16);
}

// Combined: np.sum(x*x) exact replication (validated round 4 — sum chain
// untouched) + fused bf16 conversion for z and e. Blocks 0..7 zero counts.
__global__ __launch_bounds__(256) void npsum_cvt_all(
    const float* __restrict__ z, const float* __restrict__ e,
    float* __restrict__ zsum, float* __restrict__ esum,
    unsigned short* __restrict__ zbf, unsigned short* __restrict__ ebf,
    int* __restrict__ counts) {
#pragma clang fp contract(off)
  const int bz = blockIdx.x;
  if (bz < 8) counts[bz * 256 + threadIdx.x] = 0;
  const bool isz = bz < (N_TOK / 16);
  const int blk = isz ? bz : bz - (N_TOK / 16);
  const float* x = isz ? z : e;
  float* outs = isz ? zsum : esum;
  unsigned short* xbf = isz ? zbf : ebf;

  int wave = threadIdx.x >> 6;
  int lane = threadIdx.x & 63;
  int grp = lane >> 4, l = lane & 15;
  int row = blk * 16 + wave * 4 + grp;
  {
    const float* a = x + (size_t)row * DIM;
    float L[4];
    #pragma unroll
    for (int b = 0; b < 4; ++b) {
      const float* p = a + b * 128 + l;
      float q[8];
      #pragma unroll
      for (int j = 0; j < 8; ++j) {
        float t = p[16 * j];
        float s = t * t;
        asm volatile("" : "+v"(s));
        q[j] = s;
      }
      float v = ((q[0] + q[1]) + (q[2] + q[3])) + ((q[4] + q[5]) + (q[6] + q[7]));
      v += __shfl_xor(v, 8);
      v += __shfl_xor(v, 4);
      v += __shfl_xor(v, 2);
      v += __shfl_xor(v, 1);
      L[b] = v;
    }
    if (l == 0) outs[row] = (L[0] + L[1]) + (L[2] + L[3]);
  }
  const float* blkp = x + (size_t)blk * 16 * DIM;
  unsigned short* ob = xbf + (size_t)blk * 16 * DIM;
  #pragma unroll
  for (int u = 0; u < 4; ++u) {
    size_t off = (size_t)(u * 256 + threadIdx.x) * 8;
    float4 a2 = *(const float4*)(blkp + off);
    float4 b2 = *(const float4*)(blkp + off + 4);
    unsigned short h[8] = {f2bf(a2.x), f2bf(a2.y), f2bf(a2.z), f2bf(a2.w),
                           f2bf(b2.x), f2bf(b2.y), f2bf(b2.z), f2bf(b2.w)};
    *(uint4*)(ob + off) = *(uint4*)h;
  }
}

// Stage one 128x64-bf16 half-tile (16KB) via global_load_lds width 16.
__device__ inline void stage_half(const unsigned short* __restrict__ gsrc,
                                  unsigned short* lds, int w, int l) {
  const int swz_col = ((l & 7) ^ (l >> 3)) * 8;
  const int rsub = l >> 3;
  #pragma unroll
  for (int s4 = 0; s4 < 2; ++s4) {
    int s = w * 2 + s4;
    const unsigned short* g = gsrc + (size_t)(s * 8 + rsub) * DIM + swz_col;
    __builtin_amdgcn_global_load_lds(
        (const __attribute__((address_space(1))) unsigned int*)g,
        (__attribute__((address_space(3))) unsigned int*)(lds + s * 512),
        16, 0, 0);
  }
}

#define BAR()   asm volatile("s_barrier" ::: "memory")
#define VMCNT4  asm volatile("s_waitcnt vmcnt(4)" ::: "memory")
#define VMCNT0  asm volatile("s_waitcnt vmcnt(0)" ::: "memory")

// 8-phase MFMA GEMM — R15 structure, register epilogue (R20, validated).
// Output: ONE u32 per (token, group): bf16(groupmin)<<16 | candidate mask16.
// Mask bits remain fp32-exact (bit set iff v <= m_fp32 + EPS); only the
// group-qualification value is bf16-quantized (EPS_SEL covers 2q).
__global__ __launch_bounds__(512, 2) void gemm_groupmin(
    const unsigned short* __restrict__ ebf, const unsigned short* __restrict__ zbf,
    const float* __restrict__ esum, unsigned* __restrict__ gmv) {
  extern __shared__ unsigned short smem[];
  unsigned short* As = smem;
  unsigned short* Bs = smem + 32768;

  const int tid = threadIdx.x;
  const int tb = blockIdx.x;   // token block (128) — XCD-swizzled grid
  const int cb = blockIdx.y;   // code block (8)
  const int w = tid >> 6, l = tid & 63;
  const int lr = l & 15, lk = l >> 4;
  const int wrow = (w >> 2) * 128;
  const int wcol = (w & 3) * 64;

  f32x4 acc[8][4];
  #pragma unroll
  for (int i = 0; i < 8; ++i)
    #pragma unroll
    for (int j = 0; j < 4; ++j) acc[i][j] = (f32x4)(0.f);

  bf16x8 aR[8], bA[4], bB[4];

  const unsigned short* Ag = ebf + (size_t)(cb * 256) * DIM;
  const unsigned short* Bg = zbf + (size_t)(tb * 256) * DIM;

#define LOADA(slot, qm) do { \
  _Pragma("unroll") for (int i2 = 0; i2 < 4; ++i2) { \
    int R = wrow + (qm)*64 + i2*16 + lr; \
    int rbase = ((slot)*2 + (R>>7))*8192 + (R&127)*64; \
    aR[i2*2+0] = *(const bf16x8*)&As[rbase + (((lk    ) ^ (R&7))*8)]; \
    aR[i2*2+1] = *(const bf16x8*)&As[rbase + (((4 + lk) ^ (R&7))*8)]; \
  } } while (0)

#define LOADB(dst, slot, qn) do { \
  _Pragma("unroll") for (int j = 0; j < 2; ++j) { \
    int C = wcol + (qn)*32 + j*16 + lr; \
    int cbase = ((slot)*2 + (C>>7))*8192 + (C&127)*64; \
    dst[j*2+0] = *(const bf16x8*)&Bs[cbase + (((lk    ) ^ (C&7))*8)]; \
    dst[j*2+1] = *(const bf16x8*)&Bs[cbase + (((4 + lk) ^ (C&7))*8)]; \
  } } while (0)

#define MFMA16(qm, qn, bX) do { \
  __builtin_amdgcn_s_setprio(1); \
  _Pragma("unroll") for (int i2 = 0; i2 < 4; ++i2) \
    _Pragma("unroll") for (int j = 0; j < 2; ++j) { \
      acc[(qm)*4+i2][(qn)*2+j] = __builtin_amdgcn_mfma_f32_16x16x32_bf16( \
          aR[i2*2+0], bX[j*2+0], acc[(qm)*4+i2][(qn)*2+j], 0, 0, 0); \
      acc[(qm)*4+i2][(qn)*2+j] = __builtin_amdgcn_mfma_f32_16x16x32_bf16( \
          aR[i2*2+1], bX[j*2+1], acc[(qm)*4+i2][(qn)*2+j], 0, 0, 0); \
    } \
  __builtin_amdgcn_s_setprio(0); \
} while (0)

  stage_half(Bg,                 Bs,             w, l);
  stage_half(Bg + 128 * DIM,     Bs + 8192,      w, l);
  stage_half(Ag,                 As,             w, l);
  stage_half(Ag + 128 * DIM,     As + 8192,      w, l);
  stage_half(Bg + 64,            Bs + 2 * 8192,  w, l);
  stage_half(Bg + 128 * DIM + 64, Bs + 3 * 8192, w, l);
  VMCNT4;
  BAR();

  #pragma unroll
  for (int i = 0; i < 4; ++i) {
    const int t1k = (2 * i + 1) * 64;
    const int u0k = (2 * i + 2) * 64;
    const int u1k = (2 * i + 3) * 64;
    LOADA(0, 0); LOADB(bA, 0, 0); LOADB(bB, 0, 1);
    stage_half(Ag + t1k, As + 2 * 8192, w, l);
    BAR(); MFMA16(0, 0, bA);
    stage_half(Ag + 128 * DIM + t1k, As + 3 * 8192, w, l);
    BAR(); MFMA16(0, 1, bB);
    LOADA(0, 1);
    if (i < 3) stage_half(Bg + u0k, Bs, w, l);
    BAR(); MFMA16(1, 0, bA);
    if (i < 3) stage_half(Bg + 128 * DIM + u0k, Bs + 8192, w, l);
    BAR(); MFMA16(1, 1, bB);
    if (i < 3) { VMCNT4; } else { VMCNT0; }
    BAR();
    LOADA(1, 0); LOADB(bA, 1, 0); LOADB(bB, 1, 1);
    if (i < 3) stage_half(Ag + u0k, As, w, l);
    BAR(); MFMA16(0, 0, bA);
    if (i < 3) stage_half(Ag + 128 * DIM + u0k, As + 8192, w, l);
    BAR(); MFMA16(0, 1, bB);
    LOADA(1, 1);
    if (i < 3) stage_half(Bg + u1k, Bs + 2 * 8192, w, l);
    BAR(); MFMA16(1, 0, bA);
    if (i < 3) stage_half(Bg + 128 * DIM + u1k, Bs + 3 * 8192, w, l);
    BAR(); MFMA16(1, 1, bB);
    if (i < 3) { VMCNT4; BAR(); }
  }

  float esr[8][4];
  #pragma unroll
  for (int i = 0; i < 8; ++i)
    #pragma unroll
    for (int q = 0; q < 4; ++q)
      esr[i][q] = esum[cb * 256 + wrow + i * 16 + lk * 4 + q];

  // register-accumulated epilogue (validated R20), packed u32 output
  unsigned gmv8[4][8];
  #pragma unroll
  for (int i = 0; i < 8; ++i) {
    #pragma unroll
    for (int j = 0; j < 4; ++j) {
      float v0 = fmaf(-2.f, acc[i][j][0], esr[i][0]);
      float v1 = fmaf(-2.f, acc[i][j][1], esr[i][1]);
      float v2 = fmaf(-2.f, acc[i][j][2], esr[i][2]);
      float v3 = fmaf(-2.f, acc[i][j][3], esr[i][3]);
      float m = fminf(fminf(v0, v1), fminf(v2, v3));
      m = fminf(m, __shfl_xor(m, 16));
      m = fminf(m, __shfl_xor(m, 32));
      float gl = m + EPS;
      int mk = (((v0 <= gl) ? 1 : 0) | ((v1 <= gl) ? 2 : 0) |
                ((v2 <= gl) ? 4 : 0) | ((v3 <= gl) ? 8 : 0)) << (lk * 4);
      mk |= __shfl_xor(mk, 16);
      mk |= __shfl_xor(mk, 32);
      gmv8[j][i] = ((unsigned)f2bf(m) << 16) | (unsigned)(mk & 0xFFFF);
    }
  }
  if (lk == 0) {
    #pragma unroll
    for (int j = 0; j < 4; ++j) {
      int token = tb * 256 + wcol + j * 16 + lr;
      size_t gb = (size_t)token * 128 + cb * 16 + (w >> 2) * 8;
      uint4 q0 = {gmv8[j][0], gmv8[j][1], gmv8[j][2], gmv8[j][3]};
      uint4 q1 = {gmv8[j][4], gmv8[j][5], gmv8[j][6], gmv8[j][7]};
      *(uint4*)&gmv[gb] = q0;
      *(uint4*)&gmv[gb + 4] = q1;
    }
  }
#undef LOADA
#undef LOADB
#undef MFMA16
}

// One wave per token: mask-guided exact rescan (validated R18-R20), u32
// packed gmv. If fused: also writes z_q (requires gmv NOT aliased with the
// z_q region — only enabled when gmv lives in d_ws).
__global__ __launch_bounds__(256) void select_exact(
    const float* __restrict__ z, const float* __restrict__ e,
    const float* __restrict__ zsum, const float* __restrict__ esum,
    const unsigned* __restrict__ gmv,
    int* __restrict__ idx_final, int* __restrict__ counts,
    float* __restrict__ out, float* __restrict__ lossp, int fused) {
  __shared__ float lred[4];
  const int wid = threadIdx.x >> 6;
  const int t = blockIdx.x * 4 + wid;
  const int lane = threadIdx.x & 63;
  const float* zr = z + (size_t)t * DIM;

  float4 za = *(const float4*)(zr + lane * 4);
  float4 zb = *(const float4*)(zr + 256 + lane * 4);

  unsigned u0 = gmv[(size_t)t * 128 + lane];
  unsigned u1 = gmv[(size_t)t * 128 + 64 + lane];
  float g0 = __uint_as_float(u0 & 0xFFFF0000u);
  float g1 = __uint_as_float(u1 & 0xFFFF0000u);
  float m = fminf(g0, g1);
  #pragma unroll
  for (int s = 32; s >= 1; s >>= 1) m = fminf(m, __shfl_xor(m, s));
  float lim = m + EPS_SEL;
  unsigned long long mm0 = __ballot(g0 <= lim);
  unsigned long long mm1 = __ballot(g1 <= lim);
  float zst = zsum[t];
  float bd = 3.402823466e38f; int bc = 0x7fffffff;

  #pragma unroll 1
  for (int half = 0; half < 2; ++half) {
    unsigned long long mk = half ? mm1 : mm0;
    while (mk) {
      int b = __ffsll((unsigned long long)mk) - 1;
      mk &= mk - 1;
      const int base = (half * 64 + b) * 16;
      unsigned gm = (unsigned)__shfl((int)(half ? u1 : u0), b) & 0xFFFFu;
      while (gm) {
        int ci = __ffs(gm) - 1;
        gm &= gm - 1;
        int c = base + ci;
        const float* er = e + (size_t)c * DIM;
        float4 ea = *(const float4*)(er + lane * 4);
        float4 eb = *(const float4*)(er + 256 + lane * 4);
        float p = 0.f;
        p = fmaf(za.x, ea.x, p); p = fmaf(za.y, ea.y, p);
        p = fmaf(za.z, ea.z, p); p = fmaf(za.w, ea.w, p);
        p = fmaf(zb.x, eb.x, p); p = fmaf(zb.y, eb.y, p);
        p = fmaf(zb.z, eb.z, p); p = fmaf(zb.w, eb.w, p);
        #pragma unroll
        for (int s = 1; s <= 32; s <<= 1) p += __shfl_xor(p, s);
        float d = (zst + esum[c]) - 2.f * p;
        if (d < bd) { bd = d; bc = c; }   // ascending c => first-index ties
      }
    }
  }
  if (fused) {
    // gmv is in d_ws: safe to write z_q now (winner row is L2-hot)
    const float* er = e + (size_t)(bc & (NE - 1)) * DIM;
    float4 ea = *(const float4*)(er + lane * 4);
    float4 eb = *(const float4*)(er + 256 + lane * 4);
    float* op = out + (size_t)t * DIM;
    float4 oa, ob;
    oa.x = bfround(ea.x); oa.y = bfround(ea.y);
    oa.z = bfround(ea.z); oa.w = bfround(ea.w);
    ob.x = bfround(eb.x); ob.y = bfround(eb.y);
    ob.z = bfround(eb.z); ob.w = bfround(eb.w);
    *(float4*)(op + lane * 4) = oa;
    *(float4*)(op + 256 + lane * 4) = ob;
  }
  if (lane == 0) {
    idx_final[t] = bc;
    out[IDX_OFF + t] = bfround((float)bc);
    atomicAdd(&counts[bc], 1);
    lred[wid] = bd;
  }
  __syncthreads();
  if (threadIdx.x == 0)
    lossp[blockIdx.x] = (lred[0] + lred[1]) + (lred[2] + lred[3]);
}

__device__ inline void finalize_body(const int* __restrict__ counts,
                                     const float* __restrict__ lossp,
                                     float* __restrict__ out) {
  __shared__ float red[4], red2[4];
  int tid = threadIdx.x;
  float s = 0.f;
  for (int j = tid; j < NE; j += 256) {
    float p = (float)counts[j] * (1.0f / (float)N_TOK);
    s += p * logf(p + 1e-10f);
  }
  float ls = 0.f;
  for (int j = tid; j < N_TOK / 4; j += 256) ls += lossp[j];
  #pragma unroll
  for (int m = 32; m >= 1; m >>= 1) {
    s += __shfl_xor(s, m);
    ls += __shfl_xor(ls, m);
  }
  if ((tid & 63) == 0) { red[tid >> 6] = s; red2[tid >> 6] = ls; }
  __syncthreads();
  if (tid == 0) {
    float tot = red[0] + red[1] + red[2] + red[3];
    float lt = red2[0] + red2[1] + red2[2] + red2[3];
    out[PERP_OFF] = bfround(expf(-tot));
    out[LOSS_OFF] = bfround(lt * 1.25f / (float)(N_TOK * DIM));
  }
}

__global__ __launch_bounds__(256) void fin_only(
    const int* __restrict__ counts, const float* __restrict__ lossp,
    float* __restrict__ out) {
  finalize_body(counts, lossp, out);
}

// Path B tail: blocks 0..4095 gather z_q; block 4096 finalizes (R20).
__global__ __launch_bounds__(256) void scatter_fin(
    const float* __restrict__ e, const int* __restrict__ idx_final,
    const int* __restrict__ counts, const float* __restrict__ lossp,
    float* __restrict__ out) {
  if (blockIdx.x == N_TOK / 8) { finalize_body(counts, lossp, out); return; }
  int t = blockIdx.x * 8 + (threadIdx.x >> 5);
  int g = threadIdx.x & 31;
  int idx = idx_final[t] & (NE - 1);
  const float* er = e + (size_t)idx * DIM;
  float* op = out + (size_t)t * DIM;
  #pragma unroll
  for (int p = 0; p < 4; ++p) {
    int c = p * 128 + g * 4;
    float4 ev = *(const float4*)(er + c);
    float4 ov;
    ov.x = bfround(ev.x); ov.y = bfround(ev.y);
    ov.z = bfround(ev.z); ov.w = bfround(ev.w);
    *(float4*)(op + c) = ov;
  }
}

extern "C" void kernel_launch(void* const* d_in, const int* in_sizes, int n_in,
                              void* d_out, int out_size, void* d_ws, size_t ws_size,
                              hipStream_t stream) {
  const float* z = (const float*)d_in[0];
  const float* e = (const float*)d_in[1];
  float* out = (float*)d_out;
  char* ws = (char*)d_ws;

  float*    zsum      = (float*)(ws + KB(0));      // 128 KB
  float*    esum      = (float*)(ws + KB(128));    // 8 KB
  int*      counts    = (int*)(ws + KB(136));      // 8 KB
  float*    lossp     = (float*)(ws + KB(144));    // 32 KB
  int*      idx_final = (int*)(ws + KB(176));      // 128 KB
  unsigned short* ebf = (unsigned short*)(ws + KB(304)); // 2 MB -> ends 2352 KB

  unsigned short* zbf = (unsigned short*)out;      // 32 MB scratch in d_out

  // gmv: 32768*128 u32 = 16 MB. Prefer d_ws (enables fused z_q write);
  // fall back to the d_out scratch region (strict ordering, separate scatter).
  const size_t gmv_off = KB(2368);
  const size_t gmv_bytes = (size_t)N_TOK * 128 * 4;
  const bool fused = ws_size >= gmv_off + gmv_bytes;
  unsigned* gmv = fused ? (unsigned*)(ws + gmv_off)
                        : (unsigned*)(out + 8388608);

  npsum_cvt_all<<<N_TOK / 16 + NE / 16, 256, 0, stream>>>(
      z, e, zsum, esum, zbf, ebf, counts);
  gemm_groupmin<<<dim3(N_TOK / 256, NE / 256), 512, 131072, stream>>>(
      ebf, zbf, esum, gmv);
  select_exact<<<N_TOK / 4, 256, 0, stream>>>(z, e, zsum, esum, gmv,
                                              idx_final, counts, out, lossp,
                                              fused ? 1 : 0);
  if (fused) {
    fin_only<<<1, 256, 0, stream>>>(counts, lossp, out);
  } else {
    scatter_fin<<<N_TOK / 8 + 1, 256, 0, stream>>>(e, idx_final, counts, lossp, out);
  }
}